// Round 1
// baseline (3260.605 us; speedup 1.0000x reference)
//
#include <hip/hip_runtime.h>
#include <math.h>

#define NN 50000
#define EE 800000
#define BB 250
#define TT 8
#define CIN 32
#define COUT 64
#define NPG 200          // nodes per graph (N/B)
#define SCAN_B 256
#define NBLK 196         // ceil(50000/256)

// ---------------- setup kernels (graph structure, once per call) ----------------

__global__ void init_deg(int* deg, int* cursor) {
    int n = blockIdx.x * 256 + threadIdx.x;
    if (n < NN) { deg[n] = 1; cursor[n] = 0; }   // self-loop contributes 1
}

__global__ void count_deg(const int* dst, int* deg) {
    int e = blockIdx.x * 256 + threadIdx.x;
    if (e < EE) atomicAdd(&deg[dst[e]], 1);
}

__global__ void compute_dinv(const int* deg, float* dinv) {
    int n = blockIdx.x * 256 + threadIdx.x;
    if (n < NN) dinv[n] = rsqrtf((float)deg[n]);
}

// exclusive scan of indeg (= deg-1) over N elements, 3-phase
__global__ void scan_blocks(const int* deg, int* off, int* bsum) {
    __shared__ int sh[SCAN_B];
    int gid = blockIdx.x * SCAN_B + threadIdx.x;
    int v = (gid < NN) ? (deg[gid] - 1) : 0;
    sh[threadIdx.x] = v;
    __syncthreads();
    for (int s = 1; s < SCAN_B; s <<= 1) {
        int add = (threadIdx.x >= s) ? sh[threadIdx.x - s] : 0;
        __syncthreads();
        sh[threadIdx.x] += add;
        __syncthreads();
    }
    if (gid < NN) off[gid] = sh[threadIdx.x] - v;       // exclusive
    if (threadIdx.x == SCAN_B - 1) bsum[blockIdx.x] = sh[threadIdx.x];
}

__global__ void scan_sums(int* bsum, int* off) {
    __shared__ int sh[SCAN_B];
    int v = (threadIdx.x < NBLK) ? bsum[threadIdx.x] : 0;
    sh[threadIdx.x] = v;
    __syncthreads();
    for (int s = 1; s < SCAN_B; s <<= 1) {
        int add = (threadIdx.x >= s) ? sh[threadIdx.x - s] : 0;
        __syncthreads();
        sh[threadIdx.x] += add;
        __syncthreads();
    }
    if (threadIdx.x < NBLK) bsum[threadIdx.x] = sh[threadIdx.x] - v;  // exclusive
    if (threadIdx.x == 0) off[NN] = EE;
}

__global__ void scan_add(int* off, const int* bsum) {
    int gid = blockIdx.x * SCAN_B + threadIdx.x;
    if (gid < NN) off[gid] += bsum[blockIdx.x];
}

__global__ void fill_csr(const int* src, const int* dst, const int* off,
                         int* cursor, const float* dinv, int* csr_src, float* csr_w) {
    int e = blockIdx.x * 256 + threadIdx.x;
    if (e >= EE) return;
    int s = src[e], d = dst[e];
    int p = atomicAdd(&cursor[d], 1);
    int pos = off[d] + p;
    csr_src[pos] = s;
    csr_w[pos] = dinv[s] * dinv[d];
}

// ---------------- per-timestep kernels ----------------

// layer-1 input aggregation: xa[n][c] = sum_{e: dst=n} w_e * x[src_e, c, t] + dinv[n]^2 * x[n, c, t]
// block = 256 threads = 8 nodes x 32 channels
__global__ void agg_x(const float* x, const int* off, const int* csr_src,
                      const float* csr_w, const float* dinv, float* xa, int t) {
    int c = threadIdx.x & 31;
    int n = blockIdx.x * 8 + (threadIdx.x >> 5);
    float dn = dinv[n];
    float acc = dn * dn * x[(size_t)n * (CIN * TT) + c * TT + t];
    int e0 = off[n], e1 = off[n + 1];
    for (int j = e0; j < e1; ++j) {
        int s = csr_src[j];
        acc = fmaf(csr_w[j], x[(size_t)s * (CIN * TT) + c * TT + t], acc);
    }
    xa[n * CIN + c] = acc;
}

// h = relu(xa @ W1 + b1); block = 4 nodes x 64 outch
__global__ void mat32_relu(const float* xa, const float* W, const float* b, float* h) {
    __shared__ float Ws[CIN * COUT];
    __shared__ float Xs[4][CIN];
    for (int i = threadIdx.x; i < CIN * COUT; i += 256) Ws[i] = W[i];
    int co = threadIdx.x & 63;
    int nl = threadIdx.x >> 6;
    int n = blockIdx.x * 4 + nl;
    if (co < CIN) Xs[nl][co] = xa[n * CIN + co];
    __syncthreads();
    float acc = b[co];
    #pragma unroll
    for (int k = 0; k < CIN; ++k) acc = fmaf(Xs[nl][k], Ws[k * COUT + co], acc);
    h[(size_t)n * COUT + co] = fmaxf(acc, 0.f);
}

// hw = h @ W (no bias/relu); block = 4 nodes x 64 outch
__global__ void mat64(const float* hin, const float* W, float* hw) {
    __shared__ float Ws[COUT * COUT];
    __shared__ float Xs[4][COUT];
    for (int i = threadIdx.x; i < COUT * COUT; i += 256) Ws[i] = W[i];
    int co = threadIdx.x & 63;
    int nl = threadIdx.x >> 6;
    int n = blockIdx.x * 4 + nl;
    Xs[nl][co] = hin[(size_t)n * COUT + co];
    __syncthreads();
    float acc = 0.f;
    #pragma unroll
    for (int k = 0; k < COUT; ++k) acc = fmaf(Xs[nl][k], Ws[k * COUT + co], acc);
    hw[(size_t)n * COUT + co] = acc;
}

// h_out = relu(A_hat @ hw + b); block = 4 nodes x 64 ch (one wave per node)
__global__ void agg64_relu(const float* hw, const int* off, const int* csr_src,
                           const float* csr_w, const float* dinv, const float* b,
                           float* hout) {
    int c = threadIdx.x & 63;
    int n = blockIdx.x * 4 + (threadIdx.x >> 6);
    float dn = dinv[n];
    float acc = dn * dn * hw[(size_t)n * COUT + c];
    int e0 = off[n], e1 = off[n + 1];
    for (int j = e0; j < e1; ++j) {
        int s = csr_src[j];
        acc = fmaf(csr_w[j], hw[(size_t)s * COUT + c], acc);
    }
    hout[(size_t)n * COUT + c] = fmaxf(acc + b[c], 0.f);
}

// pool one layer's h into out[b, :, t]; accumulate==0 -> write, else +=
// block = 1 graph, 256 threads = 4 rows x 64 channels
__global__ void pool_acc(const float* h, float* out, int t, int accumulate) {
    int g = blockIdx.x;
    int c = threadIdx.x & 63;
    int r = threadIdx.x >> 6;
    const float* hp = h + (size_t)g * NPG * COUT;
    float mx = -INFINITY, sm = 0.f;
    for (int n = r; n < NPG; n += 4) {
        float v = hp[n * COUT + c];
        mx = fmaxf(mx, v);
        sm += v;
    }
    __shared__ float smx[4][COUT];
    __shared__ float ssm[4][COUT];
    smx[r][c] = mx;
    ssm[r][c] = sm;
    __syncthreads();
    if (r == 0) {
        #pragma unroll
        for (int i = 1; i < 4; ++i) {
            mx = fmaxf(mx, smx[i][c]);
            sm += ssm[i][c];
        }
        float mean = sm * (1.0f / NPG);
        size_t o = (size_t)g * (2 * COUT * TT) + (size_t)c * TT + t;
        if (accumulate) {
            out[o] += mx;
            out[o + COUT * TT] += mean;
        } else {
            out[o] = mx;
            out[o + COUT * TT] = mean;
        }
    }
}

// ---------------- launch ----------------

extern "C" void kernel_launch(void* const* d_in, const int* in_sizes, int n_in,
                              void* d_out, int out_size, void* d_ws, size_t ws_size,
                              hipStream_t stream) {
    const float* x   = (const float*)d_in[0];
    const int*   ei  = (const int*)d_in[1];
    const int*   src = ei;
    const int*   dst = ei + EE;
    const float* W1  = (const float*)d_in[3];
    const float* b1  = (const float*)d_in[4];
    const float* W2  = (const float*)d_in[5];
    const float* b2  = (const float*)d_in[6];
    const float* W3  = (const float*)d_in[7];
    const float* b3  = (const float*)d_in[8];
    float* out = (float*)d_out;

    char* wsp = (char*)d_ws;
    auto alloc = [&](size_t bytes) {
        char* p = wsp;
        wsp += (bytes + 255) & ~(size_t)255;
        return p;
    };
    int*   deg     = (int*)  alloc((size_t)NN * 4);
    int*   cursor  = (int*)  alloc((size_t)NN * 4);
    float* dinv    = (float*)alloc((size_t)NN * 4);
    int*   off     = (int*)  alloc((size_t)(NN + 1) * 4);
    int*   bsum    = (int*)  alloc((size_t)SCAN_B * 4);
    int*   csr_src = (int*)  alloc((size_t)EE * 4);
    float* csr_w   = (float*)alloc((size_t)EE * 4);
    float* xa      = (float*)alloc((size_t)NN * CIN * 4);
    float* hA      = (float*)alloc((size_t)NN * COUT * 4);
    float* hB      = (float*)alloc((size_t)NN * COUT * 4);
    float* hw      = (float*)alloc((size_t)NN * COUT * 4);

    // structure (time-invariant)
    init_deg<<<NBLK, 256, 0, stream>>>(deg, cursor);
    count_deg<<<(EE + 255) / 256, 256, 0, stream>>>(dst, deg);
    compute_dinv<<<NBLK, 256, 0, stream>>>(deg, dinv);
    scan_blocks<<<NBLK, SCAN_B, 0, stream>>>(deg, off, bsum);
    scan_sums<<<1, SCAN_B, 0, stream>>>(bsum, off);
    scan_add<<<NBLK, SCAN_B, 0, stream>>>(off, bsum);
    fill_csr<<<(EE + 255) / 256, 256, 0, stream>>>(src, dst, off, cursor, dinv,
                                                   csr_src, csr_w);

    for (int t = 0; t < TT; ++t) {
        // layer 1: (A_hat x) @ W1  (reordered; halves gather width)
        agg_x<<<NN / 8, 256, 0, stream>>>(x, off, csr_src, csr_w, dinv, xa, t);
        mat32_relu<<<NN / 4, 256, 0, stream>>>(xa, W1, b1, hA);
        pool_acc<<<BB, 256, 0, stream>>>(hA, out, t, 0);
        // layer 2: A_hat (h1 @ W2)
        mat64<<<NN / 4, 256, 0, stream>>>(hA, W2, hw);
        agg64_relu<<<NN / 4, 256, 0, stream>>>(hw, off, csr_src, csr_w, dinv, b2, hB);
        pool_acc<<<BB, 256, 0, stream>>>(hB, out, t, 1);
        // layer 3: A_hat (h2 @ W3)
        mat64<<<NN / 4, 256, 0, stream>>>(hB, W3, hw);
        agg64_relu<<<NN / 4, 256, 0, stream>>>(hw, off, csr_src, csr_w, dinv, b3, hA);
        pool_acc<<<BB, 256, 0, stream>>>(hA, out, t, 1);
    }
}

// Round 2
// 3253.236 us; speedup vs baseline: 1.0023x; 1.0023x over previous
//
#include <hip/hip_runtime.h>
#include <math.h>

#define NN 50000
#define EE 800000
#define BB 250
#define TT 8
#define CIN 32
#define COUT 64
#define NPG 200          // nodes per graph (N/B)
#define SCAN_B 256
#define NBLK 196         // ceil(50000/256)

// ---------------- setup kernels (graph structure, once per call) ----------------

__global__ void init_deg(int* deg, int* cursor) {
    int n = blockIdx.x * 256 + threadIdx.x;
    if (n < NN) { deg[n] = 1; cursor[n] = 0; }   // self-loop contributes 1
}

__global__ void count_deg(const int* dst, int* deg) {
    int e = blockIdx.x * 256 + threadIdx.x;
    if (e < EE) atomicAdd(&deg[dst[e]], 1);
}

__global__ void compute_dinv(const int* deg, float* dinv) {
    int n = blockIdx.x * 256 + threadIdx.x;
    if (n < NN) dinv[n] = rsqrtf((float)deg[n]);
}

// exclusive scan of indeg (= deg-1) over N elements, 3-phase
__global__ void scan_blocks(const int* deg, int* off, int* bsum) {
    __shared__ int sh[SCAN_B];
    int gid = blockIdx.x * SCAN_B + threadIdx.x;
    int v = (gid < NN) ? (deg[gid] - 1) : 0;
    sh[threadIdx.x] = v;
    __syncthreads();
    for (int s = 1; s < SCAN_B; s <<= 1) {
        int add = (threadIdx.x >= s) ? sh[threadIdx.x - s] : 0;
        __syncthreads();
        sh[threadIdx.x] += add;
        __syncthreads();
    }
    if (gid < NN) off[gid] = sh[threadIdx.x] - v;       // exclusive
    if (threadIdx.x == SCAN_B - 1) bsum[blockIdx.x] = sh[threadIdx.x];
}

__global__ void scan_sums(int* bsum, int* off) {
    __shared__ int sh[SCAN_B];
    int v = (threadIdx.x < NBLK) ? bsum[threadIdx.x] : 0;
    sh[threadIdx.x] = v;
    __syncthreads();
    for (int s = 1; s < SCAN_B; s <<= 1) {
        int add = (threadIdx.x >= s) ? sh[threadIdx.x - s] : 0;
        __syncthreads();
        sh[threadIdx.x] += add;
        __syncthreads();
    }
    if (threadIdx.x < NBLK) bsum[threadIdx.x] = sh[threadIdx.x] - v;  // exclusive
    if (threadIdx.x == 0) off[NN] = EE;
}

__global__ void scan_add(int* off, const int* bsum) {
    int gid = blockIdx.x * SCAN_B + threadIdx.x;
    if (gid < NN) off[gid] += bsum[blockIdx.x];
}

__global__ void fill_csr(const int* src, const int* dst, const int* off,
                         int* cursor, const float* dinv, int* csr_src, float* csr_w) {
    int e = blockIdx.x * 256 + threadIdx.x;
    if (e >= EE) return;
    int s = src[e], d = dst[e];
    int p = atomicAdd(&cursor[d], 1);
    int pos = off[d] + p;
    csr_src[pos] = s;
    csr_w[pos] = dinv[s] * dinv[d];
}

// ============ BATCHED-T PATH ============

// xa[n][t][c] = sum_e w_e * x[src_e][c][t] + dinv[n]^2 * x[n][c][t], all t at once.
// One wave per node; lane l holds float4 = elements [4l,4l+4) of the node's
// contiguous 256-float (c-major, t-minor) row. Transposed write to [t][c].
__global__ void agg_x_all(const float* __restrict__ x, const int* __restrict__ off,
                          const int* __restrict__ csr_src, const float* __restrict__ csr_w,
                          const float* __restrict__ dinv, float* __restrict__ xa) {
    int lane = threadIdx.x & 63;
    int n = blockIdx.x * 4 + (threadIdx.x >> 6);
    float dn = dinv[n];
    const float4* xrow = (const float4*)(x + (size_t)n * 256);
    float4 v = xrow[lane];
    float sw = dn * dn;
    float4 acc = make_float4(sw * v.x, sw * v.y, sw * v.z, sw * v.w);
    int e0 = off[n], e1 = off[n + 1];
    for (int j = e0; j < e1; ++j) {
        int s = csr_src[j];
        float w = csr_w[j];
        float4 u = ((const float4*)(x + (size_t)s * 256))[lane];
        acc.x = fmaf(w, u.x, acc.x);
        acc.y = fmaf(w, u.y, acc.y);
        acc.z = fmaf(w, u.z, acc.z);
        acc.w = fmaf(w, u.w, acc.w);
    }
    // element flat idx f = 4*lane+k maps to (c = f>>3, t = f&7); write xa[n][t][c]
    float* xab = xa + (size_t)n * 256;
    float av[4] = {acc.x, acc.y, acc.z, acc.w};
    #pragma unroll
    for (int k = 0; k < 4; ++k) {
        int f = 4 * lane + k;
        xab[(f & 7) * 32 + (f >> 3)] = av[k];
    }
}

// h[r][co] = relu(xa[r][:] @ W1 + b1) over R = N*T rows; block = 4 rows x 64 outch
__global__ void mat32_relu_all(const float* __restrict__ xa, const float* __restrict__ W,
                               const float* __restrict__ b, float* __restrict__ h) {
    __shared__ float Ws[CIN * COUT];
    __shared__ float Xs[4][CIN];
    for (int i = threadIdx.x; i < CIN * COUT; i += 256) Ws[i] = W[i];
    int co = threadIdx.x & 63;
    int nl = threadIdx.x >> 6;
    size_t r = (size_t)blockIdx.x * 4 + nl;
    if (co < CIN) Xs[nl][co] = xa[r * CIN + co];
    __syncthreads();
    float acc = b[co];
    #pragma unroll
    for (int k = 0; k < CIN; ++k) acc = fmaf(Xs[nl][k], Ws[k * COUT + co], acc);
    h[r * COUT + co] = fmaxf(acc, 0.f);
}

// hw[r][co] = h[r][:] @ W over R = N*T rows
__global__ void mat64_all(const float* __restrict__ hin, const float* __restrict__ W,
                          float* __restrict__ hw) {
    __shared__ float Ws[COUT * COUT];
    __shared__ float Xs[4][COUT];
    for (int i = threadIdx.x; i < COUT * COUT; i += 256) Ws[i] = W[i];
    int co = threadIdx.x & 63;
    int nl = threadIdx.x >> 6;
    size_t r = (size_t)blockIdx.x * 4 + nl;
    Xs[nl][co] = hin[r * COUT + co];
    __syncthreads();
    float acc = 0.f;
    #pragma unroll
    for (int k = 0; k < COUT; ++k) acc = fmaf(Xs[nl][k], Ws[k * COUT + co], acc);
    hw[r * COUT + co] = acc;
}

// hout[n][t][c] = relu(sum_e w_e*hw[s][t][c] + dinv^2*hw[n][t][c] + b[c]), all t.
// One wave per node; node row = 512 contiguous floats; lane l holds
// elements [4l,4l+4) of each 256-float half (two float4 accumulators).
__global__ void agg64_relu_all(const float* __restrict__ hw, const int* __restrict__ off,
                               const int* __restrict__ csr_src, const float* __restrict__ csr_w,
                               const float* __restrict__ dinv, const float* __restrict__ b,
                               float* __restrict__ hout) {
    int lane = threadIdx.x & 63;
    int n = blockIdx.x * 4 + (threadIdx.x >> 6);
    float dn = dinv[n];
    float sw = dn * dn;
    const float4* hrow = (const float4*)(hw + (size_t)n * 512);
    float4 va = hrow[lane];
    float4 vb = hrow[64 + lane];
    float4 accA = make_float4(sw * va.x, sw * va.y, sw * va.z, sw * va.w);
    float4 accB = make_float4(sw * vb.x, sw * vb.y, sw * vb.z, sw * vb.w);
    int e0 = off[n], e1 = off[n + 1];
    for (int j = e0; j < e1; ++j) {
        int s = csr_src[j];
        float w = csr_w[j];
        const float4* srow = (const float4*)(hw + (size_t)s * 512);
        float4 ua = srow[lane];
        float4 ub = srow[64 + lane];
        accA.x = fmaf(w, ua.x, accA.x); accA.y = fmaf(w, ua.y, accA.y);
        accA.z = fmaf(w, ua.z, accA.z); accA.w = fmaf(w, ua.w, accA.w);
        accB.x = fmaf(w, ub.x, accB.x); accB.y = fmaf(w, ub.y, accB.y);
        accB.z = fmaf(w, ub.z, accB.z); accB.w = fmaf(w, ub.w, accB.w);
    }
    // bias: element flat idx f -> c = f & 63
    int c0 = (4 * lane) & 63;   // 4 consecutive elements share t; c = (4l+k)&63
    float4 outA, outB;
    outA.x = fmaxf(accA.x + b[c0 + 0], 0.f);
    outA.y = fmaxf(accA.y + b[c0 + 1], 0.f);
    outA.z = fmaxf(accA.z + b[c0 + 2], 0.f);
    outA.w = fmaxf(accA.w + b[c0 + 3], 0.f);
    outB.x = fmaxf(accB.x + b[c0 + 0], 0.f);
    outB.y = fmaxf(accB.y + b[c0 + 1], 0.f);
    outB.z = fmaxf(accB.z + b[c0 + 2], 0.f);
    outB.w = fmaxf(accB.w + b[c0 + 3], 0.f);
    float4* orow = (float4*)(hout + (size_t)n * 512);
    orow[lane] = outA;
    orow[64 + lane] = outB;
}

// pool over all (g,t): grid = B*T blocks; h layout [n][t][c], nodes per graph contiguous
__global__ void pool_all(const float* __restrict__ h, float* __restrict__ out, int accumulate) {
    int g = blockIdx.x >> 3;
    int t = blockIdx.x & 7;
    int c = threadIdx.x & 63;
    int r = threadIdx.x >> 6;
    float mx = -INFINITY, sm = 0.f;
    for (int n = r; n < NPG; n += 4) {
        float v = h[((size_t)(g * NPG + n) * 8 + t) * 64 + c];
        mx = fmaxf(mx, v);
        sm += v;
    }
    __shared__ float smx[4][COUT];
    __shared__ float ssm[4][COUT];
    smx[r][c] = mx;
    ssm[r][c] = sm;
    __syncthreads();
    if (r == 0) {
        #pragma unroll
        for (int i = 1; i < 4; ++i) {
            mx = fmaxf(mx, smx[i][c]);
            sm += ssm[i][c];
        }
        float mean = sm * (1.0f / NPG);
        size_t o = (size_t)g * (2 * COUT * TT) + (size_t)c * TT + t;
        if (accumulate) {
            out[o] += mx;
            out[o + COUT * TT] += mean;
        } else {
            out[o] = mx;
            out[o + COUT * TT] = mean;
        }
    }
}

// ============ FALLBACK PER-T PATH (round-1 kernels) ============

__global__ void agg_x(const float* x, const int* off, const int* csr_src,
                      const float* csr_w, const float* dinv, float* xa, int t) {
    int c = threadIdx.x & 31;
    int n = blockIdx.x * 8 + (threadIdx.x >> 5);
    float dn = dinv[n];
    float acc = dn * dn * x[(size_t)n * (CIN * TT) + c * TT + t];
    int e0 = off[n], e1 = off[n + 1];
    for (int j = e0; j < e1; ++j) {
        int s = csr_src[j];
        acc = fmaf(csr_w[j], x[(size_t)s * (CIN * TT) + c * TT + t], acc);
    }
    xa[n * CIN + c] = acc;
}

__global__ void mat32_relu(const float* xa, const float* W, const float* b, float* h) {
    __shared__ float Ws[CIN * COUT];
    __shared__ float Xs[4][CIN];
    for (int i = threadIdx.x; i < CIN * COUT; i += 256) Ws[i] = W[i];
    int co = threadIdx.x & 63;
    int nl = threadIdx.x >> 6;
    int n = blockIdx.x * 4 + nl;
    if (co < CIN) Xs[nl][co] = xa[n * CIN + co];
    __syncthreads();
    float acc = b[co];
    #pragma unroll
    for (int k = 0; k < CIN; ++k) acc = fmaf(Xs[nl][k], Ws[k * COUT + co], acc);
    h[(size_t)n * COUT + co] = fmaxf(acc, 0.f);
}

__global__ void mat64(const float* hin, const float* W, float* hw) {
    __shared__ float Ws[COUT * COUT];
    __shared__ float Xs[4][COUT];
    for (int i = threadIdx.x; i < COUT * COUT; i += 256) Ws[i] = W[i];
    int co = threadIdx.x & 63;
    int nl = threadIdx.x >> 6;
    int n = blockIdx.x * 4 + nl;
    Xs[nl][co] = hin[(size_t)n * COUT + co];
    __syncthreads();
    float acc = 0.f;
    #pragma unroll
    for (int k = 0; k < COUT; ++k) acc = fmaf(Xs[nl][k], Ws[k * COUT + co], acc);
    hw[(size_t)n * COUT + co] = acc;
}

__global__ void agg64_relu(const float* hw, const int* off, const int* csr_src,
                           const float* csr_w, const float* dinv, const float* b,
                           float* hout) {
    int c = threadIdx.x & 63;
    int n = blockIdx.x * 4 + (threadIdx.x >> 6);
    float dn = dinv[n];
    float acc = dn * dn * hw[(size_t)n * COUT + c];
    int e0 = off[n], e1 = off[n + 1];
    for (int j = e0; j < e1; ++j) {
        int s = csr_src[j];
        acc = fmaf(csr_w[j], hw[(size_t)s * COUT + c], acc);
    }
    hout[(size_t)n * COUT + c] = fmaxf(acc + b[c], 0.f);
}

__global__ void pool_acc(const float* h, float* out, int t, int accumulate) {
    int g = blockIdx.x;
    int c = threadIdx.x & 63;
    int r = threadIdx.x >> 6;
    const float* hp = h + (size_t)g * NPG * COUT;
    float mx = -INFINITY, sm = 0.f;
    for (int n = r; n < NPG; n += 4) {
        float v = hp[n * COUT + c];
        mx = fmaxf(mx, v);
        sm += v;
    }
    __shared__ float smx[4][COUT];
    __shared__ float ssm[4][COUT];
    smx[r][c] = mx;
    ssm[r][c] = sm;
    __syncthreads();
    if (r == 0) {
        #pragma unroll
        for (int i = 1; i < 4; ++i) {
            mx = fmaxf(mx, smx[i][c]);
            sm += ssm[i][c];
        }
        float mean = sm * (1.0f / NPG);
        size_t o = (size_t)g * (2 * COUT * TT) + (size_t)c * TT + t;
        if (accumulate) {
            out[o] += mx;
            out[o + COUT * TT] += mean;
        } else {
            out[o] = mx;
            out[o + COUT * TT] = mean;
        }
    }
}

// ---------------- launch ----------------

extern "C" void kernel_launch(void* const* d_in, const int* in_sizes, int n_in,
                              void* d_out, int out_size, void* d_ws, size_t ws_size,
                              hipStream_t stream) {
    const float* x   = (const float*)d_in[0];
    const int*   ei  = (const int*)d_in[1];
    const int*   src = ei;
    const int*   dst = ei + EE;
    const float* W1  = (const float*)d_in[3];
    const float* b1  = (const float*)d_in[4];
    const float* W2  = (const float*)d_in[5];
    const float* b2  = (const float*)d_in[6];
    const float* W3  = (const float*)d_in[7];
    const float* b3  = (const float*)d_in[8];
    float* out = (float*)d_out;

    char* wsp = (char*)d_ws;
    auto alloc = [&](size_t bytes) {
        char* p = wsp;
        wsp += (bytes + 255) & ~(size_t)255;
        return p;
    };
    int*   deg     = (int*)  alloc((size_t)NN * 4);
    int*   cursor  = (int*)  alloc((size_t)NN * 4);
    float* dinv    = (float*)alloc((size_t)NN * 4);
    int*   off     = (int*)  alloc((size_t)(NN + 1) * 4);
    int*   bsum    = (int*)  alloc((size_t)SCAN_B * 4);
    int*   csr_src = (int*)  alloc((size_t)EE * 4);
    float* csr_w   = (float*)alloc((size_t)EE * 4);

    // structure (time-invariant)
    init_deg<<<NBLK, 256, 0, stream>>>(deg, cursor);
    count_deg<<<(EE + 255) / 256, 256, 0, stream>>>(dst, deg);
    compute_dinv<<<NBLK, 256, 0, stream>>>(deg, dinv);
    scan_blocks<<<NBLK, SCAN_B, 0, stream>>>(deg, off, bsum);
    scan_sums<<<1, SCAN_B, 0, stream>>>(bsum, off);
    scan_add<<<NBLK, SCAN_B, 0, stream>>>(off, bsum);
    fill_csr<<<(EE + 255) / 256, 256, 0, stream>>>(src, dst, off, cursor, dinv,
                                                   csr_src, csr_w);

    size_t batched_need = (size_t)(NN * CIN * TT) * 4        // xa
                        + 3 * (size_t)(NN * COUT * TT) * 4   // hA, hw, hB
                        + (size_t)32 * 1024;
    size_t used = (size_t)(wsp - (char*)d_ws);

    if (ws_size >= used + batched_need) {
        // ===== batched-T path =====
        float* xa = (float*)alloc((size_t)NN * CIN * TT * 4);    // [n][t][c]
        float* hA = (float*)alloc((size_t)NN * COUT * TT * 4);
        float* hw = (float*)alloc((size_t)NN * COUT * TT * 4);
        float* hB = (float*)alloc((size_t)NN * COUT * TT * 4);

        const int RB = NN * TT / 4;   // blocks for 400k-row matmuls

        agg_x_all<<<NN / 4, 256, 0, stream>>>(x, off, csr_src, csr_w, dinv, xa);
        mat32_relu_all<<<RB, 256, 0, stream>>>(xa, W1, b1, hA);
        pool_all<<<BB * TT, 256, 0, stream>>>(hA, out, 0);

        mat64_all<<<RB, 256, 0, stream>>>(hA, W2, hw);
        agg64_relu_all<<<NN / 4, 256, 0, stream>>>(hw, off, csr_src, csr_w, dinv, b2, hB);
        pool_all<<<BB * TT, 256, 0, stream>>>(hB, out, 1);

        mat64_all<<<RB, 256, 0, stream>>>(hB, W3, hw);
        agg64_relu_all<<<NN / 4, 256, 0, stream>>>(hw, off, csr_src, csr_w, dinv, b3, hA);
        pool_all<<<BB * TT, 256, 0, stream>>>(hA, out, 1);
    } else {
        // ===== fallback per-t path =====
        float* xa = (float*)alloc((size_t)NN * CIN * 4);
        float* hA = (float*)alloc((size_t)NN * COUT * 4);
        float* hB = (float*)alloc((size_t)NN * COUT * 4);
        float* hw = (float*)alloc((size_t)NN * COUT * 4);
        for (int t = 0; t < TT; ++t) {
            agg_x<<<NN / 8, 256, 0, stream>>>(x, off, csr_src, csr_w, dinv, xa, t);
            mat32_relu<<<NN / 4, 256, 0, stream>>>(xa, W1, b1, hA);
            pool_acc<<<BB, 256, 0, stream>>>(hA, out, t, 0);
            mat64<<<NN / 4, 256, 0, stream>>>(hA, W2, hw);
            agg64_relu<<<NN / 4, 256, 0, stream>>>(hw, off, csr_src, csr_w, dinv, b2, hB);
            pool_acc<<<BB, 256, 0, stream>>>(hB, out, t, 1);
            mat64<<<NN / 4, 256, 0, stream>>>(hB, W3, hw);
            agg64_relu<<<NN / 4, 256, 0, stream>>>(hw, off, csr_src, csr_w, dinv, b3, hA);
            pool_acc<<<BB, 256, 0, stream>>>(hA, out, t, 1);
        }
    }
}

// Round 3
// 1855.841 us; speedup vs baseline: 1.7569x; 1.7530x over previous
//
#include <hip/hip_runtime.h>
#include <math.h>

#define NN 50000
#define EE 800000
#define BB 250
#define TT 8
#define CIN 32
#define COUT 64
#define NPG 200          // nodes per graph (N/B)
#define SCAN_B 256
#define NBLK 196         // ceil(50000/256)

// ---------------- setup kernels (graph structure, once per call) ----------------

__global__ void init_deg(int* deg, int* cursor) {
    int n = blockIdx.x * 256 + threadIdx.x;
    if (n < NN) { deg[n] = 1; cursor[n] = 0; }   // self-loop contributes 1
}

__global__ void count_deg(const int* dst, int* deg) {
    int e = blockIdx.x * 256 + threadIdx.x;
    if (e < EE) atomicAdd(&deg[dst[e]], 1);
}

__global__ void compute_dinv(const int* deg, float* dinv) {
    int n = blockIdx.x * 256 + threadIdx.x;
    if (n < NN) dinv[n] = rsqrtf((float)deg[n]);
}

// exclusive scan of indeg (= deg-1) over N elements, 3-phase
__global__ void scan_blocks(const int* deg, int* off, int* bsum) {
    __shared__ int sh[SCAN_B];
    int gid = blockIdx.x * SCAN_B + threadIdx.x;
    int v = (gid < NN) ? (deg[gid] - 1) : 0;
    sh[threadIdx.x] = v;
    __syncthreads();
    for (int s = 1; s < SCAN_B; s <<= 1) {
        int add = (threadIdx.x >= s) ? sh[threadIdx.x - s] : 0;
        __syncthreads();
        sh[threadIdx.x] += add;
        __syncthreads();
    }
    if (gid < NN) off[gid] = sh[threadIdx.x] - v;       // exclusive
    if (threadIdx.x == SCAN_B - 1) bsum[blockIdx.x] = sh[threadIdx.x];
}

__global__ void scan_sums(int* bsum, int* off) {
    __shared__ int sh[SCAN_B];
    int v = (threadIdx.x < NBLK) ? bsum[threadIdx.x] : 0;
    sh[threadIdx.x] = v;
    __syncthreads();
    for (int s = 1; s < SCAN_B; s <<= 1) {
        int add = (threadIdx.x >= s) ? sh[threadIdx.x - s] : 0;
        __syncthreads();
        sh[threadIdx.x] += add;
        __syncthreads();
    }
    if (threadIdx.x < NBLK) bsum[threadIdx.x] = sh[threadIdx.x] - v;  // exclusive
    if (threadIdx.x == 0) off[NN] = EE;
}

__global__ void scan_add(int* off, const int* bsum) {
    int gid = blockIdx.x * SCAN_B + threadIdx.x;
    if (gid < NN) off[gid] += bsum[blockIdx.x];
}

__global__ void fill_csr(const int* src, const int* dst, const int* off,
                         int* cursor, const float* dinv, int* csr_src, float* csr_w) {
    int e = blockIdx.x * 256 + threadIdx.x;
    if (e >= EE) return;
    int s = src[e], d = dst[e];
    int p = atomicAdd(&cursor[d], 1);
    int pos = off[d] + p;
    csr_src[pos] = s;
    csr_w[pos] = dinv[s] * dinv[d];
}

// ---------------- compute kernels ----------------

// Aggregate x over full contiguous 1KB node rows (all 8 t at once per row), but
// only WRITE t-slices [t0, t0+Tc) into xaT laid out [tc][n][c] (tc = t - t0).
// One wave per node; lane l holds float4 = row elements [4l, 4l+4).
__global__ void agg_x_allT(const float* __restrict__ x, const int* __restrict__ off,
                           const int* __restrict__ csr_src, const float* __restrict__ csr_w,
                           const float* __restrict__ dinv, float* __restrict__ xaT,
                           int t0, int Tc) {
    int lane = threadIdx.x & 63;
    int n = blockIdx.x * 4 + (threadIdx.x >> 6);
    float dn = dinv[n];
    float sw = dn * dn;
    float4 v = ((const float4*)(x + (size_t)n * 256))[lane];
    float4 acc = make_float4(sw * v.x, sw * v.y, sw * v.z, sw * v.w);
    int e0 = off[n], e1 = off[n + 1];
    int j = e0;
    for (; j + 1 < e1; j += 2) {
        int s0 = csr_src[j], s1 = csr_src[j + 1];
        float w0 = csr_w[j], w1 = csr_w[j + 1];
        float4 u0 = ((const float4*)(x + (size_t)s0 * 256))[lane];
        float4 u1 = ((const float4*)(x + (size_t)s1 * 256))[lane];
        acc.x = fmaf(w0, u0.x, acc.x); acc.y = fmaf(w0, u0.y, acc.y);
        acc.z = fmaf(w0, u0.z, acc.z); acc.w = fmaf(w0, u0.w, acc.w);
        acc.x = fmaf(w1, u1.x, acc.x); acc.y = fmaf(w1, u1.y, acc.y);
        acc.z = fmaf(w1, u1.z, acc.z); acc.w = fmaf(w1, u1.w, acc.w);
    }
    if (j < e1) {
        int s = csr_src[j];
        float w = csr_w[j];
        float4 u = ((const float4*)(x + (size_t)s * 256))[lane];
        acc.x = fmaf(w, u.x, acc.x); acc.y = fmaf(w, u.y, acc.y);
        acc.z = fmaf(w, u.z, acc.z); acc.w = fmaf(w, u.w, acc.w);
    }
    // element flat idx f = 4*lane+k maps to (c = f>>3, t = f&7)
    float av[4] = {acc.x, acc.y, acc.z, acc.w};
    #pragma unroll
    for (int k = 0; k < 4; ++k) {
        int f = 4 * lane + k;
        int tt = f & 7;
        int tc = tt - t0;
        if (tc >= 0 && tc < Tc)
            xaT[(size_t)tc * (NN * CIN) + n * CIN + (f >> 3)] = av[k];
    }
}

// h[n][co] = relu(xa[n][:] @ W1 + b1); block = 4 nodes x 64 outch
__global__ void mat32_relu(const float* __restrict__ xa, const float* __restrict__ W,
                           const float* __restrict__ b, float* __restrict__ h) {
    __shared__ float Ws[CIN * COUT];
    __shared__ float Xs[4][CIN];
    for (int i = threadIdx.x; i < CIN * COUT; i += 256) Ws[i] = W[i];
    int co = threadIdx.x & 63;
    int nl = threadIdx.x >> 6;
    int n = blockIdx.x * 4 + nl;
    if (co < CIN) Xs[nl][co] = xa[(size_t)n * CIN + co];
    __syncthreads();
    float acc = b[co];
    #pragma unroll
    for (int k = 0; k < CIN; ++k) acc = fmaf(Xs[nl][k], Ws[k * COUT + co], acc);
    h[(size_t)n * COUT + co] = fmaxf(acc, 0.f);
}

// hw[n][co] = h[n][:] @ W
__global__ void mat64(const float* __restrict__ hin, const float* __restrict__ W,
                      float* __restrict__ hw) {
    __shared__ float Ws[COUT * COUT];
    __shared__ float Xs[4][COUT];
    for (int i = threadIdx.x; i < COUT * COUT; i += 256) Ws[i] = W[i];
    int co = threadIdx.x & 63;
    int nl = threadIdx.x >> 6;
    int n = blockIdx.x * 4 + nl;
    Xs[nl][co] = hin[(size_t)n * COUT + co];
    __syncthreads();
    float acc = 0.f;
    #pragma unroll
    for (int k = 0; k < COUT; ++k) acc = fmaf(Xs[nl][k], Ws[k * COUT + co], acc);
    hw[(size_t)n * COUT + co] = acc;
}

// hout[n][c] = relu(sum_e w_e*hw[s][c] + dinv^2*hw[n][c] + b[c]); wave per node,
// 4x unrolled gather for memory-level parallelism.
__global__ void agg64_relu(const float* __restrict__ hw, const int* __restrict__ off,
                           const int* __restrict__ csr_src, const float* __restrict__ csr_w,
                           const float* __restrict__ dinv, const float* __restrict__ b,
                           float* __restrict__ hout) {
    int c = threadIdx.x & 63;
    int n = blockIdx.x * 4 + (threadIdx.x >> 6);
    float dn = dinv[n];
    float acc = dn * dn * hw[(size_t)n * COUT + c];
    int e0 = off[n], e1 = off[n + 1];
    int j = e0;
    for (; j + 3 < e1; j += 4) {
        int s0 = csr_src[j],     s1 = csr_src[j + 1];
        int s2 = csr_src[j + 2], s3 = csr_src[j + 3];
        float w0 = csr_w[j],     w1 = csr_w[j + 1];
        float w2 = csr_w[j + 2], w3 = csr_w[j + 3];
        float v0 = hw[(size_t)s0 * COUT + c];
        float v1 = hw[(size_t)s1 * COUT + c];
        float v2 = hw[(size_t)s2 * COUT + c];
        float v3 = hw[(size_t)s3 * COUT + c];
        acc = fmaf(w0, v0, acc);
        acc = fmaf(w1, v1, acc);
        acc = fmaf(w2, v2, acc);
        acc = fmaf(w3, v3, acc);
    }
    for (; j < e1; ++j) {
        int s = csr_src[j];
        acc = fmaf(csr_w[j], hw[(size_t)s * COUT + c], acc);
    }
    hout[(size_t)n * COUT + c] = fmaxf(acc + b[c], 0.f);
}

// pool h ([N][64] for one t) into out[g, :, t]; accumulate==0 -> write, else +=
__global__ void pool_acc(const float* __restrict__ h, float* __restrict__ out,
                         int t, int accumulate) {
    int g = blockIdx.x;
    int c = threadIdx.x & 63;
    int r = threadIdx.x >> 6;
    const float* hp = h + (size_t)g * NPG * COUT;
    float mx = -INFINITY, sm = 0.f;
    for (int n = r; n < NPG; n += 4) {
        float v = hp[n * COUT + c];
        mx = fmaxf(mx, v);
        sm += v;
    }
    __shared__ float smx[4][COUT];
    __shared__ float ssm[4][COUT];
    smx[r][c] = mx;
    ssm[r][c] = sm;
    __syncthreads();
    if (r == 0) {
        #pragma unroll
        for (int i = 1; i < 4; ++i) {
            mx = fmaxf(mx, smx[i][c]);
            sm += ssm[i][c];
        }
        float mean = sm * (1.0f / NPG);
        size_t o = (size_t)g * (2 * COUT * TT) + (size_t)c * TT + t;
        if (accumulate) {
            out[o] += mx;
            out[o + COUT * TT] += mean;
        } else {
            out[o] = mx;
            out[o + COUT * TT] = mean;
        }
    }
}

// ---------------- launch ----------------

extern "C" void kernel_launch(void* const* d_in, const int* in_sizes, int n_in,
                              void* d_out, int out_size, void* d_ws, size_t ws_size,
                              hipStream_t stream) {
    const float* x   = (const float*)d_in[0];
    const int*   ei  = (const int*)d_in[1];
    const int*   src = ei;
    const int*   dst = ei + EE;
    const float* W1  = (const float*)d_in[3];
    const float* b1  = (const float*)d_in[4];
    const float* W2  = (const float*)d_in[5];
    const float* b2  = (const float*)d_in[6];
    const float* W3  = (const float*)d_in[7];
    const float* b3  = (const float*)d_in[8];
    float* out = (float*)d_out;

    char* wsp = (char*)d_ws;
    auto alloc = [&](size_t bytes) {
        char* p = wsp;
        wsp += (bytes + 255) & ~(size_t)255;
        return p;
    };
    int*   deg     = (int*)  alloc((size_t)NN * 4);
    int*   cursor  = (int*)  alloc((size_t)NN * 4);
    float* dinv    = (float*)alloc((size_t)NN * 4);
    int*   off     = (int*)  alloc((size_t)(NN + 1) * 4);
    int*   bsum    = (int*)  alloc((size_t)SCAN_B * 4);
    int*   csr_src = (int*)  alloc((size_t)EE * 4);
    float* csr_w   = (float*)alloc((size_t)EE * 4);

    // structure (time-invariant)
    init_deg<<<NBLK, 256, 0, stream>>>(deg, cursor);
    count_deg<<<(EE + 255) / 256, 256, 0, stream>>>(dst, deg);
    compute_dinv<<<NBLK, 256, 0, stream>>>(deg, dinv);
    scan_blocks<<<NBLK, SCAN_B, 0, stream>>>(deg, off, bsum);
    scan_sums<<<1, SCAN_B, 0, stream>>>(bsum, off);
    scan_add<<<NBLK, SCAN_B, 0, stream>>>(off, bsum);
    fill_csr<<<(EE + 255) / 256, 256, 0, stream>>>(src, dst, off, cursor, dinv,
                                                   csr_src, csr_w);

    // pick largest x-agg chunk Tc that fits: xaT (Tc slices) + hA + hw + hB
    size_t used = (size_t)(wsp - (char*)d_ws);
    size_t hbytes = (size_t)NN * COUT * 4;          // 12.8 MB
    size_t slice  = (size_t)NN * CIN * 4;           // 6.4 MB
    int Tc = 1;
    for (int cand = 8; cand >= 1; cand >>= 1) {
        if (ws_size >= used + (size_t)cand * slice + 3 * hbytes + (1u << 16)) { Tc = cand; break; }
    }

    float* xaT = (float*)alloc((size_t)Tc * slice);
    float* hA  = (float*)alloc(hbytes);
    float* hw  = (float*)alloc(hbytes);
    float* hB  = (float*)alloc(hbytes);

    for (int t0 = 0; t0 < TT; t0 += Tc) {
        agg_x_allT<<<NN / 4, 256, 0, stream>>>(x, off, csr_src, csr_w, dinv, xaT, t0, Tc);
        for (int tc = 0; tc < Tc; ++tc) {
            int t = t0 + tc;
            const float* xat = xaT + (size_t)tc * NN * CIN;
            mat32_relu<<<NN / 4, 256, 0, stream>>>(xat, W1, b1, hA);
            pool_acc<<<BB, 256, 0, stream>>>(hA, out, t, 0);
            mat64<<<NN / 4, 256, 0, stream>>>(hA, W2, hw);
            agg64_relu<<<NN / 4, 256, 0, stream>>>(hw, off, csr_src, csr_w, dinv, b2, hB);
            pool_acc<<<BB, 256, 0, stream>>>(hB, out, t, 1);
            mat64<<<NN / 4, 256, 0, stream>>>(hB, W3, hw);
            agg64_relu<<<NN / 4, 256, 0, stream>>>(hw, off, csr_src, csr_w, dinv, b3, hA);
            pool_acc<<<BB, 256, 0, stream>>>(hA, out, t, 1);
        }
    }
}

// Round 4
// 1800.877 us; speedup vs baseline: 1.8106x; 1.0305x over previous
//
#include <hip/hip_runtime.h>
#include <hip/hip_fp16.h>
#include <math.h>

#define NN 50000
#define EE 800000
#define BB 250
#define TT 8
#define CIN 32
#define COUT 64
#define NPG 200          // nodes per graph (N/B)
#define SCAN_B 256
#define NBLK 196         // ceil(50000/256)

// ---------------- setup kernels (graph structure, once per call) ----------------

__global__ void init_deg(int* deg, int* cursor) {
    int n = blockIdx.x * 256 + threadIdx.x;
    if (n < NN) { deg[n] = 1; cursor[n] = 0; }   // self-loop contributes 1
}

__global__ void count_deg(const int* dst, int* deg) {
    int e = blockIdx.x * 256 + threadIdx.x;
    if (e < EE) atomicAdd(&deg[dst[e]], 1);
}

__global__ void compute_dinv(const int* deg, float* dinv) {
    int n = blockIdx.x * 256 + threadIdx.x;
    if (n < NN) dinv[n] = rsqrtf((float)deg[n]);
}

// exclusive scan of indeg (= deg-1) over N elements, 3-phase
__global__ void scan_blocks(const int* deg, int* off, int* bsum) {
    __shared__ int sh[SCAN_B];
    int gid = blockIdx.x * SCAN_B + threadIdx.x;
    int v = (gid < NN) ? (deg[gid] - 1) : 0;
    sh[threadIdx.x] = v;
    __syncthreads();
    for (int s = 1; s < SCAN_B; s <<= 1) {
        int add = (threadIdx.x >= s) ? sh[threadIdx.x - s] : 0;
        __syncthreads();
        sh[threadIdx.x] += add;
        __syncthreads();
    }
    if (gid < NN) off[gid] = sh[threadIdx.x] - v;       // exclusive
    if (threadIdx.x == SCAN_B - 1) bsum[blockIdx.x] = sh[threadIdx.x];
}

__global__ void scan_sums(int* bsum, int* off) {
    __shared__ int sh[SCAN_B];
    int v = (threadIdx.x < NBLK) ? bsum[threadIdx.x] : 0;
    sh[threadIdx.x] = v;
    __syncthreads();
    for (int s = 1; s < SCAN_B; s <<= 1) {
        int add = (threadIdx.x >= s) ? sh[threadIdx.x - s] : 0;
        __syncthreads();
        sh[threadIdx.x] += add;
        __syncthreads();
    }
    if (threadIdx.x < NBLK) bsum[threadIdx.x] = sh[threadIdx.x] - v;  // exclusive
    if (threadIdx.x == 0) off[NN] = EE;
}

__global__ void scan_add(int* off, const int* bsum) {
    int gid = blockIdx.x * SCAN_B + threadIdx.x;
    if (gid < NN) off[gid] += bsum[blockIdx.x];
}

__global__ void fill_csr(const int* src, const int* dst, const int* off,
                         int* cursor, const float* dinv, int* csr_src, float* csr_w) {
    int e = blockIdx.x * 256 + threadIdx.x;
    if (e >= EE) return;
    int s = src[e], d = dst[e];
    int p = atomicAdd(&cursor[d], 1);
    int pos = off[d] + p;
    csr_src[pos] = s;
    csr_w[pos] = dinv[s] * dinv[d];
}

// ---------------- compute kernels ----------------

// ONE pass: xaT[t][n][c] (fp16) = sum_e w_e * x[src][c][t] + dinv^2 * x[n][c][t], all t.
// One wave per node; lane l holds float4 = contiguous row elements [4l,4l+4).
// LDS transpose (padded, bank-conflict-free) -> coalesced fp16 slice writes.
__global__ void agg_x_allT(const float* __restrict__ x, const int* __restrict__ off,
                           const int* __restrict__ csr_src, const float* __restrict__ csr_w,
                           const float* __restrict__ dinv, __half* __restrict__ xaT) {
    int lane = threadIdx.x & 63;
    int w = threadIdx.x >> 6;
    int n = blockIdx.x * 4 + w;
    float dn = dinv[n];
    float sw = dn * dn;
    float4 v = ((const float4*)(x + (size_t)n * 256))[lane];
    float4 acc = make_float4(sw * v.x, sw * v.y, sw * v.z, sw * v.w);
    int e0 = off[n], e1 = off[n + 1];
    int j = e0;
    for (; j + 3 < e1; j += 4) {
        int s0 = csr_src[j],     s1 = csr_src[j + 1];
        int s2 = csr_src[j + 2], s3 = csr_src[j + 3];
        float w0 = csr_w[j],     w1 = csr_w[j + 1];
        float w2 = csr_w[j + 2], w3 = csr_w[j + 3];
        float4 u0 = ((const float4*)(x + (size_t)s0 * 256))[lane];
        float4 u1 = ((const float4*)(x + (size_t)s1 * 256))[lane];
        float4 u2 = ((const float4*)(x + (size_t)s2 * 256))[lane];
        float4 u3 = ((const float4*)(x + (size_t)s3 * 256))[lane];
        acc.x = fmaf(w0, u0.x, acc.x); acc.y = fmaf(w0, u0.y, acc.y);
        acc.z = fmaf(w0, u0.z, acc.z); acc.w = fmaf(w0, u0.w, acc.w);
        acc.x = fmaf(w1, u1.x, acc.x); acc.y = fmaf(w1, u1.y, acc.y);
        acc.z = fmaf(w1, u1.z, acc.z); acc.w = fmaf(w1, u1.w, acc.w);
        acc.x = fmaf(w2, u2.x, acc.x); acc.y = fmaf(w2, u2.y, acc.y);
        acc.z = fmaf(w2, u2.z, acc.z); acc.w = fmaf(w2, u2.w, acc.w);
        acc.x = fmaf(w3, u3.x, acc.x); acc.y = fmaf(w3, u3.y, acc.y);
        acc.z = fmaf(w3, u3.z, acc.z); acc.w = fmaf(w3, u3.w, acc.w);
    }
    for (; j < e1; ++j) {
        int s = csr_src[j];
        float wj = csr_w[j];
        float4 u = ((const float4*)(x + (size_t)s * 256))[lane];
        acc.x = fmaf(wj, u.x, acc.x); acc.y = fmaf(wj, u.y, acc.y);
        acc.z = fmaf(wj, u.z, acc.z); acc.w = fmaf(wj, u.w, acc.w);
    }
    // element flat idx f = 4*lane+k -> (c = f>>3, t = f&7)
    __shared__ float sh[4][TT][33];   // padded: bank = (t + c) % 32 -> 2-way max (free)
    float av[4] = {acc.x, acc.y, acc.z, acc.w};
    #pragma unroll
    for (int k = 0; k < 4; ++k) {
        int f = 4 * lane + k;
        sh[w][f & 7][f >> 3] = av[k];
    }
    __syncthreads();
    // 8t x 4nodes x 32c = 1024 halves; 256B-contiguous per (t, 4-node) group
    for (int i = threadIdx.x; i < 1024; i += 256) {
        int t = i >> 7;
        int r = i & 127;
        int nl = r >> 5;
        int c = r & 31;
        xaT[((size_t)t * NN + blockIdx.x * 4 + nl) * CIN + c] = __float2half(sh[nl][t][c]);
    }
}

// h[n][co] = relu(xa_t[n][:] @ W1 + b1); xa fp16; block = 4 nodes x 64 outch
__global__ void mat32_relu(const __half* __restrict__ xa, const float* __restrict__ W,
                           const float* __restrict__ b, float* __restrict__ h) {
    __shared__ float Ws[CIN * COUT];
    __shared__ float Xs[4][CIN];
    for (int i = threadIdx.x; i < CIN * COUT; i += 256) Ws[i] = W[i];
    int co = threadIdx.x & 63;
    int nl = threadIdx.x >> 6;
    int n = blockIdx.x * 4 + nl;
    if (co < CIN) Xs[nl][co] = __half2float(xa[(size_t)n * CIN + co]);
    __syncthreads();
    float acc = b[co];
    #pragma unroll
    for (int k = 0; k < CIN; ++k) acc = fmaf(Xs[nl][k], Ws[k * COUT + co], acc);
    h[(size_t)n * COUT + co] = fmaxf(acc, 0.f);
}

// hw[n][co] (fp16) = h[n][:] @ W
__global__ void mat64_f16(const float* __restrict__ hin, const float* __restrict__ W,
                          __half* __restrict__ hw) {
    __shared__ float Ws[COUT * COUT];
    __shared__ float Xs[4][COUT];
    for (int i = threadIdx.x; i < COUT * COUT; i += 256) Ws[i] = W[i];
    int co = threadIdx.x & 63;
    int nl = threadIdx.x >> 6;
    int n = blockIdx.x * 4 + nl;
    Xs[nl][co] = hin[(size_t)n * COUT + co];
    __syncthreads();
    float acc = 0.f;
    #pragma unroll
    for (int k = 0; k < COUT; ++k) acc = fmaf(Xs[nl][k], Ws[k * COUT + co], acc);
    hw[(size_t)n * COUT + co] = __float2half(acc);
}

// hout[n][c] = relu(sum_e w_e*hw[s][c] + dinv^2*hw[n][c] + b[c]); fp16 gather,
// fp32 accumulate; wave per node; 4x unrolled gather for MLP.
__global__ void agg64_relu(const __half* __restrict__ hw, const int* __restrict__ off,
                           const int* __restrict__ csr_src, const float* __restrict__ csr_w,
                           const float* __restrict__ dinv, const float* __restrict__ b,
                           float* __restrict__ hout) {
    int c = threadIdx.x & 63;
    int n = blockIdx.x * 4 + (threadIdx.x >> 6);
    float dn = dinv[n];
    float acc = dn * dn * __half2float(hw[(size_t)n * COUT + c]);
    int e0 = off[n], e1 = off[n + 1];
    int j = e0;
    for (; j + 3 < e1; j += 4) {
        int s0 = csr_src[j],     s1 = csr_src[j + 1];
        int s2 = csr_src[j + 2], s3 = csr_src[j + 3];
        float w0 = csr_w[j],     w1 = csr_w[j + 1];
        float w2 = csr_w[j + 2], w3 = csr_w[j + 3];
        float v0 = __half2float(hw[(size_t)s0 * COUT + c]);
        float v1 = __half2float(hw[(size_t)s1 * COUT + c]);
        float v2 = __half2float(hw[(size_t)s2 * COUT + c]);
        float v3 = __half2float(hw[(size_t)s3 * COUT + c]);
        acc = fmaf(w0, v0, acc);
        acc = fmaf(w1, v1, acc);
        acc = fmaf(w2, v2, acc);
        acc = fmaf(w3, v3, acc);
    }
    for (; j < e1; ++j) {
        int s = csr_src[j];
        acc = fmaf(csr_w[j], __half2float(hw[(size_t)s * COUT + c]), acc);
    }
    hout[(size_t)n * COUT + c] = fmaxf(acc + b[c], 0.f);
}

// pool h ([N][64] for one t) into out[g, :, t]; accumulate==0 -> write, else +=
__global__ void pool_acc(const float* __restrict__ h, float* __restrict__ out,
                         int t, int accumulate) {
    int g = blockIdx.x;
    int c = threadIdx.x & 63;
    int r = threadIdx.x >> 6;
    const float* hp = h + (size_t)g * NPG * COUT;
    float mx = -INFINITY, sm = 0.f;
    for (int n = r; n < NPG; n += 4) {
        float v = hp[n * COUT + c];
        mx = fmaxf(mx, v);
        sm += v;
    }
    __shared__ float smx[4][COUT];
    __shared__ float ssm[4][COUT];
    smx[r][c] = mx;
    ssm[r][c] = sm;
    __syncthreads();
    if (r == 0) {
        #pragma unroll
        for (int i = 1; i < 4; ++i) {
            mx = fmaxf(mx, smx[i][c]);
            sm += ssm[i][c];
        }
        float mean = sm * (1.0f / NPG);
        size_t o = (size_t)g * (2 * COUT * TT) + (size_t)c * TT + t;
        if (accumulate) {
            out[o] += mx;
            out[o + COUT * TT] += mean;
        } else {
            out[o] = mx;
            out[o + COUT * TT] = mean;
        }
    }
}

// ---------------- launch ----------------

extern "C" void kernel_launch(void* const* d_in, const int* in_sizes, int n_in,
                              void* d_out, int out_size, void* d_ws, size_t ws_size,
                              hipStream_t stream) {
    const float* x   = (const float*)d_in[0];
    const int*   ei  = (const int*)d_in[1];
    const int*   src = ei;
    const int*   dst = ei + EE;
    const float* W1  = (const float*)d_in[3];
    const float* b1  = (const float*)d_in[4];
    const float* W2  = (const float*)d_in[5];
    const float* b2  = (const float*)d_in[6];
    const float* W3  = (const float*)d_in[7];
    const float* b3  = (const float*)d_in[8];
    float* out = (float*)d_out;

    char* wsp = (char*)d_ws;
    auto alloc = [&](size_t bytes) {
        char* p = wsp;
        wsp += (bytes + 255) & ~(size_t)255;
        return p;
    };
    // persistent (6.8 MB) + xaT (25.6) + hA (12.8) + hwh (6.4) = 51.6 MB
    // (known floor: ws_size >= 52.07 MB from round-3 tier probe)
    float*  dinv    = (float*) alloc((size_t)NN * 4);
    int*    off     = (int*)   alloc((size_t)(NN + 1) * 4);
    int*    csr_src = (int*)   alloc((size_t)EE * 4);
    float*  csr_w   = (float*) alloc((size_t)EE * 4);
    __half* xaT     = (__half*)alloc((size_t)NN * CIN * TT * 2);   // [t][n][c]
    float*  hA      = (float*) alloc((size_t)NN * COUT * 4);
    __half* hwh     = (__half*)alloc((size_t)NN * COUT * 2);

    // setup-only buffers aliased into hA (dead before hA's first write)
    int* deg    = (int*)hA;
    int* cursor = (int*)(hA + NN);
    int* bsum   = (int*)(hA + 2 * NN);

    // structure (time-invariant)
    init_deg<<<NBLK, 256, 0, stream>>>(deg, cursor);
    count_deg<<<(EE + 255) / 256, 256, 0, stream>>>(dst, deg);
    compute_dinv<<<NBLK, 256, 0, stream>>>(deg, dinv);
    scan_blocks<<<NBLK, SCAN_B, 0, stream>>>(deg, off, bsum);
    scan_sums<<<1, SCAN_B, 0, stream>>>(bsum, off);
    scan_add<<<NBLK, SCAN_B, 0, stream>>>(off, bsum);
    fill_csr<<<(EE + 255) / 256, 256, 0, stream>>>(src, dst, off, cursor, dinv,
                                                   csr_src, csr_w);

    // x aggregation for ALL t in one pass
    agg_x_allT<<<NN / 4, 256, 0, stream>>>(x, off, csr_src, csr_w, dinv, xaT);

    for (int t = 0; t < TT; ++t) {
        const __half* xat = xaT + (size_t)t * NN * CIN;
        mat32_relu<<<NN / 4, 256, 0, stream>>>(xat, W1, b1, hA);       // h1
        pool_acc<<<BB, 256, 0, stream>>>(hA, out, t, 0);
        mat64_f16<<<NN / 4, 256, 0, stream>>>(hA, W2, hwh);
        agg64_relu<<<NN / 4, 256, 0, stream>>>(hwh, off, csr_src, csr_w, dinv, b2, hA);  // h2
        pool_acc<<<BB, 256, 0, stream>>>(hA, out, t, 1);
        mat64_f16<<<NN / 4, 256, 0, stream>>>(hA, W3, hwh);
        agg64_relu<<<NN / 4, 256, 0, stream>>>(hwh, off, csr_src, csr_w, dinv, b3, hA);  // h3
        pool_acc<<<BB, 256, 0, stream>>>(hA, out, t, 1);
    }
}

// Round 5
// 1681.687 us; speedup vs baseline: 1.9389x; 1.0709x over previous
//
#include <hip/hip_runtime.h>
#include <hip/hip_fp16.h>
#include <math.h>

#define NN 50000
#define EE 800000
#define BB 250
#define TT 8
#define CIN 32
#define COUT 64
#define NPG 200          // nodes per graph (N/B)
#define SCAN_B 256
#define NBLK 196         // ceil(50000/256)

// ---------------- setup kernels (graph structure, once per call) ----------------

__global__ void init_deg(int* deg, int* cursor) {
    int n = blockIdx.x * 256 + threadIdx.x;
    if (n < NN) { deg[n] = 1; cursor[n] = 0; }   // self-loop contributes 1
}

__global__ void count_deg(const int* dst, int* deg) {
    int e = blockIdx.x * 256 + threadIdx.x;
    if (e < EE) atomicAdd(&deg[dst[e]], 1);
}

__global__ void compute_dinv(const int* deg, float* dinv) {
    int n = blockIdx.x * 256 + threadIdx.x;
    if (n < NN) dinv[n] = rsqrtf((float)deg[n]);
}

// exclusive scan of indeg (= deg-1) over N elements, 3-phase
__global__ void scan_blocks(const int* deg, int* off, int* bsum) {
    __shared__ int sh[SCAN_B];
    int gid = blockIdx.x * SCAN_B + threadIdx.x;
    int v = (gid < NN) ? (deg[gid] - 1) : 0;
    sh[threadIdx.x] = v;
    __syncthreads();
    for (int s = 1; s < SCAN_B; s <<= 1) {
        int add = (threadIdx.x >= s) ? sh[threadIdx.x - s] : 0;
        __syncthreads();
        sh[threadIdx.x] += add;
        __syncthreads();
    }
    if (gid < NN) off[gid] = sh[threadIdx.x] - v;       // exclusive
    if (threadIdx.x == SCAN_B - 1) bsum[blockIdx.x] = sh[threadIdx.x];
}

__global__ void scan_sums(int* bsum, int* off) {
    __shared__ int sh[SCAN_B];
    int v = (threadIdx.x < NBLK) ? bsum[threadIdx.x] : 0;
    sh[threadIdx.x] = v;
    __syncthreads();
    for (int s = 1; s < SCAN_B; s <<= 1) {
        int add = (threadIdx.x >= s) ? sh[threadIdx.x - s] : 0;
        __syncthreads();
        sh[threadIdx.x] += add;
        __syncthreads();
    }
    if (threadIdx.x < NBLK) bsum[threadIdx.x] = sh[threadIdx.x] - v;  // exclusive
    if (threadIdx.x == 0) off[NN] = EE;
}

__global__ void scan_add(int* off, const int* bsum) {
    int gid = blockIdx.x * SCAN_B + threadIdx.x;
    if (gid < NN) off[gid] += bsum[blockIdx.x];
}

__global__ void fill_csr(const int* src, const int* dst, const int* off,
                         int* cursor, const float* dinv, int* csr_src, float* csr_w) {
    int e = blockIdx.x * 256 + threadIdx.x;
    if (e >= EE) return;
    int s = src[e], d = dst[e];
    int p = atomicAdd(&cursor[d], 1);
    int pos = off[d] + p;
    csr_src[pos] = s;
    csr_w[pos] = dinv[s] * dinv[d];
}

// ---------------- compute kernels ----------------

// ONE pass: xaT[t][n][c] (fp16) = sum_e w_e * x[src][c][t] + dinv^2 * x[n][c][t], all t.
// One wave per node; lane l holds float4 = contiguous row elements [4l,4l+4).
__global__ void agg_x_allT(const float* __restrict__ x, const int* __restrict__ off,
                           const int* __restrict__ csr_src, const float* __restrict__ csr_w,
                           const float* __restrict__ dinv, __half* __restrict__ xaT) {
    int lane = threadIdx.x & 63;
    int w = threadIdx.x >> 6;
    int n = blockIdx.x * 4 + w;
    float dn = dinv[n];
    float sw = dn * dn;
    float4 v = ((const float4*)(x + (size_t)n * 256))[lane];
    float4 acc = make_float4(sw * v.x, sw * v.y, sw * v.z, sw * v.w);
    int e0 = off[n], e1 = off[n + 1];
    int j = e0;
    for (; j + 3 < e1; j += 4) {
        int s0 = csr_src[j],     s1 = csr_src[j + 1];
        int s2 = csr_src[j + 2], s3 = csr_src[j + 3];
        float w0 = csr_w[j],     w1 = csr_w[j + 1];
        float w2 = csr_w[j + 2], w3 = csr_w[j + 3];
        float4 u0 = ((const float4*)(x + (size_t)s0 * 256))[lane];
        float4 u1 = ((const float4*)(x + (size_t)s1 * 256))[lane];
        float4 u2 = ((const float4*)(x + (size_t)s2 * 256))[lane];
        float4 u3 = ((const float4*)(x + (size_t)s3 * 256))[lane];
        acc.x = fmaf(w0, u0.x, acc.x); acc.y = fmaf(w0, u0.y, acc.y);
        acc.z = fmaf(w0, u0.z, acc.z); acc.w = fmaf(w0, u0.w, acc.w);
        acc.x = fmaf(w1, u1.x, acc.x); acc.y = fmaf(w1, u1.y, acc.y);
        acc.z = fmaf(w1, u1.z, acc.z); acc.w = fmaf(w1, u1.w, acc.w);
        acc.x = fmaf(w2, u2.x, acc.x); acc.y = fmaf(w2, u2.y, acc.y);
        acc.z = fmaf(w2, u2.z, acc.z); acc.w = fmaf(w2, u2.w, acc.w);
        acc.x = fmaf(w3, u3.x, acc.x); acc.y = fmaf(w3, u3.y, acc.y);
        acc.z = fmaf(w3, u3.z, acc.z); acc.w = fmaf(w3, u3.w, acc.w);
    }
    for (; j < e1; ++j) {
        int s = csr_src[j];
        float wj = csr_w[j];
        float4 u = ((const float4*)(x + (size_t)s * 256))[lane];
        acc.x = fmaf(wj, u.x, acc.x); acc.y = fmaf(wj, u.y, acc.y);
        acc.z = fmaf(wj, u.z, acc.z); acc.w = fmaf(wj, u.w, acc.w);
    }
    // element flat idx f = 4*lane+k -> (c = f>>3, t = f&7)
    __shared__ float sh[4][TT][33];
    float av[4] = {acc.x, acc.y, acc.z, acc.w};
    #pragma unroll
    for (int k = 0; k < 4; ++k) {
        int f = 4 * lane + k;
        sh[w][f & 7][f >> 3] = av[k];
    }
    __syncthreads();
    for (int i = threadIdx.x; i < 1024; i += 256) {
        int t = i >> 7;
        int r = i & 127;
        int nl = r >> 5;
        int c = r & 31;
        xaT[((size_t)t * NN + blockIdx.x * 4 + nl) * CIN + c] = __float2half(sh[nl][t][c]);
    }
}

// h[n][co] = relu(xa_t[n][:] @ W1 + b1); xa fp16; block = 4 nodes x 64 outch
__global__ void mat32_relu(const __half* __restrict__ xa, const float* __restrict__ W,
                           const float* __restrict__ b, float* __restrict__ h) {
    __shared__ float Ws[CIN * COUT];
    __shared__ float Xs[4][CIN];
    for (int i = threadIdx.x; i < CIN * COUT; i += 256) Ws[i] = W[i];
    int co = threadIdx.x & 63;
    int nl = threadIdx.x >> 6;
    int n = blockIdx.x * 4 + nl;
    if (co < CIN) Xs[nl][co] = __half2float(xa[(size_t)n * CIN + co]);
    __syncthreads();
    float acc = b[co];
    #pragma unroll
    for (int k = 0; k < CIN; ++k) acc = fmaf(Xs[nl][k], Ws[k * COUT + co], acc);
    h[(size_t)n * COUT + co] = fmaxf(acc, 0.f);
}

// hw2[n][p] (__half2 = channels 2p,2p+1) = h[n][:] @ W; block = 8 nodes x 32 pairs
__global__ void mat64_h2(const float* __restrict__ hin, const float* __restrict__ W,
                         __half2* __restrict__ hw2) {
    __shared__ float Ws[COUT * COUT];   // 16 KB
    __shared__ float Xs[8][COUT];
    for (int i = threadIdx.x; i < COUT * COUT; i += 256) Ws[i] = W[i];
    int pr = threadIdx.x & 31;
    int nl = threadIdx.x >> 5;
    for (int i = threadIdx.x; i < 8 * COUT; i += 256)
        Xs[i >> 6][i & 63] = hin[((size_t)blockIdx.x * 8 + (i >> 6)) * COUT + (i & 63)];
    __syncthreads();
    float a0 = 0.f, a1 = 0.f;
    #pragma unroll
    for (int k = 0; k < COUT; ++k) {
        float xv = Xs[nl][k];
        a0 = fmaf(xv, Ws[k * COUT + 2 * pr], a0);
        a1 = fmaf(xv, Ws[k * COUT + 2 * pr + 1], a1);
    }
    size_t n = (size_t)blockIdx.x * 8 + nl;
    hw2[n * 32 + pr] = __floats2half2_rn(a0, a1);
}

// hout[n][c] = relu(sum_e w_e*hw[s][c] + dinv^2*hw[n][c] + b[c]).
// Lane = (channel-pair p, edge-parity par). Each lane gathers one __half2 dword;
// lo/hi half-waves walk even/odd edges; cross-half shfl_xor reduction at end.
__global__ void agg64_relu_h2(const __half2* __restrict__ hw2, const int* __restrict__ off,
                              const int* __restrict__ csr_src, const float* __restrict__ csr_w,
                              const float* __restrict__ dinv, const float* __restrict__ b,
                              float* __restrict__ hout) {
    int lane = threadIdx.x & 63;
    int p = lane & 31;          // channel pair: channels 2p, 2p+1
    int par = lane >> 5;        // edge parity
    int n = blockIdx.x * 4 + (threadIdx.x >> 6);
    int e0 = off[n], e1 = off[n + 1];
    float ax = 0.f, ay = 0.f;
    int j = e0 + par;
    for (; j + 2 < e1; j += 4) {
        int s0 = csr_src[j], s1 = csr_src[j + 2];
        float w0 = csr_w[j], w1 = csr_w[j + 2];
        float2 v0 = __half22float2(hw2[(size_t)s0 * 32 + p]);
        float2 v1 = __half22float2(hw2[(size_t)s1 * 32 + p]);
        ax = fmaf(w0, v0.x, ax); ay = fmaf(w0, v0.y, ay);
        ax = fmaf(w1, v1.x, ax); ay = fmaf(w1, v1.y, ay);
    }
    if (j < e1) {
        int s = csr_src[j];
        float w = csr_w[j];
        float2 v = __half22float2(hw2[(size_t)s * 32 + p]);
        ax = fmaf(w, v.x, ax); ay = fmaf(w, v.y, ay);
    }
    ax += __shfl_xor(ax, 32, 64);
    ay += __shfl_xor(ay, 32, 64);
    if (par == 0) {
        float dn = dinv[n];
        float sw = dn * dn;
        float2 sv = __half22float2(hw2[(size_t)n * 32 + p]);
        ax = fmaf(sw, sv.x, ax);
        ay = fmaf(sw, sv.y, ay);
        float2 o;
        o.x = fmaxf(ax + b[2 * p], 0.f);
        o.y = fmaxf(ay + b[2 * p + 1], 0.f);
        ((float2*)hout)[(size_t)n * 32 + p] = o;
    }
}

// pool h ([N][64] for one t) into out[g, :, t]; accumulate==0 -> write, else +=
__global__ void pool_acc(const float* __restrict__ h, float* __restrict__ out,
                         int t, int accumulate) {
    int g = blockIdx.x;
    int c = threadIdx.x & 63;
    int r = threadIdx.x >> 6;
    const float* hp = h + (size_t)g * NPG * COUT;
    float mx = -INFINITY, sm = 0.f;
    for (int n = r; n < NPG; n += 4) {
        float v = hp[n * COUT + c];
        mx = fmaxf(mx, v);
        sm += v;
    }
    __shared__ float smx[4][COUT];
    __shared__ float ssm[4][COUT];
    smx[r][c] = mx;
    ssm[r][c] = sm;
    __syncthreads();
    if (r == 0) {
        #pragma unroll
        for (int i = 1; i < 4; ++i) {
            mx = fmaxf(mx, smx[i][c]);
            sm += ssm[i][c];
        }
        float mean = sm * (1.0f / NPG);
        size_t o = (size_t)g * (2 * COUT * TT) + (size_t)c * TT + t;
        if (accumulate) {
            out[o] += mx;
            out[o + COUT * TT] += mean;
        } else {
            out[o] = mx;
            out[o + COUT * TT] = mean;
        }
    }
}

// ---------------- launch ----------------

extern "C" void kernel_launch(void* const* d_in, const int* in_sizes, int n_in,
                              void* d_out, int out_size, void* d_ws, size_t ws_size,
                              hipStream_t stream) {
    const float* x   = (const float*)d_in[0];
    const int*   ei  = (const int*)d_in[1];
    const int*   src = ei;
    const int*   dst = ei + EE;
    const float* W1  = (const float*)d_in[3];
    const float* b1  = (const float*)d_in[4];
    const float* W2  = (const float*)d_in[5];
    const float* b2  = (const float*)d_in[6];
    const float* W3  = (const float*)d_in[7];
    const float* b3  = (const float*)d_in[8];
    float* out = (float*)d_out;

    char* wsp = (char*)d_ws;
    auto alloc = [&](size_t bytes) {
        char* p = wsp;
        wsp += (bytes + 255) & ~(size_t)255;
        return p;
    };
    // fixed 6.8 + xaT 25.6 + hA 12.8 + hwh 6.4 = 51.6 MB (ws known >= 51.9 MB)
    float*   dinv    = (float*)  alloc((size_t)NN * 4);
    int*     off     = (int*)    alloc((size_t)(NN + 1) * 4);
    int*     csr_src = (int*)    alloc((size_t)EE * 4);
    float*   csr_w   = (float*)  alloc((size_t)EE * 4);
    __half*  xaT     = (__half*) alloc((size_t)NN * CIN * TT * 2);   // [t][n][c]
    float*   hA      = (float*)  alloc((size_t)NN * COUT * 4);
    __half2* hwh     = (__half2*)alloc((size_t)NN * COUT * 2);

    // setup-only buffers aliased into hA (dead before hA's first write)
    int* deg    = (int*)hA;
    int* cursor = (int*)(hA + NN);
    int* bsum   = (int*)(hA + 2 * NN);

    // structure (time-invariant)
    init_deg<<<NBLK, 256, 0, stream>>>(deg, cursor);
    count_deg<<<(EE + 255) / 256, 256, 0, stream>>>(dst, deg);
    compute_dinv<<<NBLK, 256, 0, stream>>>(deg, dinv);
    scan_blocks<<<NBLK, SCAN_B, 0, stream>>>(deg, off, bsum);
    scan_sums<<<1, SCAN_B, 0, stream>>>(bsum, off);
    scan_add<<<NBLK, SCAN_B, 0, stream>>>(off, bsum);
    fill_csr<<<(EE + 255) / 256, 256, 0, stream>>>(src, dst, off, cursor, dinv,
                                                   csr_src, csr_w);

    // x aggregation for ALL t in one pass
    agg_x_allT<<<NN / 4, 256, 0, stream>>>(x, off, csr_src, csr_w, dinv, xaT);

    for (int t = 0; t < TT; ++t) {
        const __half* xat = xaT + (size_t)t * NN * CIN;
        mat32_relu<<<NN / 4, 256, 0, stream>>>(xat, W1, b1, hA);       // h1
        pool_acc<<<BB, 256, 0, stream>>>(hA, out, t, 0);
        mat64_h2<<<NN / 8, 256, 0, stream>>>(hA, W2, hwh);
        agg64_relu_h2<<<NN / 4, 256, 0, stream>>>(hwh, off, csr_src, csr_w, dinv, b2, hA);  // h2
        pool_acc<<<BB, 256, 0, stream>>>(hA, out, t, 1);
        mat64_h2<<<NN / 8, 256, 0, stream>>>(hA, W3, hwh);
        agg64_relu_h2<<<NN / 4, 256, 0, stream>>>(hwh, off, csr_src, csr_w, dinv, b3, hA);  // h3
        pool_acc<<<BB, 256, 0, stream>>>(hA, out, t, 1);
    }
}

// Round 6
// 1376.706 us; speedup vs baseline: 2.3684x; 1.2215x over previous
//
#include <hip/hip_runtime.h>
#include <hip/hip_fp16.h>
#include <math.h>

#define NN 50000
#define EE 800000
#define BB 250
#define TT 8
#define CIN 32
#define COUT 64
#define NPG 200          // nodes per graph (N/B)
#define SCAN_B 256
#define NBLK 196         // ceil(50000/256)

// pack/unpack CSR entry: low 16 = src node (NN<65536), high 16 = fp16 weight
__device__ __forceinline__ float unpack_w(unsigned int v) {
    union { unsigned short u; __half h; } cv;
    cv.u = (unsigned short)(v >> 16);
    return __half2float(cv.h);
}

// ---------------- setup kernels (graph structure, once per call) ----------------

__global__ void init_deg(int* deg, int* cursor) {
    int n = blockIdx.x * 256 + threadIdx.x;
    if (n < NN) { deg[n] = 1; cursor[n] = 0; }   // self-loop contributes 1
}

__global__ void count_deg(const int* dst, int* deg) {
    int e = blockIdx.x * 256 + threadIdx.x;
    if (e < EE) atomicAdd(&deg[dst[e]], 1);
}

__global__ void compute_dinv(const int* deg, float* dinv) {
    int n = blockIdx.x * 256 + threadIdx.x;
    if (n < NN) dinv[n] = rsqrtf((float)deg[n]);
}

__global__ void scan_blocks(const int* deg, int* off, int* bsum) {
    __shared__ int sh[SCAN_B];
    int gid = blockIdx.x * SCAN_B + threadIdx.x;
    int v = (gid < NN) ? (deg[gid] - 1) : 0;
    sh[threadIdx.x] = v;
    __syncthreads();
    for (int s = 1; s < SCAN_B; s <<= 1) {
        int add = (threadIdx.x >= s) ? sh[threadIdx.x - s] : 0;
        __syncthreads();
        sh[threadIdx.x] += add;
        __syncthreads();
    }
    if (gid < NN) off[gid] = sh[threadIdx.x] - v;       // exclusive
    if (threadIdx.x == SCAN_B - 1) bsum[blockIdx.x] = sh[threadIdx.x];
}

__global__ void scan_sums(int* bsum, int* off) {
    __shared__ int sh[SCAN_B];
    int v = (threadIdx.x < NBLK) ? bsum[threadIdx.x] : 0;
    sh[threadIdx.x] = v;
    __syncthreads();
    for (int s = 1; s < SCAN_B; s <<= 1) {
        int add = (threadIdx.x >= s) ? sh[threadIdx.x - s] : 0;
        __syncthreads();
        sh[threadIdx.x] += add;
        __syncthreads();
    }
    if (threadIdx.x < NBLK) bsum[threadIdx.x] = sh[threadIdx.x] - v;  // exclusive
    if (threadIdx.x == 0) off[NN] = EE;
}

__global__ void scan_add(int* off, const int* bsum) {
    int gid = blockIdx.x * SCAN_B + threadIdx.x;
    if (gid < NN) off[gid] += bsum[blockIdx.x];
}

__global__ void fill_csr(const int* src, const int* dst, const int* off,
                         int* cursor, const float* dinv, unsigned int* csrp) {
    int e = blockIdx.x * 256 + threadIdx.x;
    if (e >= EE) return;
    int s = src[e], d = dst[e];
    int p = atomicAdd(&cursor[d], 1);
    union { __half h; unsigned short u; } cv;
    cv.h = __float2half(dinv[s] * dinv[d]);
    csrp[off[d] + p] = (unsigned int)s | ((unsigned int)cv.u << 16);
}

__global__ void scratch_init(float* pmax, float* psum) {
    int i = blockIdx.x * 256 + threadIdx.x;
    if (i < 3 * BB * COUT) pmax[i] = 0.f;
    if (i < BB * COUT) psum[i] = 0.f;
}

// ---------------- compute kernels ----------------

// ONE pass: xaT[t][n][c] (fp16) = sum_e w_e * x[src][c][t] + dinv^2 * x[n][c][t], all t.
// One wave per node; lane l holds float4 = contiguous row elements [4l,4l+4).
__global__ void agg_x_allT(const float* __restrict__ x, const int* __restrict__ off,
                           const unsigned int* __restrict__ csrp,
                           const float* __restrict__ dinv, __half* __restrict__ xaT) {
    int lane = threadIdx.x & 63;
    int w = threadIdx.x >> 6;
    int n = blockIdx.x * 4 + w;
    float dn = dinv[n];
    float sw = dn * dn;
    float4 v = ((const float4*)(x + (size_t)n * 256))[lane];
    float4 acc = make_float4(sw * v.x, sw * v.y, sw * v.z, sw * v.w);
    int e0 = off[n], e1 = off[n + 1];
    int j = e0;
    for (; j + 3 < e1; j += 4) {
        unsigned int p0 = csrp[j],     p1 = csrp[j + 1];
        unsigned int p2 = csrp[j + 2], p3 = csrp[j + 3];
        float4 u0 = ((const float4*)(x + (size_t)(p0 & 0xffff) * 256))[lane];
        float4 u1 = ((const float4*)(x + (size_t)(p1 & 0xffff) * 256))[lane];
        float4 u2 = ((const float4*)(x + (size_t)(p2 & 0xffff) * 256))[lane];
        float4 u3 = ((const float4*)(x + (size_t)(p3 & 0xffff) * 256))[lane];
        float w0 = unpack_w(p0), w1 = unpack_w(p1);
        float w2 = unpack_w(p2), w3 = unpack_w(p3);
        acc.x = fmaf(w0, u0.x, acc.x); acc.y = fmaf(w0, u0.y, acc.y);
        acc.z = fmaf(w0, u0.z, acc.z); acc.w = fmaf(w0, u0.w, acc.w);
        acc.x = fmaf(w1, u1.x, acc.x); acc.y = fmaf(w1, u1.y, acc.y);
        acc.z = fmaf(w1, u1.z, acc.z); acc.w = fmaf(w1, u1.w, acc.w);
        acc.x = fmaf(w2, u2.x, acc.x); acc.y = fmaf(w2, u2.y, acc.y);
        acc.z = fmaf(w2, u2.z, acc.z); acc.w = fmaf(w2, u2.w, acc.w);
        acc.x = fmaf(w3, u3.x, acc.x); acc.y = fmaf(w3, u3.y, acc.y);
        acc.z = fmaf(w3, u3.z, acc.z); acc.w = fmaf(w3, u3.w, acc.w);
    }
    for (; j < e1; ++j) {
        unsigned int p = csrp[j];
        float wj = unpack_w(p);
        float4 u = ((const float4*)(x + (size_t)(p & 0xffff) * 256))[lane];
        acc.x = fmaf(wj, u.x, acc.x); acc.y = fmaf(wj, u.y, acc.y);
        acc.z = fmaf(wj, u.z, acc.z); acc.w = fmaf(wj, u.w, acc.w);
    }
    // element flat idx f = 4*lane+k -> (c = f>>3, t = f&7)
    __shared__ float sh[4][TT][33];
    float av[4] = {acc.x, acc.y, acc.z, acc.w};
    #pragma unroll
    for (int k = 0; k < 4; ++k) {
        int f = 4 * lane + k;
        sh[w][f & 7][f >> 3] = av[k];
    }
    __syncthreads();
    for (int i = threadIdx.x; i < 1024; i += 256) {
        int t = i >> 7;
        int r = i & 127;
        int nl = r >> 5;
        int c = r & 31;
        xaT[((size_t)t * NN + blockIdx.x * 4 + nl) * CIN + c] = __float2half(sh[nl][t][c]);
    }
}

// h1 = relu(xa_t @ W1 + b1) (fp16 out) + fused pooling into pmax[0]/psum.
// block = 4 nodes x 64 outch; 50 blocks per graph.
__global__ void matpool1(const __half* __restrict__ xa, const float* __restrict__ W,
                         const float* __restrict__ b, __half2* __restrict__ h,
                         float* __restrict__ pmax, float* __restrict__ psum) {
    __shared__ float Ws[CIN * COUT];      // 8 KB
    __shared__ float Xs[4][CIN];
    __shared__ float tile[4][COUT];
    for (int i = threadIdx.x; i < CIN * COUT; i += 256) Ws[i] = W[i];
    {   // load 4 nodes x 32 ch (half2 pairs) of xa
        int i = threadIdx.x;
        if (i < 64) {
            int nl = i >> 4, pp = i & 15;
            float2 v = __half22float2(((const __half2*)xa)[((size_t)blockIdx.x * 4 + nl) * 16 + pp]);
            Xs[nl][2 * pp] = v.x;
            Xs[nl][2 * pp + 1] = v.y;
        }
    }
    int co = threadIdx.x & 63;
    int nl = threadIdx.x >> 6;
    __syncthreads();
    float acc = b[co];
    #pragma unroll
    for (int k = 0; k < CIN; ++k) acc = fmaf(Xs[nl][k], Ws[k * COUT + co], acc);
    acc = fmaxf(acc, 0.f);
    tile[nl][co] = acc;
    __syncthreads();
    // fp16 store: 128 threads write half2
    if (threadIdx.x < 128) {
        int n2 = threadIdx.x >> 5, p = threadIdx.x & 31;
        h[((size_t)blockIdx.x * 4 + n2) * 32 + p] =
            __floats2half2_rn(tile[n2][2 * p], tile[n2][2 * p + 1]);
    }
    // pool reduce over 4 nodes -> atomics
    if (threadIdx.x < 64) {
        int c = threadIdx.x;
        float m = fmaxf(fmaxf(tile[0][c], tile[1][c]), fmaxf(tile[2][c], tile[3][c]));
        float s = tile[0][c] + tile[1][c] + tile[2][c] + tile[3][c];
        int g = blockIdx.x / 50;
        atomicMax((int*)&pmax[g * COUT + c], __float_as_int(m));
        atomicAdd(&psum[g * COUT + c], s);
    }
}

// hw2[n][p] (__half2) = h[n][:] @ W ; h fp16; block = 8 nodes x 32 pairs
__global__ void mat64_h2(const __half2* __restrict__ hin, const float* __restrict__ W,
                         __half2* __restrict__ hw2) {
    __shared__ float Ws[COUT * COUT];   // 16 KB
    __shared__ float Xs[8][COUT];
    for (int i = threadIdx.x; i < COUT * COUT; i += 256) Ws[i] = W[i];
    {
        int i = threadIdx.x;            // 256 = 8 nodes x 32 pairs
        int nl = i >> 5, pp = i & 31;
        float2 v = __half22float2(hin[((size_t)blockIdx.x * 8 + nl) * 32 + pp]);
        Xs[nl][2 * pp] = v.x;
        Xs[nl][2 * pp + 1] = v.y;
    }
    int pr = threadIdx.x & 31;
    int nl = threadIdx.x >> 5;
    __syncthreads();
    float a0 = 0.f, a1 = 0.f;
    #pragma unroll
    for (int k = 0; k < COUT; ++k) {
        float xv = Xs[nl][k];
        a0 = fmaf(xv, Ws[k * COUT + 2 * pr], a0);
        a1 = fmaf(xv, Ws[k * COUT + 2 * pr + 1], a1);
    }
    hw2[((size_t)blockIdx.x * 8 + nl) * 32 + pr] = __floats2half2_rn(a0, a1);
}

// h_out = relu(A_hat hw + b) with fused pooling; optionally store h_out (fp16).
// Lane = (channel-pair p, edge-parity par); 4x-unrolled parity walk (MLP=4).
template <int STORE>
__global__ void aggpool(const __half2* __restrict__ hw2, const int* __restrict__ off,
                        const unsigned int* __restrict__ csrp,
                        const float* __restrict__ dinv, const float* __restrict__ b,
                        __half2* __restrict__ hout,
                        float* __restrict__ pmax, float* __restrict__ psum) {
    int lane = threadIdx.x & 63;
    int p = lane & 31;
    int par = lane >> 5;
    int w = threadIdx.x >> 6;
    int n = blockIdx.x * 4 + w;
    int e0 = off[n], e1 = off[n + 1];
    float ax = 0.f, ay = 0.f;
    int j = e0 + par;
    for (; j + 6 < e1; j += 8) {
        unsigned int c0 = csrp[j],     c1 = csrp[j + 2];
        unsigned int c2 = csrp[j + 4], c3 = csrp[j + 6];
        float2 v0 = __half22float2(hw2[(size_t)(c0 & 0xffff) * 32 + p]);
        float2 v1 = __half22float2(hw2[(size_t)(c1 & 0xffff) * 32 + p]);
        float2 v2 = __half22float2(hw2[(size_t)(c2 & 0xffff) * 32 + p]);
        float2 v3 = __half22float2(hw2[(size_t)(c3 & 0xffff) * 32 + p]);
        float w0 = unpack_w(c0), w1 = unpack_w(c1);
        float w2 = unpack_w(c2), w3 = unpack_w(c3);
        ax = fmaf(w0, v0.x, ax); ay = fmaf(w0, v0.y, ay);
        ax = fmaf(w1, v1.x, ax); ay = fmaf(w1, v1.y, ay);
        ax = fmaf(w2, v2.x, ax); ay = fmaf(w2, v2.y, ay);
        ax = fmaf(w3, v3.x, ax); ay = fmaf(w3, v3.y, ay);
    }
    for (; j < e1; j += 2) {
        unsigned int c = csrp[j];
        float wv = unpack_w(c);
        float2 v = __half22float2(hw2[(size_t)(c & 0xffff) * 32 + p]);
        ax = fmaf(wv, v.x, ax); ay = fmaf(wv, v.y, ay);
    }
    ax += __shfl_xor(ax, 32, 64);
    ay += __shfl_xor(ay, 32, 64);
    __shared__ float tile[4][COUT];
    if (par == 0) {
        float dn = dinv[n];
        float sw = dn * dn;
        float2 sv = __half22float2(hw2[(size_t)n * 32 + p]);
        float ox = fmaxf(fmaf(sw, sv.x, ax) + b[2 * p], 0.f);
        float oy = fmaxf(fmaf(sw, sv.y, ay) + b[2 * p + 1], 0.f);
        tile[w][2 * p] = ox;
        tile[w][2 * p + 1] = oy;
        if (STORE) hout[(size_t)n * 32 + p] = __floats2half2_rn(ox, oy);
    }
    __syncthreads();
    if (threadIdx.x < 64) {
        int c = threadIdx.x;
        float m = fmaxf(fmaxf(tile[0][c], tile[1][c]), fmaxf(tile[2][c], tile[3][c]));
        float s = tile[0][c] + tile[1][c] + tile[2][c] + tile[3][c];
        int g = blockIdx.x / 50;
        atomicMax((int*)&pmax[g * COUT + c], __float_as_int(m));
        atomicAdd(&psum[g * COUT + c], s);
    }
}

// fold scratch -> out[:, :, t], then reset scratch for next t
__global__ void fold(const float* __restrict__ pmax, float* __restrict__ psum,
                     float* __restrict__ out, int t, float* pmax_mut) {
    int i = blockIdx.x * 256 + threadIdx.x;
    if (i >= BB * COUT) return;
    int g = i >> 6, c = i & 63;
    float m = pmax[i] + pmax[BB * COUT + i] + pmax[2 * BB * COUT + i];
    float mean = psum[i] * (1.0f / NPG);
    out[((size_t)g * 128 + c) * TT + t] = m;
    out[((size_t)g * 128 + 64 + c) * TT + t] = mean;
    pmax_mut[i] = 0.f;
    pmax_mut[BB * COUT + i] = 0.f;
    pmax_mut[2 * BB * COUT + i] = 0.f;
    psum[i] = 0.f;
}

// ---------------- launch ----------------

extern "C" void kernel_launch(void* const* d_in, const int* in_sizes, int n_in,
                              void* d_out, int out_size, void* d_ws, size_t ws_size,
                              hipStream_t stream) {
    const float* x   = (const float*)d_in[0];
    const int*   ei  = (const int*)d_in[1];
    const int*   src = ei;
    const int*   dst = ei + EE;
    const float* W1  = (const float*)d_in[3];
    const float* b1  = (const float*)d_in[4];
    const float* W2  = (const float*)d_in[5];
    const float* b2  = (const float*)d_in[6];
    const float* W3  = (const float*)d_in[7];
    const float* b3  = (const float*)d_in[8];
    float* out = (float*)d_out;

    char* wsp = (char*)d_ws;
    auto alloc = [&](size_t bytes) {
        char* p = wsp;
        wsp += (bytes + 255) & ~(size_t)255;
        return p;
    };
    // total ~42.3 MB (ws known >= 52.07 MB)
    float*        dinv = (float*)       alloc((size_t)NN * 4);
    int*          off  = (int*)         alloc((size_t)(NN + 1) * 4);
    unsigned int* csrp = (unsigned int*)alloc((size_t)EE * 4);
    __half*       xaT  = (__half*)      alloc((size_t)NN * CIN * TT * 2);  // [t][n][c]
    __half2*      h    = (__half2*)     alloc((size_t)NN * COUT * 2);
    __half2*      hw   = (__half2*)     alloc((size_t)NN * COUT * 2);
    float*        pmax = (float*)       alloc((size_t)3 * BB * COUT * 4);
    float*        psum = (float*)       alloc((size_t)BB * COUT * 4);

    // setup-only buffers aliased into h (dead before h's first write)
    int* deg    = (int*)h;
    int* cursor = ((int*)h) + NN;
    int* bsum   = ((int*)h) + 2 * NN;

    // structure (time-invariant)
    init_deg<<<NBLK, 256, 0, stream>>>(deg, cursor);
    count_deg<<<(EE + 255) / 256, 256, 0, stream>>>(dst, deg);
    compute_dinv<<<NBLK, 256, 0, stream>>>(deg, dinv);
    scan_blocks<<<NBLK, SCAN_B, 0, stream>>>(deg, off, bsum);
    scan_sums<<<1, SCAN_B, 0, stream>>>(bsum, off);
    scan_add<<<NBLK, SCAN_B, 0, stream>>>(off, bsum);
    fill_csr<<<(EE + 255) / 256, 256, 0, stream>>>(src, dst, off, cursor, dinv, csrp);
    scratch_init<<<(3 * BB * COUT + 255) / 256, 256, 0, stream>>>(pmax, psum);

    // x aggregation for ALL t in one pass
    agg_x_allT<<<NN / 4, 256, 0, stream>>>(x, off, csrp, dinv, xaT);

    for (int t = 0; t < TT; ++t) {
        const __half* xat = xaT + (size_t)t * NN * CIN;
        matpool1<<<NN / 4, 256, 0, stream>>>(xat, W1, b1, h, pmax, psum);
        mat64_h2<<<NN / 8, 256, 0, stream>>>(h, W2, hw);
        aggpool<1><<<NN / 4, 256, 0, stream>>>(hw, off, csrp, dinv, b2, h,
                                               pmax + BB * COUT, psum);
        mat64_h2<<<NN / 8, 256, 0, stream>>>(h, W3, hw);
        aggpool<0><<<NN / 4, 256, 0, stream>>>(hw, off, csrp, dinv, b3, nullptr,
                                               pmax + 2 * BB * COUT, psum);
        fold<<<(BB * COUT + 255) / 256, 256, 0, stream>>>(pmax, psum, out, t, pmax);
    }
}

// Round 7
// 1341.524 us; speedup vs baseline: 2.4305x; 1.0262x over previous
//
#include <hip/hip_runtime.h>
#include <hip/hip_fp16.h>
#include <math.h>

#define NN 50000
#define EE 800000
#define BB 250
#define TT 8
#define CIN 32
#define COUT 64
#define NPG 200          // nodes per graph (N/B)
#define SCAN_B 256
#define NBLK 196         // ceil(50000/256)

// pack/unpack CSR entry: low 16 = src node (NN<65536), high 16 = fp16 weight
__device__ __forceinline__ float unpack_w(unsigned int v) {
    union { unsigned short u; __half h; } cv;
    cv.u = (unsigned short)(v >> 16);
    return __half2float(cv.h);
}

// ---------------- setup kernels (graph structure, once per call) ----------------

__global__ void init_deg(int* deg, int* cursor) {
    int n = blockIdx.x * 256 + threadIdx.x;
    if (n < NN) { deg[n] = 1; cursor[n] = 0; }   // self-loop contributes 1
}

__global__ void count_deg(const int* dst, int* deg) {
    int e = blockIdx.x * 256 + threadIdx.x;
    if (e < EE) atomicAdd(&deg[dst[e]], 1);
}

__global__ void compute_dinv(const int* deg, float* dinv) {
    int n = blockIdx.x * 256 + threadIdx.x;
    if (n < NN) dinv[n] = rsqrtf((float)deg[n]);
}

__global__ void scan_blocks(const int* deg, int* off, int* bsum) {
    __shared__ int sh[SCAN_B];
    int gid = blockIdx.x * SCAN_B + threadIdx.x;
    int v = (gid < NN) ? (deg[gid] - 1) : 0;
    sh[threadIdx.x] = v;
    __syncthreads();
    for (int s = 1; s < SCAN_B; s <<= 1) {
        int add = (threadIdx.x >= s) ? sh[threadIdx.x - s] : 0;
        __syncthreads();
        sh[threadIdx.x] += add;
        __syncthreads();
    }
    if (gid < NN) off[gid] = sh[threadIdx.x] - v;       // exclusive
    if (threadIdx.x == SCAN_B - 1) bsum[blockIdx.x] = sh[threadIdx.x];
}

__global__ void scan_sums(int* bsum, int* off) {
    __shared__ int sh[SCAN_B];
    int v = (threadIdx.x < NBLK) ? bsum[threadIdx.x] : 0;
    sh[threadIdx.x] = v;
    __syncthreads();
    for (int s = 1; s < SCAN_B; s <<= 1) {
        int add = (threadIdx.x >= s) ? sh[threadIdx.x - s] : 0;
        __syncthreads();
        sh[threadIdx.x] += add;
        __syncthreads();
    }
    if (threadIdx.x < NBLK) bsum[threadIdx.x] = sh[threadIdx.x] - v;  // exclusive
    if (threadIdx.x == 0) off[NN] = EE;
}

__global__ void scan_add(int* off, const int* bsum) {
    int gid = blockIdx.x * SCAN_B + threadIdx.x;
    if (gid < NN) off[gid] += bsum[blockIdx.x];
}

__global__ void fill_csr(const int* src, const int* dst, const int* off,
                         int* cursor, const float* dinv, unsigned int* csrp) {
    int e = blockIdx.x * 256 + threadIdx.x;
    if (e >= EE) return;
    int s = src[e], d = dst[e];
    int p = atomicAdd(&cursor[d], 1);
    union { __half h; unsigned short u; } cv;
    cv.h = __float2half(dinv[s] * dinv[d]);
    csrp[off[d] + p] = (unsigned int)s | ((unsigned int)cv.u << 16);
}

__global__ void scratch_init(float* pmax, float* psum) {
    int i = blockIdx.x * 256 + threadIdx.x;
    if (i < 3 * BB * COUT) pmax[i] = 0.f;
    if (i < BB * COUT) psum[i] = 0.f;
}

// ---------------- compute kernels ----------------

// transpose x[n][c][t] (fp32, 256/row) -> xhT[t][n][16 half2] (fp16)
// one wave per node, LDS staged, coalesced both sides
__global__ void transpose_x(const float* __restrict__ x, __half2* __restrict__ xhT) {
    int lane = threadIdx.x & 63;
    int w = threadIdx.x >> 6;
    int n = blockIdx.x * 4 + w;
    float4 v = ((const float4*)(x + (size_t)n * 256))[lane];
    __shared__ float sh[4][TT][33];
    float av[4] = {v.x, v.y, v.z, v.w};
    #pragma unroll
    for (int k = 0; k < 4; ++k) {
        int f = 4 * lane + k;               // c = f>>3, t = f&7
        sh[w][f & 7][f >> 3] = av[k];
    }
    __syncthreads();
    // 8t x 4n x 16 pairs = 512 half2; per t: 64 consecutive half2 = 256B
    for (int i = threadIdx.x; i < 512; i += 256) {
        int t = i >> 6;
        int r = i & 63;
        int nl = r >> 4;
        int pp = r & 15;
        xhT[(size_t)t * (NN * 16) + ((size_t)blockIdx.x * 4 + nl) * 16 + pp] =
            __floats2half2_rn(sh[nl][t][2 * pp], sh[nl][t][2 * pp + 1]);
    }
}

// Layer 1 fused: xa = A_hat xh_t (gather 32ch), h1 = relu(xa W1 + b1), pool,
// hw2 = h1 W2. Block = 4 nodes x 64 lanes; gather lane = (pp 0..15, quad 0..3).
__global__ void fused_l1(const __half2* __restrict__ xh, const int* __restrict__ off,
                         const unsigned int* __restrict__ csrp, const float* __restrict__ dinv,
                         const float* __restrict__ W1, const float* __restrict__ b1,
                         const float* __restrict__ W2, __half2* __restrict__ hw2,
                         float* __restrict__ pmax, float* __restrict__ psum) {
    __shared__ float W1s[CIN * COUT];     // 8 KB
    __shared__ float W2s[COUT * COUT];    // 16 KB
    __shared__ float Xs[4][CIN];
    __shared__ float tile[4][COUT];
    for (int i = threadIdx.x; i < CIN * COUT; i += 256) W1s[i] = W1[i];
    for (int i = threadIdx.x; i < COUT * COUT; i += 256) W2s[i] = W2[i];

    int lane = threadIdx.x & 63;
    int w = threadIdx.x >> 6;
    int pp = lane & 15;
    int quad = lane >> 4;
    int n = blockIdx.x * 4 + w;
    int e0 = off[n], e1 = off[n + 1];
    float ax = 0.f, ay = 0.f;
    int j = e0 + quad;
    for (; j + 4 < e1; j += 8) {           // 2-deep per quad, 8 lines in flight/wave
        unsigned int c0 = csrp[j], c1 = csrp[j + 4];
        float2 v0 = __half22float2(xh[(size_t)(c0 & 0xffff) * 16 + pp]);
        float2 v1 = __half22float2(xh[(size_t)(c1 & 0xffff) * 16 + pp]);
        float w0 = unpack_w(c0), w1 = unpack_w(c1);
        ax = fmaf(w0, v0.x, ax); ay = fmaf(w0, v0.y, ay);
        ax = fmaf(w1, v1.x, ax); ay = fmaf(w1, v1.y, ay);
    }
    for (; j < e1; j += 4) {
        unsigned int c = csrp[j];
        float2 v = __half22float2(xh[(size_t)(c & 0xffff) * 16 + pp]);
        float wv = unpack_w(c);
        ax = fmaf(wv, v.x, ax); ay = fmaf(wv, v.y, ay);
    }
    ax += __shfl_xor(ax, 16, 64); ax += __shfl_xor(ax, 32, 64);
    ay += __shfl_xor(ay, 16, 64); ay += __shfl_xor(ay, 32, 64);
    if (quad == 0) {
        float dn = dinv[n];
        float sw = dn * dn;
        float2 sv = __half22float2(xh[(size_t)n * 16 + pp]);
        Xs[w][2 * pp]     = fmaf(sw, sv.x, ax);
        Xs[w][2 * pp + 1] = fmaf(sw, sv.y, ay);
    }
    __syncthreads();
    // h1 = relu(Xs @ W1 + b1): 256 thr = 4 nodes x 64 outch
    int co = threadIdx.x & 63;
    int nl = threadIdx.x >> 6;
    float acc = b1[co];
    #pragma unroll
    for (int k = 0; k < CIN; ++k) acc = fmaf(Xs[nl][k], W1s[k * COUT + co], acc);
    acc = fmaxf(acc, 0.f);
    tile[nl][co] = acc;
    __syncthreads();
    if (threadIdx.x < 64) {
        int c = threadIdx.x;
        float m = fmaxf(fmaxf(tile[0][c], tile[1][c]), fmaxf(tile[2][c], tile[3][c]));
        float s = tile[0][c] + tile[1][c] + tile[2][c] + tile[3][c];
        int g = blockIdx.x / 50;
        atomicMax((int*)&pmax[g * COUT + c], __float_as_int(m));
        atomicAdd(&psum[g * COUT + c], s);
    }
    // hw2 = h1 @ W2: 128 thr = 4 nodes x 32 pairs
    if (threadIdx.x < 128) {
        int nl2 = threadIdx.x >> 5;
        int pr = threadIdx.x & 31;
        float a0 = 0.f, a1 = 0.f;
        #pragma unroll
        for (int k = 0; k < COUT; ++k) {
            float xv = tile[nl2][k];
            a0 = fmaf(xv, W2s[k * COUT + 2 * pr], a0);
            a1 = fmaf(xv, W2s[k * COUT + 2 * pr + 1], a1);
        }
        hw2[((size_t)blockIdx.x * 4 + nl2) * 32 + pr] = __floats2half2_rn(a0, a1);
    }
}

// Layers 2/3 fused: h = relu(A_hat hw_in + b), pool; if FUSE: hw_out = h W.
// Block = 4 nodes x 64 lanes; gather lane = (pair p 0..31, parity 0..1).
template <int FUSE>
__global__ void agg_fused(const __half2* __restrict__ hw_in, const int* __restrict__ off,
                          const unsigned int* __restrict__ csrp,
                          const float* __restrict__ dinv, const float* __restrict__ b,
                          const float* __restrict__ W, __half2* __restrict__ hw_out,
                          float* __restrict__ pmax, float* __restrict__ psum) {
    __shared__ float Ws[FUSE ? COUT * COUT : 1];
    __shared__ float tile[4][COUT];
    if (FUSE)
        for (int i = threadIdx.x; i < COUT * COUT; i += 256) Ws[i] = W[i];

    int lane = threadIdx.x & 63;
    int p = lane & 31;
    int par = lane >> 5;
    int w = threadIdx.x >> 6;
    int n = blockIdx.x * 4 + w;
    int e0 = off[n], e1 = off[n + 1];
    float ax = 0.f, ay = 0.f;
    int j = e0 + par;
    for (; j + 6 < e1; j += 8) {          // 4-deep per parity, 8 lines/wave in flight
        unsigned int c0 = csrp[j],     c1 = csrp[j + 2];
        unsigned int c2 = csrp[j + 4], c3 = csrp[j + 6];
        float2 v0 = __half22float2(hw_in[(size_t)(c0 & 0xffff) * 32 + p]);
        float2 v1 = __half22float2(hw_in[(size_t)(c1 & 0xffff) * 32 + p]);
        float2 v2 = __half22float2(hw_in[(size_t)(c2 & 0xffff) * 32 + p]);
        float2 v3 = __half22float2(hw_in[(size_t)(c3 & 0xffff) * 32 + p]);
        float w0 = unpack_w(c0), w1 = unpack_w(c1);
        float w2 = unpack_w(c2), w3 = unpack_w(c3);
        ax = fmaf(w0, v0.x, ax); ay = fmaf(w0, v0.y, ay);
        ax = fmaf(w1, v1.x, ax); ay = fmaf(w1, v1.y, ay);
        ax = fmaf(w2, v2.x, ax); ay = fmaf(w2, v2.y, ay);
        ax = fmaf(w3, v3.x, ax); ay = fmaf(w3, v3.y, ay);
    }
    for (; j < e1; j += 2) {
        unsigned int c = csrp[j];
        float wv = unpack_w(c);
        float2 v = __half22float2(hw_in[(size_t)(c & 0xffff) * 32 + p]);
        ax = fmaf(wv, v.x, ax); ay = fmaf(wv, v.y, ay);
    }
    ax += __shfl_xor(ax, 32, 64);
    ay += __shfl_xor(ay, 32, 64);
    if (par == 0) {
        float dn = dinv[n];
        float sw = dn * dn;
        float2 sv = __half22float2(hw_in[(size_t)n * 32 + p]);
        tile[w][2 * p]     = fmaxf(fmaf(sw, sv.x, ax) + b[2 * p], 0.f);
        tile[w][2 * p + 1] = fmaxf(fmaf(sw, sv.y, ay) + b[2 * p + 1], 0.f);
    }
    __syncthreads();
    if (threadIdx.x < 64) {
        int c = threadIdx.x;
        float m = fmaxf(fmaxf(tile[0][c], tile[1][c]), fmaxf(tile[2][c], tile[3][c]));
        float s = tile[0][c] + tile[1][c] + tile[2][c] + tile[3][c];
        int g = blockIdx.x / 50;
        atomicMax((int*)&pmax[g * COUT + c], __float_as_int(m));
        atomicAdd(&psum[g * COUT + c], s);
    }
    if (FUSE && threadIdx.x < 128) {
        int nl2 = threadIdx.x >> 5;
        int pr = threadIdx.x & 31;
        float a0 = 0.f, a1 = 0.f;
        #pragma unroll
        for (int k = 0; k < COUT; ++k) {
            float xv = tile[nl2][k];
            a0 = fmaf(xv, Ws[k * COUT + 2 * pr], a0);
            a1 = fmaf(xv, Ws[k * COUT + 2 * pr + 1], a1);
        }
        hw_out[((size_t)blockIdx.x * 4 + nl2) * 32 + pr] = __floats2half2_rn(a0, a1);
    }
}

// fold scratch -> out[:, :, t], then reset scratch for next t
__global__ void fold(const float* __restrict__ pmax, float* __restrict__ psum,
                     float* __restrict__ out, int t, float* pmax_mut) {
    int i = blockIdx.x * 256 + threadIdx.x;
    if (i >= BB * COUT) return;
    int g = i >> 6, c = i & 63;
    float m = pmax[i] + pmax[BB * COUT + i] + pmax[2 * BB * COUT + i];
    float mean = psum[i] * (1.0f / NPG);
    out[((size_t)g * 128 + c) * TT + t] = m;
    out[((size_t)g * 128 + 64 + c) * TT + t] = mean;
    pmax_mut[i] = 0.f;
    pmax_mut[BB * COUT + i] = 0.f;
    pmax_mut[2 * BB * COUT + i] = 0.f;
    psum[i] = 0.f;
}

// ---------------- launch ----------------

extern "C" void kernel_launch(void* const* d_in, const int* in_sizes, int n_in,
                              void* d_out, int out_size, void* d_ws, size_t ws_size,
                              hipStream_t stream) {
    const float* x   = (const float*)d_in[0];
    const int*   ei  = (const int*)d_in[1];
    const int*   src = ei;
    const int*   dst = ei + EE;
    const float* W1  = (const float*)d_in[3];
    const float* b1  = (const float*)d_in[4];
    const float* W2  = (const float*)d_in[5];
    const float* b2  = (const float*)d_in[6];
    const float* W3  = (const float*)d_in[7];
    const float* b3  = (const float*)d_in[8];
    float* out = (float*)d_out;

    char* wsp = (char*)d_ws;
    auto alloc = [&](size_t bytes) {
        char* p = wsp;
        wsp += (bytes + 255) & ~(size_t)255;
        return p;
    };
    // total ~42.3 MB (known-safe footprint from round 6)
    float*        dinv = (float*)       alloc((size_t)NN * 4);
    int*          off  = (int*)         alloc((size_t)(NN + 1) * 4);
    unsigned int* csrp = (unsigned int*)alloc((size_t)EE * 4);
    __half2*      xhT  = (__half2*)     alloc((size_t)NN * CIN * TT * 2);  // [t][n][16]
    __half2*      hw2  = (__half2*)     alloc((size_t)NN * COUT * 2);
    __half2*      hw3  = (__half2*)     alloc((size_t)NN * COUT * 2);
    float*        pmax = (float*)       alloc((size_t)3 * BB * COUT * 4);
    float*        psum = (float*)       alloc((size_t)BB * COUT * 4);

    // setup-only buffers aliased into hw2 (dead before hw2's first write)
    int* deg    = (int*)hw2;
    int* cursor = ((int*)hw2) + NN;
    int* bsum   = ((int*)hw2) + 2 * NN;

    // structure (time-invariant)
    init_deg<<<NBLK, 256, 0, stream>>>(deg, cursor);
    count_deg<<<(EE + 255) / 256, 256, 0, stream>>>(dst, deg);
    compute_dinv<<<NBLK, 256, 0, stream>>>(deg, dinv);
    scan_blocks<<<NBLK, SCAN_B, 0, stream>>>(deg, off, bsum);
    scan_sums<<<1, SCAN_B, 0, stream>>>(bsum, off);
    scan_add<<<NBLK, SCAN_B, 0, stream>>>(off, bsum);
    fill_csr<<<(EE + 255) / 256, 256, 0, stream>>>(src, dst, off, cursor, dinv, csrp);
    scratch_init<<<(3 * BB * COUT + 255) / 256, 256, 0, stream>>>(pmax, psum);
    transpose_x<<<NN / 4, 256, 0, stream>>>(x, xhT);

    for (int t = 0; t < TT; ++t) {
        const __half2* xt = xhT + (size_t)t * NN * 16;
        fused_l1<<<NN / 4, 256, 0, stream>>>(xt, off, csrp, dinv, W1, b1, W2,
                                             hw2, pmax, psum);
        agg_fused<1><<<NN / 4, 256, 0, stream>>>(hw2, off, csrp, dinv, b2, W3, hw3,
                                                 pmax + BB * COUT, psum);
        agg_fused<0><<<NN / 4, 256, 0, stream>>>(hw3, off, csrp, dinv, b3, nullptr, nullptr,
                                                 pmax + 2 * BB * COUT, psum);
        fold<<<(BB * COUT + 255) / 256, 256, 0, stream>>>(pmax, psum, out, t, pmax);
    }
}

// Round 8
// 1227.777 us; speedup vs baseline: 2.6557x; 1.0926x over previous
//
#include <hip/hip_runtime.h>
#include <hip/hip_fp16.h>
#include <math.h>

#define NN 50000
#define EE 800000
#define BB 250
#define TT 8
#define CIN 32
#define COUT 64
#define NPG 200          // nodes per graph (N/B)
#define SCAN_B 256
#define NBLK 196         // ceil(50000/256)

// pack/unpack CSR entry: low 16 = src node (NN<65536), high 16 = fp16 weight
__device__ __forceinline__ float unpack_w(unsigned int v) {
    union { unsigned short u; __half h; } cv;
    cv.u = (unsigned short)(v >> 16);
    return __half2float(cv.h);
}

// ---------------- setup kernels (graph structure, once per call) ----------------

__global__ void init_deg(int* deg, int* cursor) {
    int n = blockIdx.x * 256 + threadIdx.x;
    if (n < NN) { deg[n] = 1; cursor[n] = 0; }   // self-loop contributes 1
}

__global__ void count_deg(const int* dst, int* deg) {
    int e = blockIdx.x * 256 + threadIdx.x;
    if (e < EE) atomicAdd(&deg[dst[e]], 1);
}

__global__ void compute_dinv(const int* deg, float* dinv) {
    int n = blockIdx.x * 256 + threadIdx.x;
    if (n < NN) dinv[n] = rsqrtf((float)deg[n]);
}

__global__ void scan_blocks(const int* deg, int* off, int* bsum) {
    __shared__ int sh[SCAN_B];
    int gid = blockIdx.x * SCAN_B + threadIdx.x;
    int v = (gid < NN) ? (deg[gid] - 1) : 0;
    sh[threadIdx.x] = v;
    __syncthreads();
    for (int s = 1; s < SCAN_B; s <<= 1) {
        int add = (threadIdx.x >= s) ? sh[threadIdx.x - s] : 0;
        __syncthreads();
        sh[threadIdx.x] += add;
        __syncthreads();
    }
    if (gid < NN) off[gid] = sh[threadIdx.x] - v;       // exclusive
    if (threadIdx.x == SCAN_B - 1) bsum[blockIdx.x] = sh[threadIdx.x];
}

__global__ void scan_sums(int* bsum, int* off) {
    __shared__ int sh[SCAN_B];
    int v = (threadIdx.x < NBLK) ? bsum[threadIdx.x] : 0;
    sh[threadIdx.x] = v;
    __syncthreads();
    for (int s = 1; s < SCAN_B; s <<= 1) {
        int add = (threadIdx.x >= s) ? sh[threadIdx.x - s] : 0;
        __syncthreads();
        sh[threadIdx.x] += add;
        __syncthreads();
    }
    if (threadIdx.x < NBLK) bsum[threadIdx.x] = sh[threadIdx.x] - v;  // exclusive
    if (threadIdx.x == 0) off[NN] = EE;
}

__global__ void scan_add(int* off, const int* bsum) {
    int gid = blockIdx.x * SCAN_B + threadIdx.x;
    if (gid < NN) off[gid] += bsum[blockIdx.x];
}

__global__ void fill_csr(const int* src, const int* dst, const int* off,
                         int* cursor, const float* dinv, unsigned int* csrp) {
    int e = blockIdx.x * 256 + threadIdx.x;
    if (e >= EE) return;
    int s = src[e], d = dst[e];
    int p = atomicAdd(&cursor[d], 1);
    union { __half h; unsigned short u; } cv;
    cv.h = __float2half(dinv[s] * dinv[d]);
    csrp[off[d] + p] = (unsigned int)s | ((unsigned int)cv.u << 16);
}

__global__ void scratch_init(float* pmax, float* psum) {
    int i = blockIdx.x * 256 + threadIdx.x;
    if (i < 3 * BB * COUT) pmax[i] = 0.f;
    if (i < BB * COUT) psum[i] = 0.f;
}

// ---------------- compute kernels ----------------

// ONE pass over edges: xa2[t][n][16 half2] = A_hat x (all 8 t), fp16 out.
// One wave per node; lane l holds float4 = contiguous fp32 row elems [4l,4l+4).
__global__ void agg_x_allT16(const float* __restrict__ x, const int* __restrict__ off,
                             const unsigned int* __restrict__ csrp,
                             const float* __restrict__ dinv, __half2* __restrict__ xa2) {
    int lane = threadIdx.x & 63;
    int w = threadIdx.x >> 6;
    int n = blockIdx.x * 4 + w;
    float dn = dinv[n];
    float sw = dn * dn;
    float4 v = ((const float4*)(x + (size_t)n * 256))[lane];
    float4 acc = make_float4(sw * v.x, sw * v.y, sw * v.z, sw * v.w);
    int e0 = off[n], e1 = off[n + 1];
    int j = e0;
    for (; j + 3 < e1; j += 4) {
        unsigned int p0 = csrp[j],     p1 = csrp[j + 1];
        unsigned int p2 = csrp[j + 2], p3 = csrp[j + 3];
        float4 u0 = ((const float4*)(x + (size_t)(p0 & 0xffff) * 256))[lane];
        float4 u1 = ((const float4*)(x + (size_t)(p1 & 0xffff) * 256))[lane];
        float4 u2 = ((const float4*)(x + (size_t)(p2 & 0xffff) * 256))[lane];
        float4 u3 = ((const float4*)(x + (size_t)(p3 & 0xffff) * 256))[lane];
        float w0 = unpack_w(p0), w1 = unpack_w(p1);
        float w2 = unpack_w(p2), w3 = unpack_w(p3);
        acc.x = fmaf(w0, u0.x, acc.x); acc.y = fmaf(w0, u0.y, acc.y);
        acc.z = fmaf(w0, u0.z, acc.z); acc.w = fmaf(w0, u0.w, acc.w);
        acc.x = fmaf(w1, u1.x, acc.x); acc.y = fmaf(w1, u1.y, acc.y);
        acc.z = fmaf(w1, u1.z, acc.z); acc.w = fmaf(w1, u1.w, acc.w);
        acc.x = fmaf(w2, u2.x, acc.x); acc.y = fmaf(w2, u2.y, acc.y);
        acc.z = fmaf(w2, u2.z, acc.z); acc.w = fmaf(w2, u2.w, acc.w);
        acc.x = fmaf(w3, u3.x, acc.x); acc.y = fmaf(w3, u3.y, acc.y);
        acc.z = fmaf(w3, u3.z, acc.z); acc.w = fmaf(w3, u3.w, acc.w);
    }
    for (; j < e1; ++j) {
        unsigned int p = csrp[j];
        float wj = unpack_w(p);
        float4 u = ((const float4*)(x + (size_t)(p & 0xffff) * 256))[lane];
        acc.x = fmaf(wj, u.x, acc.x); acc.y = fmaf(wj, u.y, acc.y);
        acc.z = fmaf(wj, u.z, acc.z); acc.w = fmaf(wj, u.w, acc.w);
    }
    // element flat idx f = 4*lane+k -> (c = f>>3, t = f&7)
    __shared__ float sh[4][TT][33];
    float av[4] = {acc.x, acc.y, acc.z, acc.w};
    #pragma unroll
    for (int k = 0; k < 4; ++k) {
        int f = 4 * lane + k;
        sh[w][f & 7][f >> 3] = av[k];
    }
    __syncthreads();
    // 8t x 4n x 16 pairs = 512 half2 writes; 256B contiguous per (t, 4-node) group
    for (int i = threadIdx.x; i < 512; i += 256) {
        int t = i >> 6;
        int r = i & 63;
        int nl = r >> 4;
        int pp = r & 15;
        xa2[((size_t)t * NN + blockIdx.x * 4 + nl) * 16 + pp] =
            __floats2half2_rn(sh[nl][t][2 * pp], sh[nl][t][2 * pp + 1]);
    }
}

// Row-local layer 1: h1 = relu(xa_t W1 + b1), pool, hw2 = h1 W2.
// Block = 4 nodes x 64 outch.
__global__ void l1mat(const __half2* __restrict__ xa, const float* __restrict__ W1,
                      const float* __restrict__ b1, const float* __restrict__ W2,
                      __half2* __restrict__ hw2,
                      float* __restrict__ pmax, float* __restrict__ psum) {
    __shared__ float W1s[CIN * COUT];     // 8 KB
    __shared__ float W2s[COUT * COUT];    // 16 KB
    __shared__ float Xs[4][CIN];
    __shared__ float tile[4][COUT];
    for (int i = threadIdx.x; i < CIN * COUT; i += 256) W1s[i] = W1[i];
    for (int i = threadIdx.x; i < COUT * COUT; i += 256) W2s[i] = W2[i];
    if (threadIdx.x < 64) {
        int nl = threadIdx.x >> 4, pp = threadIdx.x & 15;
        float2 v = __half22float2(xa[((size_t)blockIdx.x * 4 + nl) * 16 + pp]);
        Xs[nl][2 * pp] = v.x;
        Xs[nl][2 * pp + 1] = v.y;
    }
    __syncthreads();
    int co = threadIdx.x & 63;
    int nl = threadIdx.x >> 6;
    float acc = b1[co];
    #pragma unroll
    for (int k = 0; k < CIN; ++k) acc = fmaf(Xs[nl][k], W1s[k * COUT + co], acc);
    acc = fmaxf(acc, 0.f);
    tile[nl][co] = acc;
    __syncthreads();
    if (threadIdx.x < 64) {
        int c = threadIdx.x;
        float m = fmaxf(fmaxf(tile[0][c], tile[1][c]), fmaxf(tile[2][c], tile[3][c]));
        float s = tile[0][c] + tile[1][c] + tile[2][c] + tile[3][c];
        int g = blockIdx.x / 50;
        atomicMax((int*)&pmax[g * COUT + c], __float_as_int(m));
        atomicAdd(&psum[g * COUT + c], s);
    }
    if (threadIdx.x < 128) {
        int nl2 = threadIdx.x >> 5;
        int pr = threadIdx.x & 31;
        float a0 = 0.f, a1 = 0.f;
        #pragma unroll
        for (int k = 0; k < COUT; ++k) {
            float xv = tile[nl2][k];
            a0 = fmaf(xv, W2s[k * COUT + 2 * pr], a0);
            a1 = fmaf(xv, W2s[k * COUT + 2 * pr + 1], a1);
        }
        hw2[((size_t)blockIdx.x * 4 + nl2) * 32 + pr] = __floats2half2_rn(a0, a1);
    }
}

// Layers 2/3 fused: h = relu(A_hat hw_in + b), pool; if FUSE: hw_out = h W.
// Block = 4 nodes x 64 lanes; gather lane = (pair p 0..31, parity 0..1).
// 8/4/2/1-deep MLP tiers on the parity walk.
template <int FUSE>
__global__ void agg_fused(const __half2* __restrict__ hw_in, const int* __restrict__ off,
                          const unsigned int* __restrict__ csrp,
                          const float* __restrict__ dinv, const float* __restrict__ b,
                          const float* __restrict__ W, __half2* __restrict__ hw_out,
                          float* __restrict__ pmax, float* __restrict__ psum) {
    __shared__ float Ws[FUSE ? COUT * COUT : 1];
    __shared__ float tile[4][COUT];
    if (FUSE)
        for (int i = threadIdx.x; i < COUT * COUT; i += 256) Ws[i] = W[i];

    int lane = threadIdx.x & 63;
    int p = lane & 31;
    int par = lane >> 5;
    int w = threadIdx.x >> 6;
    int n = blockIdx.x * 4 + w;
    int e0 = off[n], e1 = off[n + 1];
    float ax = 0.f, ay = 0.f;
    int j = e0 + par;
    for (; j + 14 < e1; j += 16) {        // 8-deep per parity
        unsigned int c0 = csrp[j],      c1 = csrp[j + 2];
        unsigned int c2 = csrp[j + 4],  c3 = csrp[j + 6];
        unsigned int c4 = csrp[j + 8],  c5 = csrp[j + 10];
        unsigned int c6 = csrp[j + 12], c7 = csrp[j + 14];
        float2 v0 = __half22float2(hw_in[(size_t)(c0 & 0xffff) * 32 + p]);
        float2 v1 = __half22float2(hw_in[(size_t)(c1 & 0xffff) * 32 + p]);
        float2 v2 = __half22float2(hw_in[(size_t)(c2 & 0xffff) * 32 + p]);
        float2 v3 = __half22float2(hw_in[(size_t)(c3 & 0xffff) * 32 + p]);
        float2 v4 = __half22float2(hw_in[(size_t)(c4 & 0xffff) * 32 + p]);
        float2 v5 = __half22float2(hw_in[(size_t)(c5 & 0xffff) * 32 + p]);
        float2 v6 = __half22float2(hw_in[(size_t)(c6 & 0xffff) * 32 + p]);
        float2 v7 = __half22float2(hw_in[(size_t)(c7 & 0xffff) * 32 + p]);
        float w0 = unpack_w(c0), w1 = unpack_w(c1), w2 = unpack_w(c2), w3 = unpack_w(c3);
        float w4 = unpack_w(c4), w5 = unpack_w(c5), w6 = unpack_w(c6), w7 = unpack_w(c7);
        ax = fmaf(w0, v0.x, ax); ay = fmaf(w0, v0.y, ay);
        ax = fmaf(w1, v1.x, ax); ay = fmaf(w1, v1.y, ay);
        ax = fmaf(w2, v2.x, ax); ay = fmaf(w2, v2.y, ay);
        ax = fmaf(w3, v3.x, ax); ay = fmaf(w3, v3.y, ay);
        ax = fmaf(w4, v4.x, ax); ay = fmaf(w4, v4.y, ay);
        ax = fmaf(w5, v5.x, ax); ay = fmaf(w5, v5.y, ay);
        ax = fmaf(w6, v6.x, ax); ay = fmaf(w6, v6.y, ay);
        ax = fmaf(w7, v7.x, ax); ay = fmaf(w7, v7.y, ay);
    }
    for (; j + 6 < e1; j += 8) {          // 4-deep
        unsigned int c0 = csrp[j],     c1 = csrp[j + 2];
        unsigned int c2 = csrp[j + 4], c3 = csrp[j + 6];
        float2 v0 = __half22float2(hw_in[(size_t)(c0 & 0xffff) * 32 + p]);
        float2 v1 = __half22float2(hw_in[(size_t)(c1 & 0xffff) * 32 + p]);
        float2 v2 = __half22float2(hw_in[(size_t)(c2 & 0xffff) * 32 + p]);
        float2 v3 = __half22float2(hw_in[(size_t)(c3 & 0xffff) * 32 + p]);
        float w0 = unpack_w(c0), w1 = unpack_w(c1);
        float w2 = unpack_w(c2), w3 = unpack_w(c3);
        ax = fmaf(w0, v0.x, ax); ay = fmaf(w0, v0.y, ay);
        ax = fmaf(w1, v1.x, ax); ay = fmaf(w1, v1.y, ay);
        ax = fmaf(w2, v2.x, ax); ay = fmaf(w2, v2.y, ay);
        ax = fmaf(w3, v3.x, ax); ay = fmaf(w3, v3.y, ay);
    }
    for (; j + 2 < e1; j += 4) {          // 2-deep
        unsigned int c0 = csrp[j], c1 = csrp[j + 2];
        float2 v0 = __half22float2(hw_in[(size_t)(c0 & 0xffff) * 32 + p]);
        float2 v1 = __half22float2(hw_in[(size_t)(c1 & 0xffff) * 32 + p]);
        float w0 = unpack_w(c0), w1 = unpack_w(c1);
        ax = fmaf(w0, v0.x, ax); ay = fmaf(w0, v0.y, ay);
        ax = fmaf(w1, v1.x, ax); ay = fmaf(w1, v1.y, ay);
    }
    for (; j < e1; j += 2) {
        unsigned int c = csrp[j];
        float wv = unpack_w(c);
        float2 v = __half22float2(hw_in[(size_t)(c & 0xffff) * 32 + p]);
        ax = fmaf(wv, v.x, ax); ay = fmaf(wv, v.y, ay);
    }
    ax += __shfl_xor(ax, 32, 64);
    ay += __shfl_xor(ay, 32, 64);
    if (par == 0) {
        float dn = dinv[n];
        float sw = dn * dn;
        float2 sv = __half22float2(hw_in[(size_t)n * 32 + p]);
        tile[w][2 * p]     = fmaxf(fmaf(sw, sv.x, ax) + b[2 * p], 0.f);
        tile[w][2 * p + 1] = fmaxf(fmaf(sw, sv.y, ay) + b[2 * p + 1], 0.f);
    }
    __syncthreads();
    if (threadIdx.x < 64) {
        int c = threadIdx.x;
        float m = fmaxf(fmaxf(tile[0][c], tile[1][c]), fmaxf(tile[2][c], tile[3][c]));
        float s = tile[0][c] + tile[1][c] + tile[2][c] + tile[3][c];
        int g = blockIdx.x / 50;
        atomicMax((int*)&pmax[g * COUT + c], __float_as_int(m));
        atomicAdd(&psum[g * COUT + c], s);
    }
    if (FUSE && threadIdx.x < 128) {
        int nl2 = threadIdx.x >> 5;
        int pr = threadIdx.x & 31;
        float a0 = 0.f, a1 = 0.f;
        #pragma unroll
        for (int k = 0; k < COUT; ++k) {
            float xv = tile[nl2][k];
            a0 = fmaf(xv, Ws[k * COUT + 2 * pr], a0);
            a1 = fmaf(xv, Ws[k * COUT + 2 * pr + 1], a1);
        }
        hw_out[((size_t)blockIdx.x * 4 + nl2) * 32 + pr] = __floats2half2_rn(a0, a1);
    }
}

// fold scratch -> out[:, :, t], then reset scratch for next t
__global__ void fold(const float* __restrict__ pmax, float* __restrict__ psum,
                     float* __restrict__ out, int t, float* pmax_mut) {
    int i = blockIdx.x * 256 + threadIdx.x;
    if (i >= BB * COUT) return;
    int g = i >> 6, c = i & 63;
    float m = pmax[i] + pmax[BB * COUT + i] + pmax[2 * BB * COUT + i];
    float mean = psum[i] * (1.0f / NPG);
    out[((size_t)g * 128 + c) * TT + t] = m;
    out[((size_t)g * 128 + 64 + c) * TT + t] = mean;
    pmax_mut[i] = 0.f;
    pmax_mut[BB * COUT + i] = 0.f;
    pmax_mut[2 * BB * COUT + i] = 0.f;
    psum[i] = 0.f;
}

// ---------------- launch ----------------

extern "C" void kernel_launch(void* const* d_in, const int* in_sizes, int n_in,
                              void* d_out, int out_size, void* d_ws, size_t ws_size,
                              hipStream_t stream) {
    const float* x   = (const float*)d_in[0];
    const int*   ei  = (const int*)d_in[1];
    const int*   src = ei;
    const int*   dst = ei + EE;
    const float* W1  = (const float*)d_in[3];
    const float* b1  = (const float*)d_in[4];
    const float* W2  = (const float*)d_in[5];
    const float* b2  = (const float*)d_in[6];
    const float* W3  = (const float*)d_in[7];
    const float* b3  = (const float*)d_in[8];
    float* out = (float*)d_out;

    char* wsp = (char*)d_ws;
    auto alloc = [&](size_t bytes) {
        char* p = wsp;
        wsp += (bytes + 255) & ~(size_t)255;
        return p;
    };
    // total ~42.3 MB (known-safe footprint)
    float*        dinv = (float*)       alloc((size_t)NN * 4);
    int*          off  = (int*)         alloc((size_t)(NN + 1) * 4);
    unsigned int* csrp = (unsigned int*)alloc((size_t)EE * 4);
    __half2*      xa2  = (__half2*)     alloc((size_t)NN * CIN * TT * 2);  // [t][n][16]
    __half2*      hw2  = (__half2*)     alloc((size_t)NN * COUT * 2);
    __half2*      hw3  = (__half2*)     alloc((size_t)NN * COUT * 2);
    float*        pmax = (float*)       alloc((size_t)3 * BB * COUT * 4);
    float*        psum = (float*)       alloc((size_t)BB * COUT * 4);

    // setup-only buffers aliased into hw2 (dead before hw2's first write)
    int* deg    = (int*)hw2;
    int* cursor = ((int*)hw2) + NN;
    int* bsum   = ((int*)hw2) + 2 * NN;

    // structure (time-invariant)
    init_deg<<<NBLK, 256, 0, stream>>>(deg, cursor);
    count_deg<<<(EE + 255) / 256, 256, 0, stream>>>(dst, deg);
    compute_dinv<<<NBLK, 256, 0, stream>>>(deg, dinv);
    scan_blocks<<<NBLK, SCAN_B, 0, stream>>>(deg, off, bsum);
    scan_sums<<<1, SCAN_B, 0, stream>>>(bsum, off);
    scan_add<<<NBLK, SCAN_B, 0, stream>>>(off, bsum);
    fill_csr<<<(EE + 255) / 256, 256, 0, stream>>>(src, dst, off, cursor, dinv, csrp);
    scratch_init<<<(3 * BB * COUT + 255) / 256, 256, 0, stream>>>(pmax, psum);

    // layer-1 aggregation for ALL t in one edge pass
    agg_x_allT16<<<NN / 4, 256, 0, stream>>>(x, off, csrp, dinv, xa2);

    for (int t = 0; t < TT; ++t) {
        const __half2* xt = xa2 + (size_t)t * NN * 16;
        l1mat<<<NN / 4, 256, 0, stream>>>(xt, W1, b1, W2, hw2, pmax, psum);
        agg_fused<1><<<NN / 4, 256, 0, stream>>>(hw2, off, csrp, dinv, b2, W3, hw3,
                                                 pmax + BB * COUT, psum);
        agg_fused<0><<<NN / 4, 256, 0, stream>>>(hw3, off, csrp, dinv, b3, nullptr, nullptr,
                                                 pmax + 2 * BB * COUT, psum);
        fold<<<(BB * COUT + 255) / 256, 256, 0, stream>>>(pmax, psum, out, t, pmax);
    }
}

// Round 9
// 879.446 us; speedup vs baseline: 3.7076x; 1.3961x over previous
//
#include <hip/hip_runtime.h>
#include <hip/hip_fp16.h>
#include <math.h>

#define NN 50000
#define EE 800000
#define BB 250
#define TT 8
#define CIN 32
#define COUT 64
#define NPG 200          // nodes per graph (N/B)
#define SCAN_B 256
#define NBLK 196         // ceil(50000/256)
#define GC (BB * COUT)   // 16000 floats per pool slab

// pack/unpack CSR entry: low 16 = src node (NN<65536), high 16 = fp16 weight
__device__ __forceinline__ float unpack_w(unsigned int v) {
    union { unsigned short u; __half h; } cv;
    cv.u = (unsigned short)(v >> 16);
    return __half2float(cv.h);
}

// ---------------- setup kernels (graph structure, once per call) ----------------

__global__ void init_deg(int* deg, int* cursor) {
    int n = blockIdx.x * 256 + threadIdx.x;
    if (n < NN) { deg[n] = 1; cursor[n] = 0; }
}

__global__ void count_deg(const int* dst, int* deg) {
    int e = blockIdx.x * 256 + threadIdx.x;
    if (e < EE) atomicAdd(&deg[dst[e]], 1);
}

__global__ void compute_dinv(const int* deg, float* dinv) {
    int n = blockIdx.x * 256 + threadIdx.x;
    if (n < NN) dinv[n] = rsqrtf((float)deg[n]);
}

__global__ void scan_blocks(const int* deg, int* off, int* bsum) {
    __shared__ int sh[SCAN_B];
    int gid = blockIdx.x * SCAN_B + threadIdx.x;
    int v = (gid < NN) ? (deg[gid] - 1) : 0;
    sh[threadIdx.x] = v;
    __syncthreads();
    for (int s = 1; s < SCAN_B; s <<= 1) {
        int add = (threadIdx.x >= s) ? sh[threadIdx.x - s] : 0;
        __syncthreads();
        sh[threadIdx.x] += add;
        __syncthreads();
    }
    if (gid < NN) off[gid] = sh[threadIdx.x] - v;
    if (threadIdx.x == SCAN_B - 1) bsum[blockIdx.x] = sh[threadIdx.x];
}

__global__ void scan_sums(int* bsum, int* off) {
    __shared__ int sh[SCAN_B];
    int v = (threadIdx.x < NBLK) ? bsum[threadIdx.x] : 0;
    sh[threadIdx.x] = v;
    __syncthreads();
    for (int s = 1; s < SCAN_B; s <<= 1) {
        int add = (threadIdx.x >= s) ? sh[threadIdx.x - s] : 0;
        __syncthreads();
        sh[threadIdx.x] += add;
        __syncthreads();
    }
    if (threadIdx.x < NBLK) bsum[threadIdx.x] = sh[threadIdx.x] - v;
    if (threadIdx.x == 0) off[NN] = EE;
}

__global__ void scan_add(int* off, const int* bsum) {
    int gid = blockIdx.x * SCAN_B + threadIdx.x;
    if (gid < NN) off[gid] += bsum[blockIdx.x];
}

__global__ void fill_csr(const int* src, const int* dst, const int* off,
                         int* cursor, const float* dinv, unsigned int* csrp) {
    int e = blockIdx.x * 256 + threadIdx.x;
    if (e >= EE) return;
    int s = src[e], d = dst[e];
    int p = atomicAdd(&cursor[d], 1);
    union { __half h; unsigned short u; } cv;
    cv.h = __float2half(dinv[s] * dinv[d]);
    csrp[off[d] + p] = (unsigned int)s | ((unsigned int)cv.u << 16);
}

__global__ void scratch_init(float* scr, int ntot) {
    int i = blockIdx.x * 256 + threadIdx.x;
    if (i < ntot) scr[i] = 0.f;
}

// ---------------- compute kernels ----------------

// ONE pass over edges: xa2[t][n][16 half2] = A_hat x (all 8 t), fp16 out.
__global__ void agg_x_allT16(const float* __restrict__ x, const int* __restrict__ off,
                             const unsigned int* __restrict__ csrp,
                             const float* __restrict__ dinv, __half2* __restrict__ xa2) {
    int lane = threadIdx.x & 63;
    int w = threadIdx.x >> 6;
    int n = blockIdx.x * 4 + w;
    float dn = dinv[n];
    float sw = dn * dn;
    float4 v = ((const float4*)(x + (size_t)n * 256))[lane];
    float4 acc = make_float4(sw * v.x, sw * v.y, sw * v.z, sw * v.w);
    int e0 = off[n], e1 = off[n + 1];
    int j = e0;
    for (; j + 3 < e1; j += 4) {
        unsigned int p0 = csrp[j],     p1 = csrp[j + 1];
        unsigned int p2 = csrp[j + 2], p3 = csrp[j + 3];
        float4 u0 = ((const float4*)(x + (size_t)(p0 & 0xffff) * 256))[lane];
        float4 u1 = ((const float4*)(x + (size_t)(p1 & 0xffff) * 256))[lane];
        float4 u2 = ((const float4*)(x + (size_t)(p2 & 0xffff) * 256))[lane];
        float4 u3 = ((const float4*)(x + (size_t)(p3 & 0xffff) * 256))[lane];
        float w0 = unpack_w(p0), w1 = unpack_w(p1);
        float w2 = unpack_w(p2), w3 = unpack_w(p3);
        acc.x = fmaf(w0, u0.x, acc.x); acc.y = fmaf(w0, u0.y, acc.y);
        acc.z = fmaf(w0, u0.z, acc.z); acc.w = fmaf(w0, u0.w, acc.w);
        acc.x = fmaf(w1, u1.x, acc.x); acc.y = fmaf(w1, u1.y, acc.y);
        acc.z = fmaf(w1, u1.z, acc.z); acc.w = fmaf(w1, u1.w, acc.w);
        acc.x = fmaf(w2, u2.x, acc.x); acc.y = fmaf(w2, u2.y, acc.y);
        acc.z = fmaf(w2, u2.z, acc.z); acc.w = fmaf(w2, u2.w, acc.w);
        acc.x = fmaf(w3, u3.x, acc.x); acc.y = fmaf(w3, u3.y, acc.y);
        acc.z = fmaf(w3, u3.z, acc.z); acc.w = fmaf(w3, u3.w, acc.w);
    }
    for (; j < e1; ++j) {
        unsigned int p = csrp[j];
        float wj = unpack_w(p);
        float4 u = ((const float4*)(x + (size_t)(p & 0xffff) * 256))[lane];
        acc.x = fmaf(wj, u.x, acc.x); acc.y = fmaf(wj, u.y, acc.y);
        acc.z = fmaf(wj, u.z, acc.z); acc.w = fmaf(wj, u.w, acc.w);
    }
    __shared__ float sh[4][TT][33];
    float av[4] = {acc.x, acc.y, acc.z, acc.w};
    #pragma unroll
    for (int k = 0; k < 4; ++k) {
        int f = 4 * lane + k;
        sh[w][f & 7][f >> 3] = av[k];
    }
    __syncthreads();
    for (int i = threadIdx.x; i < 512; i += 256) {
        int t = i >> 6;
        int r = i & 63;
        int nl = r >> 4;
        int pp = r & 15;
        xa2[((size_t)t * NN + blockIdx.x * 4 + nl) * 16 + pp] =
            __floats2half2_rn(sh[nl][t][2 * pp], sh[nl][t][2 * pp + 1]);
    }
}

// ===== Tc=1 kernels (round-8 proven; used for chunk 0 in the fallback path) =====

__global__ void l1mat(const __half2* __restrict__ xa, const float* __restrict__ W1,
                      const float* __restrict__ b1, const float* __restrict__ W2,
                      __half2* __restrict__ hw2,
                      float* __restrict__ pmax, float* __restrict__ psum) {
    __shared__ float W1s[CIN * COUT];
    __shared__ float W2s[COUT * COUT];
    __shared__ float Xs[4][CIN];
    __shared__ float tile[4][COUT];
    for (int i = threadIdx.x; i < CIN * COUT; i += 256) W1s[i] = W1[i];
    for (int i = threadIdx.x; i < COUT * COUT; i += 256) W2s[i] = W2[i];
    if (threadIdx.x < 64) {
        int nl = threadIdx.x >> 4, pp = threadIdx.x & 15;
        float2 v = __half22float2(xa[((size_t)blockIdx.x * 4 + nl) * 16 + pp]);
        Xs[nl][2 * pp] = v.x;
        Xs[nl][2 * pp + 1] = v.y;
    }
    __syncthreads();
    int co = threadIdx.x & 63;
    int nl = threadIdx.x >> 6;
    float acc = b1[co];
    #pragma unroll
    for (int k = 0; k < CIN; ++k) acc = fmaf(Xs[nl][k], W1s[k * COUT + co], acc);
    acc = fmaxf(acc, 0.f);
    tile[nl][co] = acc;
    __syncthreads();
    if (threadIdx.x < 64) {
        int c = threadIdx.x;
        float m = fmaxf(fmaxf(tile[0][c], tile[1][c]), fmaxf(tile[2][c], tile[3][c]));
        float s = tile[0][c] + tile[1][c] + tile[2][c] + tile[3][c];
        int g = blockIdx.x / 50;
        atomicMax((int*)&pmax[g * COUT + c], __float_as_int(m));
        atomicAdd(&psum[g * COUT + c], s);
    }
    if (threadIdx.x < 128) {
        int nl2 = threadIdx.x >> 5;
        int pr = threadIdx.x & 31;
        float a0 = 0.f, a1 = 0.f;
        #pragma unroll
        for (int k = 0; k < COUT; ++k) {
            float xv = tile[nl2][k];
            a0 = fmaf(xv, W2s[k * COUT + 2 * pr], a0);
            a1 = fmaf(xv, W2s[k * COUT + 2 * pr + 1], a1);
        }
        hw2[((size_t)blockIdx.x * 4 + nl2) * 32 + pr] = __floats2half2_rn(a0, a1);
    }
}

template <int FUSE>
__global__ void agg_fused(const __half2* __restrict__ hw_in, const int* __restrict__ off,
                          const unsigned int* __restrict__ csrp,
                          const float* __restrict__ dinv, const float* __restrict__ b,
                          const float* __restrict__ W, __half2* __restrict__ hw_out,
                          float* __restrict__ pmax, float* __restrict__ psum) {
    __shared__ float Ws[FUSE ? COUT * COUT : 1];
    __shared__ float tile[4][COUT];
    if (FUSE)
        for (int i = threadIdx.x; i < COUT * COUT; i += 256) Ws[i] = W[i];
    int lane = threadIdx.x & 63;
    int p = lane & 31;
    int par = lane >> 5;
    int w = threadIdx.x >> 6;
    int n = blockIdx.x * 4 + w;
    int e0 = off[n], e1 = off[n + 1];
    float ax = 0.f, ay = 0.f;
    int j = e0 + par;
    for (; j + 6 < e1; j += 8) {
        unsigned int c0 = csrp[j],     c1 = csrp[j + 2];
        unsigned int c2 = csrp[j + 4], c3 = csrp[j + 6];
        float2 v0 = __half22float2(hw_in[(size_t)(c0 & 0xffff) * 32 + p]);
        float2 v1 = __half22float2(hw_in[(size_t)(c1 & 0xffff) * 32 + p]);
        float2 v2 = __half22float2(hw_in[(size_t)(c2 & 0xffff) * 32 + p]);
        float2 v3 = __half22float2(hw_in[(size_t)(c3 & 0xffff) * 32 + p]);
        float w0 = unpack_w(c0), w1 = unpack_w(c1);
        float w2 = unpack_w(c2), w3 = unpack_w(c3);
        ax = fmaf(w0, v0.x, ax); ay = fmaf(w0, v0.y, ay);
        ax = fmaf(w1, v1.x, ax); ay = fmaf(w1, v1.y, ay);
        ax = fmaf(w2, v2.x, ax); ay = fmaf(w2, v2.y, ay);
        ax = fmaf(w3, v3.x, ax); ay = fmaf(w3, v3.y, ay);
    }
    for (; j < e1; j += 2) {
        unsigned int c = csrp[j];
        float wv = unpack_w(c);
        float2 v = __half22float2(hw_in[(size_t)(c & 0xffff) * 32 + p]);
        ax = fmaf(wv, v.x, ax); ay = fmaf(wv, v.y, ay);
    }
    ax += __shfl_xor(ax, 32, 64);
    ay += __shfl_xor(ay, 32, 64);
    if (par == 0) {
        float dn = dinv[n];
        float sw = dn * dn;
        float2 sv = __half22float2(hw_in[(size_t)n * 32 + p]);
        tile[w][2 * p]     = fmaxf(fmaf(sw, sv.x, ax) + b[2 * p], 0.f);
        tile[w][2 * p + 1] = fmaxf(fmaf(sw, sv.y, ay) + b[2 * p + 1], 0.f);
    }
    __syncthreads();
    if (threadIdx.x < 64) {
        int c = threadIdx.x;
        float m = fmaxf(fmaxf(tile[0][c], tile[1][c]), fmaxf(tile[2][c], tile[3][c]));
        float s = tile[0][c] + tile[1][c] + tile[2][c] + tile[3][c];
        int g = blockIdx.x / 50;
        atomicMax((int*)&pmax[g * COUT + c], __float_as_int(m));
        atomicAdd(&psum[g * COUT + c], s);
    }
    if (FUSE && threadIdx.x < 128) {
        int nl2 = threadIdx.x >> 5;
        int pr = threadIdx.x & 31;
        float a0 = 0.f, a1 = 0.f;
        #pragma unroll
        for (int k = 0; k < COUT; ++k) {
            float xv = tile[nl2][k];
            a0 = fmaf(xv, Ws[k * COUT + 2 * pr], a0);
            a1 = fmaf(xv, Ws[k * COUT + 2 * pr + 1], a1);
        }
        hw_out[((size_t)blockIdx.x * 4 + nl2) * 32 + pr] = __floats2half2_rn(a0, a1);
    }
}

__global__ void fold1(float* __restrict__ pmax, float* __restrict__ psum,
                      float* __restrict__ out, int t) {
    int i = blockIdx.x * 256 + threadIdx.x;
    if (i >= GC) return;
    int g = i >> 6, c = i & 63;
    float m = pmax[i] + pmax[GC + i] + pmax[2 * GC + i];
    float mean = psum[i] * (1.0f / NPG);
    out[((size_t)g * 128 + c) * TT + t] = m;
    out[((size_t)g * 128 + 64 + c) * TT + t] = mean;
    pmax[i] = 0.f;
    pmax[GC + i] = 0.f;
    pmax[2 * GC + i] = 0.f;
    psum[i] = 0.f;
}

// ===== Tc=2 kernels =====

// h1 = relu(xa[t0..t0+1] W1 + b1), pool, hw2[tc][n] = h1 W2 (half2 weights in LDS)
__global__ void l1mat2(const __half2* __restrict__ xa, const float* __restrict__ W1,
                       const float* __restrict__ b1, const float* __restrict__ W2,
                       __half2* __restrict__ hw2,
                       float* __restrict__ pmax, float* __restrict__ psum) {
    __shared__ float W1s[CIN * COUT];      // 8 KB
    __shared__ __half2 W2s[COUT * 32];     // 8 KB
    __shared__ float Xs[4][2][CIN];
    __shared__ float tile[4][2][COUT];
    for (int i = threadIdx.x; i < CIN * COUT; i += 256) W1s[i] = W1[i];
    for (int i = threadIdx.x; i < COUT * 32; i += 256) {
        int k = i >> 5, pr = i & 31;
        W2s[i] = __floats2half2_rn(W2[k * COUT + 2 * pr], W2[k * COUT + 2 * pr + 1]);
    }
    if (threadIdx.x < 128) {
        int pp = threadIdx.x & 15, tc = (threadIdx.x >> 4) & 1, nl = threadIdx.x >> 5;
        float2 v = __half22float2(
            xa[(size_t)tc * NN * 16 + ((size_t)blockIdx.x * 4 + nl) * 16 + pp]);
        Xs[nl][tc][2 * pp] = v.x;
        Xs[nl][tc][2 * pp + 1] = v.y;
    }
    __syncthreads();
    int co = threadIdx.x & 63;
    int nl = threadIdx.x >> 6;
    float a0 = b1[co], a1 = b1[co];
    #pragma unroll
    for (int k = 0; k < CIN; ++k) {
        float wv = W1s[k * COUT + co];
        a0 = fmaf(Xs[nl][0][k], wv, a0);
        a1 = fmaf(Xs[nl][1][k], wv, a1);
    }
    tile[nl][0][co] = fmaxf(a0, 0.f);
    tile[nl][1][co] = fmaxf(a1, 0.f);
    __syncthreads();
    if (threadIdx.x < 128) {
        int c = threadIdx.x & 63, tc = threadIdx.x >> 6;
        float m = fmaxf(fmaxf(tile[0][tc][c], tile[1][tc][c]),
                        fmaxf(tile[2][tc][c], tile[3][tc][c]));
        float s = tile[0][tc][c] + tile[1][tc][c] + tile[2][tc][c] + tile[3][tc][c];
        int g = blockIdx.x / 50;
        atomicMax((int*)&pmax[tc * GC + g * COUT + c], __float_as_int(m));
        atomicAdd(&psum[tc * GC + g * COUT + c], s);
    }
    {   // W2 matmul: 256 thr = 8 rows (4 nodes x 2 tc) x 32 pairs
        int row = threadIdx.x >> 5;
        int pr = threadIdx.x & 31;
        int nl2 = row >> 1, tc2 = row & 1;
        float b0 = 0.f, bb1 = 0.f;
        #pragma unroll
        for (int k = 0; k < COUT; ++k) {
            float xv = tile[nl2][tc2][k];
            float2 wv = __half22float2(W2s[k * 32 + pr]);
            b0 = fmaf(xv, wv.x, b0);
            bb1 = fmaf(xv, wv.y, bb1);
        }
        hw2[((size_t)tc2 * NN + (size_t)blockIdx.x * 4 + nl2) * 32 + pr] =
            __floats2half2_rn(b0, bb1);
    }
}

// gather 2-t table, relu+bias, pool; if FUSE: out = h W (next layer's table)
template <int FUSE>
__global__ void agg2(const __half2* __restrict__ hin, const int* __restrict__ off,
                     const unsigned int* __restrict__ csrp,
                     const float* __restrict__ dinv, const float* __restrict__ b,
                     const float* __restrict__ W, __half2* __restrict__ hout,
                     float* __restrict__ pmax, float* __restrict__ psum) {
    __shared__ __half2 Ws[FUSE ? COUT * 32 : 1];
    __shared__ float tile[4][2][COUT];
    if (FUSE)
        for (int i = threadIdx.x; i < COUT * 32; i += 256) {
            int k = i >> 5, pr = i & 31;
            Ws[i] = __floats2half2_rn(W[k * COUT + 2 * pr], W[k * COUT + 2 * pr + 1]);
        }
    int lane = threadIdx.x & 63;
    int p = lane & 31;
    int par = lane >> 5;
    int w = threadIdx.x >> 6;
    int n = blockIdx.x * 4 + w;
    int e0 = off[n], e1 = off[n + 1];
    const __half2* T0 = hin;
    const __half2* T1 = hin + (size_t)NN * 32;
    float ax0 = 0.f, ay0 = 0.f, ax1 = 0.f, ay1 = 0.f;
    int j = e0 + par;
    for (; j + 6 < e1; j += 8) {          // 4-deep x 2 tables = 8 loads in flight
        unsigned int c0 = csrp[j],     c1 = csrp[j + 2];
        unsigned int c2 = csrp[j + 4], c3 = csrp[j + 6];
        size_t s0 = (size_t)(c0 & 0xffff) * 32 + p;
        size_t s1 = (size_t)(c1 & 0xffff) * 32 + p;
        size_t s2 = (size_t)(c2 & 0xffff) * 32 + p;
        size_t s3 = (size_t)(c3 & 0xffff) * 32 + p;
        float2 u0 = __half22float2(T0[s0]);
        float2 u1 = __half22float2(T0[s1]);
        float2 u2 = __half22float2(T0[s2]);
        float2 u3 = __half22float2(T0[s3]);
        float2 v0 = __half22float2(T1[s0]);
        float2 v1 = __half22float2(T1[s1]);
        float2 v2 = __half22float2(T1[s2]);
        float2 v3 = __half22float2(T1[s3]);
        float w0 = unpack_w(c0), w1 = unpack_w(c1);
        float w2 = unpack_w(c2), w3 = unpack_w(c3);
        ax0 = fmaf(w0, u0.x, ax0); ay0 = fmaf(w0, u0.y, ay0);
        ax0 = fmaf(w1, u1.x, ax0); ay0 = fmaf(w1, u1.y, ay0);
        ax0 = fmaf(w2, u2.x, ax0); ay0 = fmaf(w2, u2.y, ay0);
        ax0 = fmaf(w3, u3.x, ax0); ay0 = fmaf(w3, u3.y, ay0);
        ax1 = fmaf(w0, v0.x, ax1); ay1 = fmaf(w0, v0.y, ay1);
        ax1 = fmaf(w1, v1.x, ax1); ay1 = fmaf(w1, v1.y, ay1);
        ax1 = fmaf(w2, v2.x, ax1); ay1 = fmaf(w2, v2.y, ay1);
        ax1 = fmaf(w3, v3.x, ax1); ay1 = fmaf(w3, v3.y, ay1);
    }
    for (; j < e1; j += 2) {
        unsigned int c = csrp[j];
        size_t s = (size_t)(c & 0xffff) * 32 + p;
        float wv = unpack_w(c);
        float2 u = __half22float2(T0[s]);
        float2 v = __half22float2(T1[s]);
        ax0 = fmaf(wv, u.x, ax0); ay0 = fmaf(wv, u.y, ay0);
        ax1 = fmaf(wv, v.x, ax1); ay1 = fmaf(wv, v.y, ay1);
    }
    ax0 += __shfl_xor(ax0, 32, 64);
    ay0 += __shfl_xor(ay0, 32, 64);
    ax1 += __shfl_xor(ax1, 32, 64);
    ay1 += __shfl_xor(ay1, 32, 64);
    if (par == 0) {
        float dn = dinv[n];
        float sw = dn * dn;
        size_t sp = (size_t)n * 32 + p;
        float2 s0 = __half22float2(T0[sp]);
        float2 s1 = __half22float2(T1[sp]);
        tile[w][0][2 * p]     = fmaxf(fmaf(sw, s0.x, ax0) + b[2 * p], 0.f);
        tile[w][0][2 * p + 1] = fmaxf(fmaf(sw, s0.y, ay0) + b[2 * p + 1], 0.f);
        tile[w][1][2 * p]     = fmaxf(fmaf(sw, s1.x, ax1) + b[2 * p], 0.f);
        tile[w][1][2 * p + 1] = fmaxf(fmaf(sw, s1.y, ay1) + b[2 * p + 1], 0.f);
    }
    __syncthreads();
    if (threadIdx.x < 128) {
        int c = threadIdx.x & 63, tc = threadIdx.x >> 6;
        float m = fmaxf(fmaxf(tile[0][tc][c], tile[1][tc][c]),
                        fmaxf(tile[2][tc][c], tile[3][tc][c]));
        float s = tile[0][tc][c] + tile[1][tc][c] + tile[2][tc][c] + tile[3][tc][c];
        int g = blockIdx.x / 50;
        atomicMax((int*)&pmax[tc * GC + g * COUT + c], __float_as_int(m));
        atomicAdd(&psum[tc * GC + g * COUT + c], s);
    }
    if (FUSE) {
        int row = threadIdx.x >> 5;
        int pr = threadIdx.x & 31;
        int nl2 = row >> 1, tc2 = row & 1;
        float b0 = 0.f, bb1 = 0.f;
        #pragma unroll
        for (int k = 0; k < COUT; ++k) {
            float xv = tile[nl2][tc2][k];
            float2 wv = __half22float2(Ws[k * 32 + pr]);
            b0 = fmaf(xv, wv.x, b0);
            bb1 = fmaf(xv, wv.y, bb1);
        }
        hout[((size_t)tc2 * NN + (size_t)blockIdx.x * 4 + nl2) * 32 + pr] =
            __floats2half2_rn(b0, bb1);
    }
}

// fold 2-t scratch -> out[:, :, t0..t0+1], reset
__global__ void fold2(float* __restrict__ pmaxT, float* __restrict__ psumT,
                      float* __restrict__ out, int t0) {
    int i = blockIdx.x * 256 + threadIdx.x;
    if (i >= 2 * GC) return;
    int tc = i / GC;
    int r = i - tc * GC;
    int g = r >> 6, c = r & 63;
    float m = pmaxT[tc * GC + r] + pmaxT[2 * GC + tc * GC + r] +
              pmaxT[4 * GC + tc * GC + r];
    float mean = psumT[i] * (1.0f / NPG);
    int t = t0 + tc;
    out[((size_t)g * 128 + c) * TT + t] = m;
    out[((size_t)g * 128 + 64 + c) * TT + t] = mean;
    pmaxT[tc * GC + r] = 0.f;
    pmaxT[2 * GC + tc * GC + r] = 0.f;
    pmaxT[4 * GC + tc * GC + r] = 0.f;
    psumT[i] = 0.f;
}

// ---------------- launch ----------------

extern "C" void kernel_launch(void* const* d_in, const int* in_sizes, int n_in,
                              void* d_out, int out_size, void* d_ws, size_t ws_size,
                              hipStream_t stream) {
    const float* x   = (const float*)d_in[0];
    const int*   ei  = (const int*)d_in[1];
    const int*   src = ei;
    const int*   dst = ei + EE;
    const float* W1  = (const float*)d_in[3];
    const float* b1  = (const float*)d_in[4];
    const float* W2  = (const float*)d_in[5];
    const float* b2  = (const float*)d_in[6];
    const float* W3  = (const float*)d_in[7];
    const float* b3  = (const float*)d_in[8];
    float* out = (float*)d_out;

    char* wsp = (char*)d_ws;
    auto alloc = [&](size_t bytes) {
        char* p = wsp;
        wsp += (bytes + 255) & ~(size_t)255;
        return p;
    };
    float*        dinv = (float*)       alloc((size_t)NN * 4);
    int*          off  = (int*)         alloc((size_t)(NN + 1) * 4);
    unsigned int* csrp = (unsigned int*)alloc((size_t)EE * 4);
    __half2*      xa2  = (__half2*)     alloc((size_t)NN * 16 * TT * 4);  // 25.6 MB
    __half2*      H1   = (__half2*)     alloc((size_t)2 * NN * 32 * 4);   // 12.8 MB
    float*        scr  = (float*)       alloc((size_t)12 * GC * 4);       // pools
    // scratch carve: [pmaxO 3*GC][psumO GC][pmaxT 6*GC][psumT 2*GC]
    float* pmaxO = scr;
    float* psumO = scr + 3 * GC;
    float* pmaxT = scr + 4 * GC;
    float* psumT = scr + 10 * GC;

    size_t used = (size_t)(wsp - (char*)d_ws);
    bool dedicated = ws_size >= used + (size_t)2 * NN * 32 * 4 + (1u << 20);
    __half2* H2 = dedicated ? (__half2*)alloc((size_t)2 * NN * 32 * 4)
                            : xa2;   // aliases xa slices t=0..3 (fallback)

    // setup-only buffers aliased into H1 (dead before H1's first write)
    int* deg    = (int*)H1;
    int* cursor = ((int*)H1) + NN;
    int* bsum   = ((int*)H1) + 2 * NN;

    init_deg<<<NBLK, 256, 0, stream>>>(deg, cursor);
    count_deg<<<(EE + 255) / 256, 256, 0, stream>>>(dst, deg);
    compute_dinv<<<NBLK, 256, 0, stream>>>(deg, dinv);
    scan_blocks<<<NBLK, SCAN_B, 0, stream>>>(deg, off, bsum);
    scan_sums<<<1, SCAN_B, 0, stream>>>(bsum, off);
    scan_add<<<NBLK, SCAN_B, 0, stream>>>(off, bsum);
    fill_csr<<<(EE + 255) / 256, 256, 0, stream>>>(src, dst, off, cursor, dinv, csrp);
    scratch_init<<<(12 * GC + 255) / 256, 256, 0, stream>>>(scr, 12 * GC);

    agg_x_allT16<<<NN / 4, 256, 0, stream>>>(x, off, csrp, dinv, xa2);

    int t0_first = 0;
    if (!dedicated) {
        // chunk 0 (t=0,1) per-t with Tc=1 kernels; H1 halves hold hw2/hw3
        __half2* hw2a = H1;
        __half2* hw3a = H1 + (size_t)NN * 32;
        for (int t = 0; t < 2; ++t) {
            const __half2* xt = xa2 + (size_t)t * NN * 16;
            l1mat<<<NN / 4, 256, 0, stream>>>(xt, W1, b1, W2, hw2a, pmaxO, psumO);
            agg_fused<1><<<NN / 4, 256, 0, stream>>>(hw2a, off, csrp, dinv, b2, W3,
                                                     hw3a, pmaxO + GC, psumO);
            agg_fused<0><<<NN / 4, 256, 0, stream>>>(hw3a, off, csrp, dinv, b3,
                                                     nullptr, nullptr,
                                                     pmaxO + 2 * GC, psumO);
            fold1<<<(GC + 255) / 256, 256, 0, stream>>>(pmaxO, psumO, out, t);
        }
        t0_first = 2;
        // now xa slices 0..3 are dead after the next chunk's l1mat2 -> H2 = xa2 valid
    }

    for (int t0 = t0_first; t0 < TT; t0 += 2) {
        const __half2* xt = xa2 + (size_t)t0 * NN * 16;
        l1mat2<<<NN / 4, 256, 0, stream>>>(xt, W1, b1, W2, H1, pmaxT, psumT);
        agg2<1><<<NN / 4, 256, 0, stream>>>(H1, off, csrp, dinv, b2, W3, H2,
                                            pmaxT + 2 * GC, psumT);
        agg2<0><<<NN / 4, 256, 0, stream>>>(H2, off, csrp, dinv, b3, nullptr, nullptr,
                                            pmaxT + 4 * GC, psumT);
        fold2<<<(2 * GC + 255) / 256, 256, 0, stream>>>(pmaxT, psumT, out, t0);
    }
}

// Round 10
// 866.680 us; speedup vs baseline: 3.7622x; 1.0147x over previous
//
#include <hip/hip_runtime.h>
#include <hip/hip_fp16.h>
#include <math.h>

#define NN 50000
#define EE 800000
#define BB 250
#define TT 8
#define CIN 32
#define COUT 64
#define NPG 200          // nodes per graph (N/B)
#define SCAN_B 256
#define NBLK 196         // ceil(50000/256)
#define GC (BB * COUT)   // 16000 floats per pool slab

// pack/unpack CSR entry: low 16 = src node (NN<65536), high 16 = fp16 weight
__device__ __forceinline__ float unpack_w(unsigned int v) {
    union { unsigned short u; __half h; } cv;
    cv.u = (unsigned short)(v >> 16);
    return __half2float(cv.h);
}

// ---------------- setup kernels (graph structure, once per call) ----------------

__global__ void init_deg(int* deg, int* cursor) {
    int n = blockIdx.x * 256 + threadIdx.x;
    if (n < NN) { deg[n] = 1; cursor[n] = 0; }
}

__global__ void count_deg(const int* dst, int* deg) {
    int e = blockIdx.x * 256 + threadIdx.x;
    if (e < EE) atomicAdd(&deg[dst[e]], 1);
}

__global__ void compute_dinv(const int* deg, float* dinv) {
    int n = blockIdx.x * 256 + threadIdx.x;
    if (n < NN) dinv[n] = rsqrtf((float)deg[n]);
}

__global__ void scan_blocks(const int* deg, int* off, int* bsum) {
    __shared__ int sh[SCAN_B];
    int gid = blockIdx.x * SCAN_B + threadIdx.x;
    int v = (gid < NN) ? (deg[gid] - 1) : 0;
    sh[threadIdx.x] = v;
    __syncthreads();
    for (int s = 1; s < SCAN_B; s <<= 1) {
        int add = (threadIdx.x >= s) ? sh[threadIdx.x - s] : 0;
        __syncthreads();
        sh[threadIdx.x] += add;
        __syncthreads();
    }
    if (gid < NN) off[gid] = sh[threadIdx.x] - v;
    if (threadIdx.x == SCAN_B - 1) bsum[blockIdx.x] = sh[threadIdx.x];
}

__global__ void scan_sums(int* bsum, int* off) {
    __shared__ int sh[SCAN_B];
    int v = (threadIdx.x < NBLK) ? bsum[threadIdx.x] : 0;
    sh[threadIdx.x] = v;
    __syncthreads();
    for (int s = 1; s < SCAN_B; s <<= 1) {
        int add = (threadIdx.x >= s) ? sh[threadIdx.x - s] : 0;
        __syncthreads();
        sh[threadIdx.x] += add;
        __syncthreads();
    }
    if (threadIdx.x < NBLK) bsum[threadIdx.x] = sh[threadIdx.x] - v;
    if (threadIdx.x == 0) off[NN] = EE;
}

__global__ void scan_add(int* off, const int* bsum) {
    int gid = blockIdx.x * SCAN_B + threadIdx.x;
    if (gid < NN) off[gid] += bsum[blockIdx.x];
}

__global__ void fill_csr(const int* src, const int* dst, const int* off,
                         int* cursor, const float* dinv, unsigned int* csrp) {
    int e = blockIdx.x * 256 + threadIdx.x;
    if (e >= EE) return;
    int s = src[e], d = dst[e];
    int p = atomicAdd(&cursor[d], 1);
    union { __half h; unsigned short u; } cv;
    cv.h = __float2half(dinv[s] * dinv[d]);
    csrp[off[d] + p] = (unsigned int)s | ((unsigned int)cv.u << 16);
}

__global__ void scratch_init(float* scr, int ntot) {
    int i = blockIdx.x * 256 + threadIdx.x;
    if (i < ntot) scr[i] = 0.f;
}

// ---------------- compute kernels ----------------

// ONE pass over edges: xa2 chunk-interleaved fp16: chunk c = t0=2c holds
// [n][tc(2)][pp(16)] half2. 8-deep unrolled gather of 1KB fp32 x-rows.
__global__ void agg_x_allT16(const float* __restrict__ x, const int* __restrict__ off,
                             const unsigned int* __restrict__ csrp,
                             const float* __restrict__ dinv, __half2* __restrict__ xa2) {
    int lane = threadIdx.x & 63;
    int w = threadIdx.x >> 6;
    int n = blockIdx.x * 4 + w;
    float dn = dinv[n];
    float sw = dn * dn;
    float4 v = ((const float4*)(x + (size_t)n * 256))[lane];
    float4 acc = make_float4(sw * v.x, sw * v.y, sw * v.z, sw * v.w);
    int e0 = off[n], e1 = off[n + 1];
    int j = e0;
    for (; j + 7 < e1; j += 8) {          // 8-deep MLP
        unsigned int p0 = csrp[j],     p1 = csrp[j + 1];
        unsigned int p2 = csrp[j + 2], p3 = csrp[j + 3];
        unsigned int p4 = csrp[j + 4], p5 = csrp[j + 5];
        unsigned int p6 = csrp[j + 6], p7 = csrp[j + 7];
        float4 u0 = ((const float4*)(x + (size_t)(p0 & 0xffff) * 256))[lane];
        float4 u1 = ((const float4*)(x + (size_t)(p1 & 0xffff) * 256))[lane];
        float4 u2 = ((const float4*)(x + (size_t)(p2 & 0xffff) * 256))[lane];
        float4 u3 = ((const float4*)(x + (size_t)(p3 & 0xffff) * 256))[lane];
        float4 u4 = ((const float4*)(x + (size_t)(p4 & 0xffff) * 256))[lane];
        float4 u5 = ((const float4*)(x + (size_t)(p5 & 0xffff) * 256))[lane];
        float4 u6 = ((const float4*)(x + (size_t)(p6 & 0xffff) * 256))[lane];
        float4 u7 = ((const float4*)(x + (size_t)(p7 & 0xffff) * 256))[lane];
        float w0 = unpack_w(p0), w1 = unpack_w(p1), w2 = unpack_w(p2), w3 = unpack_w(p3);
        float w4 = unpack_w(p4), w5 = unpack_w(p5), w6 = unpack_w(p6), w7 = unpack_w(p7);
        acc.x = fmaf(w0, u0.x, acc.x); acc.y = fmaf(w0, u0.y, acc.y);
        acc.z = fmaf(w0, u0.z, acc.z); acc.w = fmaf(w0, u0.w, acc.w);
        acc.x = fmaf(w1, u1.x, acc.x); acc.y = fmaf(w1, u1.y, acc.y);
        acc.z = fmaf(w1, u1.z, acc.z); acc.w = fmaf(w1, u1.w, acc.w);
        acc.x = fmaf(w2, u2.x, acc.x); acc.y = fmaf(w2, u2.y, acc.y);
        acc.z = fmaf(w2, u2.z, acc.z); acc.w = fmaf(w2, u2.w, acc.w);
        acc.x = fmaf(w3, u3.x, acc.x); acc.y = fmaf(w3, u3.y, acc.y);
        acc.z = fmaf(w3, u3.z, acc.z); acc.w = fmaf(w3, u3.w, acc.w);
        acc.x = fmaf(w4, u4.x, acc.x); acc.y = fmaf(w4, u4.y, acc.y);
        acc.z = fmaf(w4, u4.z, acc.z); acc.w = fmaf(w4, u4.w, acc.w);
        acc.x = fmaf(w5, u5.x, acc.x); acc.y = fmaf(w5, u5.y, acc.y);
        acc.z = fmaf(w5, u5.z, acc.z); acc.w = fmaf(w5, u5.w, acc.w);
        acc.x = fmaf(w6, u6.x, acc.x); acc.y = fmaf(w6, u6.y, acc.y);
        acc.z = fmaf(w6, u6.z, acc.z); acc.w = fmaf(w6, u6.w, acc.w);
        acc.x = fmaf(w7, u7.x, acc.x); acc.y = fmaf(w7, u7.y, acc.y);
        acc.z = fmaf(w7, u7.z, acc.z); acc.w = fmaf(w7, u7.w, acc.w);
    }
    for (; j + 3 < e1; j += 4) {
        unsigned int p0 = csrp[j],     p1 = csrp[j + 1];
        unsigned int p2 = csrp[j + 2], p3 = csrp[j + 3];
        float4 u0 = ((const float4*)(x + (size_t)(p0 & 0xffff) * 256))[lane];
        float4 u1 = ((const float4*)(x + (size_t)(p1 & 0xffff) * 256))[lane];
        float4 u2 = ((const float4*)(x + (size_t)(p2 & 0xffff) * 256))[lane];
        float4 u3 = ((const float4*)(x + (size_t)(p3 & 0xffff) * 256))[lane];
        float w0 = unpack_w(p0), w1 = unpack_w(p1);
        float w2 = unpack_w(p2), w3 = unpack_w(p3);
        acc.x = fmaf(w0, u0.x, acc.x); acc.y = fmaf(w0, u0.y, acc.y);
        acc.z = fmaf(w0, u0.z, acc.z); acc.w = fmaf(w0, u0.w, acc.w);
        acc.x = fmaf(w1, u1.x, acc.x); acc.y = fmaf(w1, u1.y, acc.y);
        acc.z = fmaf(w1, u1.z, acc.z); acc.w = fmaf(w1, u1.w, acc.w);
        acc.x = fmaf(w2, u2.x, acc.x); acc.y = fmaf(w2, u2.y, acc.y);
        acc.z = fmaf(w2, u2.z, acc.z); acc.w = fmaf(w2, u2.w, acc.w);
        acc.x = fmaf(w3, u3.x, acc.x); acc.y = fmaf(w3, u3.y, acc.y);
        acc.z = fmaf(w3, u3.z, acc.z); acc.w = fmaf(w3, u3.w, acc.w);
    }
    for (; j < e1; ++j) {
        unsigned int p = csrp[j];
        float wj = unpack_w(p);
        float4 u = ((const float4*)(x + (size_t)(p & 0xffff) * 256))[lane];
        acc.x = fmaf(wj, u.x, acc.x); acc.y = fmaf(wj, u.y, acc.y);
        acc.z = fmaf(wj, u.z, acc.z); acc.w = fmaf(wj, u.w, acc.w);
    }
    // element flat idx f = 4*lane+k -> (c = f>>3, t = f&7)
    __shared__ float sh[4][TT][33];
    float av[4] = {acc.x, acc.y, acc.z, acc.w};
    #pragma unroll
    for (int k = 0; k < 4; ++k) {
        int f = 4 * lane + k;
        sh[w][f & 7][f >> 3] = av[k];
    }
    __syncthreads();
    // chunk-interleaved write: addr = (chunk*NN + n)*32 + tc*16 + pp
    for (int i = threadIdx.x; i < 512; i += 256) {
        int t = i >> 6;
        int r = i & 63;
        int nl = r >> 4;
        int pp = r & 15;
        xa2[((size_t)(t >> 1) * NN + blockIdx.x * 4 + nl) * 32 + (t & 1) * 16 + pp] =
            __floats2half2_rn(sh[nl][t][2 * pp], sh[nl][t][2 * pp + 1]);
    }
}

// h1 = relu(xa[chunk] W1 + b1), pool, H1[n][tc][pr] = h1 W2 (interleaved out)
__global__ void l1mat2i(const __half2* __restrict__ xa, const float* __restrict__ W1,
                        const float* __restrict__ b1, const float* __restrict__ W2,
                        __half2* __restrict__ H1,
                        float* __restrict__ pmax, float* __restrict__ psum) {
    __shared__ float W1s[CIN * COUT];      // 8 KB
    __shared__ __half2 W2s[COUT * 32];     // 8 KB
    __shared__ float Xs[4][2][CIN];
    __shared__ float tile[4][2][COUT];
    for (int i = threadIdx.x; i < CIN * COUT; i += 256) W1s[i] = W1[i];
    for (int i = threadIdx.x; i < COUT * 32; i += 256) {
        int k = i >> 5, pr = i & 31;
        W2s[i] = __floats2half2_rn(W2[k * COUT + 2 * pr], W2[k * COUT + 2 * pr + 1]);
    }
    if (threadIdx.x < 128) {
        int nl = threadIdx.x >> 5, idx = threadIdx.x & 31;
        int tc = idx >> 4, pp = idx & 15;
        float2 v = __half22float2(xa[((size_t)blockIdx.x * 4 + nl) * 32 + idx]);
        Xs[nl][tc][2 * pp] = v.x;
        Xs[nl][tc][2 * pp + 1] = v.y;
    }
    __syncthreads();
    int co = threadIdx.x & 63;
    int nl = threadIdx.x >> 6;
    float a0 = b1[co], a1 = b1[co];
    #pragma unroll
    for (int k = 0; k < CIN; ++k) {
        float wv = W1s[k * COUT + co];
        a0 = fmaf(Xs[nl][0][k], wv, a0);
        a1 = fmaf(Xs[nl][1][k], wv, a1);
    }
    tile[nl][0][co] = fmaxf(a0, 0.f);
    tile[nl][1][co] = fmaxf(a1, 0.f);
    __syncthreads();
    if (threadIdx.x < 128) {
        int c = threadIdx.x & 63, tc = threadIdx.x >> 6;
        float m = fmaxf(fmaxf(tile[0][tc][c], tile[1][tc][c]),
                        fmaxf(tile[2][tc][c], tile[3][tc][c]));
        float s = tile[0][tc][c] + tile[1][tc][c] + tile[2][tc][c] + tile[3][tc][c];
        int g = blockIdx.x / 50;
        atomicMax((int*)&pmax[tc * GC + g * COUT + c], __float_as_int(m));
        atomicAdd(&psum[tc * GC + g * COUT + c], s);
    }
    {   // W2 matmul: 256 thr = 8 rows (4 nodes x 2 tc) x 32 pairs
        int row = threadIdx.x >> 5;
        int pr = threadIdx.x & 31;
        int nl2 = row >> 1, tc2 = row & 1;
        float b0 = 0.f, bb1 = 0.f;
        #pragma unroll
        for (int k = 0; k < COUT; ++k) {
            float xv = tile[nl2][tc2][k];
            float2 wv = __half22float2(W2s[k * 32 + pr]);
            b0 = fmaf(xv, wv.x, b0);
            bb1 = fmaf(xv, wv.y, bb1);
        }
        H1[((size_t)blockIdx.x * 4 + nl2) * 64 + tc2 * 32 + pr] =
            __floats2half2_rn(b0, bb1);
    }
}

// Interleaved 2-t aggregation: node payload = 256 B contiguous; whole wave
// (lane = tc*32 + p) loads one edge's payload in ONE dword instruction.
// No cross-lane reduction needed. 8-deep MLP.
template <int FUSE>
__global__ void agg2i(const __half2* __restrict__ Hin, const int* __restrict__ off,
                      const unsigned int* __restrict__ csrp,
                      const float* __restrict__ dinv, const float* __restrict__ b,
                      const float* __restrict__ W, __half2* __restrict__ Hout,
                      float* __restrict__ pmax, float* __restrict__ psum) {
    __shared__ __half2 Ws[FUSE ? COUT * 32 : 1];
    __shared__ float tile[4][2][COUT];
    if (FUSE)
        for (int i = threadIdx.x; i < COUT * 32; i += 256) {
            int k = i >> 5, pr = i & 31;
            Ws[i] = __floats2half2_rn(W[k * COUT + 2 * pr], W[k * COUT + 2 * pr + 1]);
        }
    int lane = threadIdx.x & 63;
    int tc = lane >> 5;
    int p = lane & 31;
    int w = threadIdx.x >> 6;
    int n = blockIdx.x * 4 + w;
    int e0 = off[n], e1 = off[n + 1];
    float ax = 0.f, ay = 0.f;
    int j = e0;
    for (; j + 7 < e1; j += 8) {          // 8 edges x 256B in flight
        unsigned int c0 = csrp[j],     c1 = csrp[j + 1];
        unsigned int c2 = csrp[j + 2], c3 = csrp[j + 3];
        unsigned int c4 = csrp[j + 4], c5 = csrp[j + 5];
        unsigned int c6 = csrp[j + 6], c7 = csrp[j + 7];
        float2 v0 = __half22float2(Hin[(size_t)(c0 & 0xffff) * 64 + lane]);
        float2 v1 = __half22float2(Hin[(size_t)(c1 & 0xffff) * 64 + lane]);
        float2 v2 = __half22float2(Hin[(size_t)(c2 & 0xffff) * 64 + lane]);
        float2 v3 = __half22float2(Hin[(size_t)(c3 & 0xffff) * 64 + lane]);
        float2 v4 = __half22float2(Hin[(size_t)(c4 & 0xffff) * 64 + lane]);
        float2 v5 = __half22float2(Hin[(size_t)(c5 & 0xffff) * 64 + lane]);
        float2 v6 = __half22float2(Hin[(size_t)(c6 & 0xffff) * 64 + lane]);
        float2 v7 = __half22float2(Hin[(size_t)(c7 & 0xffff) * 64 + lane]);
        float w0 = unpack_w(c0), w1 = unpack_w(c1), w2 = unpack_w(c2), w3 = unpack_w(c3);
        float w4 = unpack_w(c4), w5 = unpack_w(c5), w6 = unpack_w(c6), w7 = unpack_w(c7);
        ax = fmaf(w0, v0.x, ax); ay = fmaf(w0, v0.y, ay);
        ax = fmaf(w1, v1.x, ax); ay = fmaf(w1, v1.y, ay);
        ax = fmaf(w2, v2.x, ax); ay = fmaf(w2, v2.y, ay);
        ax = fmaf(w3, v3.x, ax); ay = fmaf(w3, v3.y, ay);
        ax = fmaf(w4, v4.x, ax); ay = fmaf(w4, v4.y, ay);
        ax = fmaf(w5, v5.x, ax); ay = fmaf(w5, v5.y, ay);
        ax = fmaf(w6, v6.x, ax); ay = fmaf(w6, v6.y, ay);
        ax = fmaf(w7, v7.x, ax); ay = fmaf(w7, v7.y, ay);
    }
    for (; j + 3 < e1; j += 4) {
        unsigned int c0 = csrp[j],     c1 = csrp[j + 1];
        unsigned int c2 = csrp[j + 2], c3 = csrp[j + 3];
        float2 v0 = __half22float2(Hin[(size_t)(c0 & 0xffff) * 64 + lane]);
        float2 v1 = __half22float2(Hin[(size_t)(c1 & 0xffff) * 64 + lane]);
        float2 v2 = __half22float2(Hin[(size_t)(c2 & 0xffff) * 64 + lane]);
        float2 v3 = __half22float2(Hin[(size_t)(c3 & 0xffff) * 64 + lane]);
        float w0 = unpack_w(c0), w1 = unpack_w(c1);
        float w2 = unpack_w(c2), w3 = unpack_w(c3);
        ax = fmaf(w0, v0.x, ax); ay = fmaf(w0, v0.y, ay);
        ax = fmaf(w1, v1.x, ax); ay = fmaf(w1, v1.y, ay);
        ax = fmaf(w2, v2.x, ax); ay = fmaf(w2, v2.y, ay);
        ax = fmaf(w3, v3.x, ax); ay = fmaf(w3, v3.y, ay);
    }
    for (; j < e1; ++j) {
        unsigned int c = csrp[j];
        float wv = unpack_w(c);
        float2 v = __half22float2(Hin[(size_t)(c & 0xffff) * 64 + lane]);
        ax = fmaf(wv, v.x, ax); ay = fmaf(wv, v.y, ay);
    }
    // self-loop + bias + relu
    {
        float dn = dinv[n];
        float sw = dn * dn;
        float2 sv = __half22float2(Hin[(size_t)n * 64 + lane]);
        float ox = fmaxf(fmaf(sw, sv.x, ax) + b[2 * p], 0.f);
        float oy = fmaxf(fmaf(sw, sv.y, ay) + b[2 * p + 1], 0.f);
        tile[w][tc][2 * p] = ox;
        tile[w][tc][2 * p + 1] = oy;
    }
    __syncthreads();
    if (threadIdx.x < 128) {
        int c = threadIdx.x & 63, tcc = threadIdx.x >> 6;
        float m = fmaxf(fmaxf(tile[0][tcc][c], tile[1][tcc][c]),
                        fmaxf(tile[2][tcc][c], tile[3][tcc][c]));
        float s = tile[0][tcc][c] + tile[1][tcc][c] + tile[2][tcc][c] + tile[3][tcc][c];
        int g = blockIdx.x / 50;
        atomicMax((int*)&pmax[tcc * GC + g * COUT + c], __float_as_int(m));
        atomicAdd(&psum[tcc * GC + g * COUT + c], s);
    }
    if (FUSE) {
        int row = threadIdx.x >> 5;
        int pr = threadIdx.x & 31;
        int nl2 = row >> 1, tc2 = row & 1;
        float b0 = 0.f, bb1 = 0.f;
        #pragma unroll
        for (int k = 0; k < COUT; ++k) {
            float xv = tile[nl2][tc2][k];
            float2 wv = __half22float2(Ws[k * 32 + pr]);
            b0 = fmaf(xv, wv.x, b0);
            bb1 = fmaf(xv, wv.y, bb1);
        }
        Hout[((size_t)blockIdx.x * 4 + nl2) * 64 + tc2 * 32 + pr] =
            __floats2half2_rn(b0, bb1);
    }
}

// fold 2-t scratch -> out[:, :, t0..t0+1], reset
__global__ void fold2(float* __restrict__ pmaxT, float* __restrict__ psumT,
                      float* __restrict__ out, int t0) {
    int i = blockIdx.x * 256 + threadIdx.x;
    if (i >= 2 * GC) return;
    int tc = i / GC;
    int r = i - tc * GC;
    int g = r >> 6, c = r & 63;
    float m = pmaxT[tc * GC + r] + pmaxT[2 * GC + tc * GC + r] +
              pmaxT[4 * GC + tc * GC + r];
    float mean = psumT[i] * (1.0f / NPG);
    int t = t0 + tc;
    out[((size_t)g * 128 + c) * TT + t] = m;
    out[((size_t)g * 128 + 64 + c) * TT + t] = mean;
    pmaxT[tc * GC + r] = 0.f;
    pmaxT[2 * GC + tc * GC + r] = 0.f;
    pmaxT[4 * GC + tc * GC + r] = 0.f;
    psumT[i] = 0.f;
}

// ---------------- launch ----------------

extern "C" void kernel_launch(void* const* d_in, const int* in_sizes, int n_in,
                              void* d_out, int out_size, void* d_ws, size_t ws_size,
                              hipStream_t stream) {
    const float* x   = (const float*)d_in[0];
    const int*   ei  = (const int*)d_in[1];
    const int*   src = ei;
    const int*   dst = ei + EE;
    const float* W1  = (const float*)d_in[3];
    const float* b1  = (const float*)d_in[4];
    const float* W2  = (const float*)d_in[5];
    const float* b2  = (const float*)d_in[6];
    const float* W3  = (const float*)d_in[7];
    const float* b3  = (const float*)d_in[8];
    float* out = (float*)d_out;

    char* wsp = (char*)d_ws;
    auto alloc = [&](size_t bytes) {
        char* p = wsp;
        wsp += (bytes + 255) & ~(size_t)255;
        return p;
    };
    // layout (~48.9 MB total, ws known >= 52.07 MB):
    // [dinv][off][csrp][H1 12.8M][xa2 25.6M][H2extra 6.4M][scr]
    // H2 (12.8M) = xa2's chunk-3 region + H2extra (contiguous: chunk size is
    // 256-aligned so no alloc padding). Chunks processed DESCENDING so chunk 3's
    // xa is consumed before agg2i first writes H2.
    const size_t chunkHalf2 = (size_t)NN * 32;              // half2 per chunk
    float*        dinv = (float*)       alloc((size_t)NN * 4);
    int*          off  = (int*)         alloc((size_t)(NN + 1) * 4);
    unsigned int* csrp = (unsigned int*)alloc((size_t)EE * 4);
    __half2*      H1   = (__half2*)     alloc((size_t)NN * 64 * 4);      // 12.8 MB
    __half2*      xa2  = (__half2*)     alloc(chunkHalf2 * 4 * 4);       // 25.6 MB
    __half2*      h2x  = (__half2*)     alloc(chunkHalf2 * 4);           // 6.4 MB
    float*        scr  = (float*)       alloc((size_t)8 * GC * 4);
    (void)h2x;
    __half2* H2 = xa2 + 3 * chunkHalf2;   // chunk-3 region + h2x, contiguous
    float* pmaxT = scr;                   // [layer(3)][tc(2)][GC]
    float* psumT = scr + 6 * GC;          // [tc(2)][GC]

    // setup-only buffers aliased into H1 (dead before H1's first write)
    int* deg    = (int*)H1;
    int* cursor = ((int*)H1) + NN;
    int* bsum   = ((int*)H1) + 2 * NN;

    init_deg<<<NBLK, 256, 0, stream>>>(deg, cursor);
    count_deg<<<(EE + 255) / 256, 256, 0, stream>>>(dst, deg);
    compute_dinv<<<NBLK, 256, 0, stream>>>(deg, dinv);
    scan_blocks<<<NBLK, SCAN_B, 0, stream>>>(deg, off, bsum);
    scan_sums<<<1, SCAN_B, 0, stream>>>(bsum, off);
    scan_add<<<NBLK, SCAN_B, 0, stream>>>(off, bsum);
    fill_csr<<<(EE + 255) / 256, 256, 0, stream>>>(src, dst, off, cursor, dinv, csrp);
    scratch_init<<<(8 * GC + 255) / 256, 256, 0, stream>>>(scr, 8 * GC);

    agg_x_allT16<<<NN / 4, 256, 0, stream>>>(x, off, csrp, dinv, xa2);

    for (int c = 3; c >= 0; --c) {        // descending: frees chunk 3 first
        int t0 = 2 * c;
        const __half2* xc = xa2 + (size_t)c * chunkHalf2;
        l1mat2i<<<NN / 4, 256, 0, stream>>>(xc, W1, b1, W2, H1, pmaxT, psumT);
        agg2i<1><<<NN / 4, 256, 0, stream>>>(H1, off, csrp, dinv, b2, W3, H2,
                                             pmaxT + 2 * GC, psumT);
        agg2i<0><<<NN / 4, 256, 0, stream>>>(H2, off, csrp, dinv, b3, nullptr, nullptr,
                                             pmaxT + 4 * GC, psumT);
        fold2<<<(2 * GC + 255) / 256, 256, 0, stream>>>(pmaxT, psumT, out, t0);
    }
}

// Round 11
// 861.446 us; speedup vs baseline: 3.7850x; 1.0061x over previous
//
#include <hip/hip_runtime.h>
#include <hip/hip_fp16.h>
#include <math.h>

#define NN 50000
#define EE 800000
#define BB 250
#define TT 8
#define CIN 32
#define COUT 64
#define NPG 200          // nodes per graph (N/B)
#define SCAN_B 256
#define NBLK 196         // ceil(50000/256)
#define GC (BB * COUT)   // 16000 floats per pool slab

// pack/unpack CSR entry: low 16 = src node (NN<65536), high 16 = fp16 weight
__device__ __forceinline__ float unpack_w(unsigned int v) {
    union { unsigned short u; __half h; } cv;
    cv.u = (unsigned short)(v >> 16);
    return __half2float(cv.h);
}

// ---------------- setup kernels (graph structure, once per call) ----------------

__global__ void init_deg(int* deg, int* cursor) {
    int n = blockIdx.x * 256 + threadIdx.x;
    if (n < NN) { deg[n] = 1; cursor[n] = 0; }
}

__global__ void count_deg(const int* dst, int* deg) {
    int e = blockIdx.x * 256 + threadIdx.x;
    if (e < EE) atomicAdd(&deg[dst[e]], 1);
}

__global__ void compute_dinv(const int* deg, float* dinv) {
    int n = blockIdx.x * 256 + threadIdx.x;
    if (n < NN) dinv[n] = rsqrtf((float)deg[n]);
}

__global__ void scan_blocks(const int* deg, int* off, int* bsum) {
    __shared__ int sh[SCAN_B];
    int gid = blockIdx.x * SCAN_B + threadIdx.x;
    int v = (gid < NN) ? (deg[gid] - 1) : 0;
    sh[threadIdx.x] = v;
    __syncthreads();
    for (int s = 1; s < SCAN_B; s <<= 1) {
        int add = (threadIdx.x >= s) ? sh[threadIdx.x - s] : 0;
        __syncthreads();
        sh[threadIdx.x] += add;
        __syncthreads();
    }
    if (gid < NN) off[gid] = sh[threadIdx.x] - v;
    if (threadIdx.x == SCAN_B - 1) bsum[blockIdx.x] = sh[threadIdx.x];
}

__global__ void scan_sums(int* bsum, int* off) {
    __shared__ int sh[SCAN_B];
    int v = (threadIdx.x < NBLK) ? bsum[threadIdx.x] : 0;
    sh[threadIdx.x] = v;
    __syncthreads();
    for (int s = 1; s < SCAN_B; s <<= 1) {
        int add = (threadIdx.x >= s) ? sh[threadIdx.x - s] : 0;
        __syncthreads();
        sh[threadIdx.x] += add;
        __syncthreads();
    }
    if (threadIdx.x < NBLK) bsum[threadIdx.x] = sh[threadIdx.x] - v;
    if (threadIdx.x == 0) off[NN] = EE;
}

__global__ void scan_add(int* off, const int* bsum) {
    int gid = blockIdx.x * SCAN_B + threadIdx.x;
    if (gid < NN) off[gid] += bsum[blockIdx.x];
}

__global__ void fill_csr(const int* src, const int* dst, const int* off,
                         int* cursor, const float* dinv, unsigned int* csrp) {
    int e = blockIdx.x * 256 + threadIdx.x;
    if (e >= EE) return;
    int s = src[e], d = dst[e];
    int p = atomicAdd(&cursor[d], 1);
    union { __half h; unsigned short u; } cv;
    cv.h = __float2half(dinv[s] * dinv[d]);
    csrp[off[d] + p] = (unsigned int)s | ((unsigned int)cv.u << 16);
}

__global__ void scratch_init(float* scr, int ntot) {
    int i = blockIdx.x * 256 + threadIdx.x;
    if (i < ntot) scr[i] = 0.f;
}

// ---------------- compute kernels ----------------

// ONE pass over edges: xa2 chunk-interleaved fp16. Broadcast walk: one
// cooperative csrp load per <=64 edges, __shfl broadcast for indices.
__global__ void agg_x_allT16(const float* __restrict__ x, const int* __restrict__ off,
                             const unsigned int* __restrict__ csrp,
                             const float* __restrict__ dinv, __half2* __restrict__ xa2) {
    int lane = threadIdx.x & 63;
    int w = threadIdx.x >> 6;
    int n = blockIdx.x * 4 + w;
    float dn = dinv[n];
    float sw = dn * dn;
    float4 v = ((const float4*)(x + (size_t)n * 256))[lane];
    float4 acc = make_float4(sw * v.x, sw * v.y, sw * v.z, sw * v.w);
    int e0 = off[n], e1 = off[n + 1];
    for (int base = e0; base < e1; base += 64) {
        int idx = base + lane;
        unsigned int cme = (idx < e1) ? csrp[idx] : 0u;   // 1 coalesced load / 64 edges
        int cnt = min(64, e1 - base);
        int k = 0;
        for (; k + 7 < cnt; k += 8) {
            unsigned int p0 = __shfl(cme, k, 64),     p1 = __shfl(cme, k + 1, 64);
            unsigned int p2 = __shfl(cme, k + 2, 64), p3 = __shfl(cme, k + 3, 64);
            unsigned int p4 = __shfl(cme, k + 4, 64), p5 = __shfl(cme, k + 5, 64);
            unsigned int p6 = __shfl(cme, k + 6, 64), p7 = __shfl(cme, k + 7, 64);
            float4 u0 = ((const float4*)(x + (size_t)(p0 & 0xffff) * 256))[lane];
            float4 u1 = ((const float4*)(x + (size_t)(p1 & 0xffff) * 256))[lane];
            float4 u2 = ((const float4*)(x + (size_t)(p2 & 0xffff) * 256))[lane];
            float4 u3 = ((const float4*)(x + (size_t)(p3 & 0xffff) * 256))[lane];
            float4 u4 = ((const float4*)(x + (size_t)(p4 & 0xffff) * 256))[lane];
            float4 u5 = ((const float4*)(x + (size_t)(p5 & 0xffff) * 256))[lane];
            float4 u6 = ((const float4*)(x + (size_t)(p6 & 0xffff) * 256))[lane];
            float4 u7 = ((const float4*)(x + (size_t)(p7 & 0xffff) * 256))[lane];
            float w0 = unpack_w(p0), w1 = unpack_w(p1), w2 = unpack_w(p2), w3 = unpack_w(p3);
            float w4 = unpack_w(p4), w5 = unpack_w(p5), w6 = unpack_w(p6), w7 = unpack_w(p7);
            acc.x = fmaf(w0, u0.x, acc.x); acc.y = fmaf(w0, u0.y, acc.y);
            acc.z = fmaf(w0, u0.z, acc.z); acc.w = fmaf(w0, u0.w, acc.w);
            acc.x = fmaf(w1, u1.x, acc.x); acc.y = fmaf(w1, u1.y, acc.y);
            acc.z = fmaf(w1, u1.z, acc.z); acc.w = fmaf(w1, u1.w, acc.w);
            acc.x = fmaf(w2, u2.x, acc.x); acc.y = fmaf(w2, u2.y, acc.y);
            acc.z = fmaf(w2, u2.z, acc.z); acc.w = fmaf(w2, u2.w, acc.w);
            acc.x = fmaf(w3, u3.x, acc.x); acc.y = fmaf(w3, u3.y, acc.y);
            acc.z = fmaf(w3, u3.z, acc.z); acc.w = fmaf(w3, u3.w, acc.w);
            acc.x = fmaf(w4, u4.x, acc.x); acc.y = fmaf(w4, u4.y, acc.y);
            acc.z = fmaf(w4, u4.z, acc.z); acc.w = fmaf(w4, u4.w, acc.w);
            acc.x = fmaf(w5, u5.x, acc.x); acc.y = fmaf(w5, u5.y, acc.y);
            acc.z = fmaf(w5, u5.z, acc.z); acc.w = fmaf(w5, u5.w, acc.w);
            acc.x = fmaf(w6, u6.x, acc.x); acc.y = fmaf(w6, u6.y, acc.y);
            acc.z = fmaf(w6, u6.z, acc.z); acc.w = fmaf(w6, u6.w, acc.w);
            acc.x = fmaf(w7, u7.x, acc.x); acc.y = fmaf(w7, u7.y, acc.y);
            acc.z = fmaf(w7, u7.z, acc.z); acc.w = fmaf(w7, u7.w, acc.w);
        }
        for (; k < cnt; ++k) {
            unsigned int p = __shfl(cme, k, 64);
            float wj = unpack_w(p);
            float4 u = ((const float4*)(x + (size_t)(p & 0xffff) * 256))[lane];
            acc.x = fmaf(wj, u.x, acc.x); acc.y = fmaf(wj, u.y, acc.y);
            acc.z = fmaf(wj, u.z, acc.z); acc.w = fmaf(wj, u.w, acc.w);
        }
    }
    // element flat idx f = 4*lane+k -> (c = f>>3, t = f&7)
    __shared__ float sh[4][TT][33];
    float av[4] = {acc.x, acc.y, acc.z, acc.w};
    #pragma unroll
    for (int k = 0; k < 4; ++k) {
        int f = 4 * lane + k;
        sh[w][f & 7][f >> 3] = av[k];
    }
    __syncthreads();
    // chunk-interleaved write: addr = (chunk*NN + n)*32 + tc*16 + pp
    for (int i = threadIdx.x; i < 512; i += 256) {
        int t = i >> 6;
        int r = i & 63;
        int nl = r >> 4;
        int pp = r & 15;
        xa2[((size_t)(t >> 1) * NN + blockIdx.x * 4 + nl) * 32 + (t & 1) * 16 + pp] =
            __floats2half2_rn(sh[nl][t][2 * pp], sh[nl][t][2 * pp + 1]);
    }
}

// h1 = relu(xa[chunk] W1 + b1), pool, H1[n][tc][pr] = h1 W2 (interleaved out)
__global__ void l1mat2i(const __half2* __restrict__ xa, const float* __restrict__ W1,
                        const float* __restrict__ b1, const float* __restrict__ W2,
                        __half2* __restrict__ H1,
                        float* __restrict__ pmax, float* __restrict__ psum) {
    __shared__ float W1s[CIN * COUT];      // 8 KB
    __shared__ __half2 W2s[COUT * 32];     // 8 KB
    __shared__ float Xs[4][2][CIN];
    __shared__ float tile[4][2][COUT];
    for (int i = threadIdx.x; i < CIN * COUT; i += 256) W1s[i] = W1[i];
    for (int i = threadIdx.x; i < COUT * 32; i += 256) {
        int k = i >> 5, pr = i & 31;
        W2s[i] = __floats2half2_rn(W2[k * COUT + 2 * pr], W2[k * COUT + 2 * pr + 1]);
    }
    if (threadIdx.x < 128) {
        int nl = threadIdx.x >> 5, idx = threadIdx.x & 31;
        int tc = idx >> 4, pp = idx & 15;
        float2 v = __half22float2(xa[((size_t)blockIdx.x * 4 + nl) * 32 + idx]);
        Xs[nl][tc][2 * pp] = v.x;
        Xs[nl][tc][2 * pp + 1] = v.y;
    }
    __syncthreads();
    int co = threadIdx.x & 63;
    int nl = threadIdx.x >> 6;
    float a0 = b1[co], a1 = b1[co];
    #pragma unroll
    for (int k = 0; k < CIN; ++k) {
        float wv = W1s[k * COUT + co];
        a0 = fmaf(Xs[nl][0][k], wv, a0);
        a1 = fmaf(Xs[nl][1][k], wv, a1);
    }
    tile[nl][0][co] = fmaxf(a0, 0.f);
    tile[nl][1][co] = fmaxf(a1, 0.f);
    __syncthreads();
    if (threadIdx.x < 128) {
        int c = threadIdx.x & 63, tc = threadIdx.x >> 6;
        float m = fmaxf(fmaxf(tile[0][tc][c], tile[1][tc][c]),
                        fmaxf(tile[2][tc][c], tile[3][tc][c]));
        float s = tile[0][tc][c] + tile[1][tc][c] + tile[2][tc][c] + tile[3][tc][c];
        int g = blockIdx.x / 50;
        atomicMax((int*)&pmax[tc * GC + g * COUT + c], __float_as_int(m));
        atomicAdd(&psum[tc * GC + g * COUT + c], s);
    }
    {   // W2 matmul: 256 thr = 8 rows (4 nodes x 2 tc) x 32 pairs
        int row = threadIdx.x >> 5;
        int pr = threadIdx.x & 31;
        int nl2 = row >> 1, tc2 = row & 1;
        float b0 = 0.f, bb1 = 0.f;
        #pragma unroll
        for (int k = 0; k < COUT; ++k) {
            float xv = tile[nl2][tc2][k];
            float2 wv = __half22float2(W2s[k * 32 + pr]);
            b0 = fmaf(xv, wv.x, b0);
            bb1 = fmaf(xv, wv.y, bb1);
        }
        H1[((size_t)blockIdx.x * 4 + nl2) * 64 + tc2 * 32 + pr] =
            __floats2half2_rn(b0, bb1);
    }
}

// Interleaved 2-t aggregation with broadcast walk. Node payload = 256 B
// contiguous; wave loads it in ONE dword instruction per edge; csrp comes
// from one cooperative load + __shfl broadcasts (no load->load chain).
template <int FUSE>
__global__ void agg2i(const __half2* __restrict__ Hin, const int* __restrict__ off,
                      const unsigned int* __restrict__ csrp,
                      const float* __restrict__ dinv, const float* __restrict__ b,
                      const float* __restrict__ W, __half2* __restrict__ Hout,
                      float* __restrict__ pmax, float* __restrict__ psum) {
    __shared__ __half2 Ws[FUSE ? COUT * 32 : 1];
    __shared__ float tile[4][2][COUT];
    if (FUSE)
        for (int i = threadIdx.x; i < COUT * 32; i += 256) {
            int k = i >> 5, pr = i & 31;
            Ws[i] = __floats2half2_rn(W[k * COUT + 2 * pr], W[k * COUT + 2 * pr + 1]);
        }
    int lane = threadIdx.x & 63;
    int tc = lane >> 5;
    int p = lane & 31;
    int w = threadIdx.x >> 6;
    int n = blockIdx.x * 4 + w;
    int e0 = off[n], e1 = off[n + 1];
    float ax = 0.f, ay = 0.f;
    for (int base = e0; base < e1; base += 64) {
        int idx = base + lane;
        unsigned int cme = (idx < e1) ? csrp[idx] : 0u;   // 1 load / 64 edges
        int cnt = min(64, e1 - base);
        int k = 0;
        for (; k + 7 < cnt; k += 8) {
            unsigned int c0 = __shfl(cme, k, 64),     c1 = __shfl(cme, k + 1, 64);
            unsigned int c2 = __shfl(cme, k + 2, 64), c3 = __shfl(cme, k + 3, 64);
            unsigned int c4 = __shfl(cme, k + 4, 64), c5 = __shfl(cme, k + 5, 64);
            unsigned int c6 = __shfl(cme, k + 6, 64), c7 = __shfl(cme, k + 7, 64);
            float2 v0 = __half22float2(Hin[(size_t)(c0 & 0xffff) * 64 + lane]);
            float2 v1 = __half22float2(Hin[(size_t)(c1 & 0xffff) * 64 + lane]);
            float2 v2 = __half22float2(Hin[(size_t)(c2 & 0xffff) * 64 + lane]);
            float2 v3 = __half22float2(Hin[(size_t)(c3 & 0xffff) * 64 + lane]);
            float2 v4 = __half22float2(Hin[(size_t)(c4 & 0xffff) * 64 + lane]);
            float2 v5 = __half22float2(Hin[(size_t)(c5 & 0xffff) * 64 + lane]);
            float2 v6 = __half22float2(Hin[(size_t)(c6 & 0xffff) * 64 + lane]);
            float2 v7 = __half22float2(Hin[(size_t)(c7 & 0xffff) * 64 + lane]);
            float w0 = unpack_w(c0), w1 = unpack_w(c1), w2 = unpack_w(c2), w3 = unpack_w(c3);
            float w4 = unpack_w(c4), w5 = unpack_w(c5), w6 = unpack_w(c6), w7 = unpack_w(c7);
            ax = fmaf(w0, v0.x, ax); ay = fmaf(w0, v0.y, ay);
            ax = fmaf(w1, v1.x, ax); ay = fmaf(w1, v1.y, ay);
            ax = fmaf(w2, v2.x, ax); ay = fmaf(w2, v2.y, ay);
            ax = fmaf(w3, v3.x, ax); ay = fmaf(w3, v3.y, ay);
            ax = fmaf(w4, v4.x, ax); ay = fmaf(w4, v4.y, ay);
            ax = fmaf(w5, v5.x, ax); ay = fmaf(w5, v5.y, ay);
            ax = fmaf(w6, v6.x, ax); ay = fmaf(w6, v6.y, ay);
            ax = fmaf(w7, v7.x, ax); ay = fmaf(w7, v7.y, ay);
        }
        for (; k < cnt; ++k) {
            unsigned int c = __shfl(cme, k, 64);
            float wv = unpack_w(c);
            float2 v = __half22float2(Hin[(size_t)(c & 0xffff) * 64 + lane]);
            ax = fmaf(wv, v.x, ax); ay = fmaf(wv, v.y, ay);
        }
    }
    // self-loop + bias + relu
    {
        float dn = dinv[n];
        float sw = dn * dn;
        float2 sv = __half22float2(Hin[(size_t)n * 64 + lane]);
        float ox = fmaxf(fmaf(sw, sv.x, ax) + b[2 * p], 0.f);
        float oy = fmaxf(fmaf(sw, sv.y, ay) + b[2 * p + 1], 0.f);
        tile[w][tc][2 * p] = ox;
        tile[w][tc][2 * p + 1] = oy;
    }
    __syncthreads();
    if (threadIdx.x < 128) {
        int c = threadIdx.x & 63, tcc = threadIdx.x >> 6;
        float m = fmaxf(fmaxf(tile[0][tcc][c], tile[1][tcc][c]),
                        fmaxf(tile[2][tcc][c], tile[3][tcc][c]));
        float s = tile[0][tcc][c] + tile[1][tcc][c] + tile[2][tcc][c] + tile[3][tcc][c];
        int g = blockIdx.x / 50;
        atomicMax((int*)&pmax[tcc * GC + g * COUT + c], __float_as_int(m));
        atomicAdd(&psum[tcc * GC + g * COUT + c], s);
    }
    if (FUSE) {
        int row = threadIdx.x >> 5;
        int pr = threadIdx.x & 31;
        int nl2 = row >> 1, tc2 = row & 1;
        float b0 = 0.f, bb1 = 0.f;
        #pragma unroll
        for (int k = 0; k < COUT; ++k) {
            float xv = tile[nl2][tc2][k];
            float2 wv = __half22float2(Ws[k * 32 + pr]);
            b0 = fmaf(xv, wv.x, b0);
            bb1 = fmaf(xv, wv.y, bb1);
        }
        Hout[((size_t)blockIdx.x * 4 + nl2) * 64 + tc2 * 32 + pr] =
            __floats2half2_rn(b0, bb1);
    }
}

// fold 2-t scratch -> out[:, :, t0..t0+1], reset
__global__ void fold2(float* __restrict__ pmaxT, float* __restrict__ psumT,
                      float* __restrict__ out, int t0) {
    int i = blockIdx.x * 256 + threadIdx.x;
    if (i >= 2 * GC) return;
    int tc = i / GC;
    int r = i - tc * GC;
    int g = r >> 6, c = r & 63;
    float m = pmaxT[tc * GC + r] + pmaxT[2 * GC + tc * GC + r] +
              pmaxT[4 * GC + tc * GC + r];
    float mean = psumT[i] * (1.0f / NPG);
    int t = t0 + tc;
    out[((size_t)g * 128 + c) * TT + t] = m;
    out[((size_t)g * 128 + 64 + c) * TT + t] = mean;
    pmaxT[tc * GC + r] = 0.f;
    pmaxT[2 * GC + tc * GC + r] = 0.f;
    pmaxT[4 * GC + tc * GC + r] = 0.f;
    psumT[i] = 0.f;
}

// ---------------- launch ----------------

extern "C" void kernel_launch(void* const* d_in, const int* in_sizes, int n_in,
                              void* d_out, int out_size, void* d_ws, size_t ws_size,
                              hipStream_t stream) {
    const float* x   = (const float*)d_in[0];
    const int*   ei  = (const int*)d_in[1];
    const int*   src = ei;
    const int*   dst = ei + EE;
    const float* W1  = (const float*)d_in[3];
    const float* b1  = (const float*)d_in[4];
    const float* W2  = (const float*)d_in[5];
    const float* b2  = (const float*)d_in[6];
    const float* W3  = (const float*)d_in[7];
    const float* b3  = (const float*)d_in[8];
    float* out = (float*)d_out;

    char* wsp = (char*)d_ws;
    auto alloc = [&](size_t bytes) {
        char* p = wsp;
        wsp += (bytes + 255) & ~(size_t)255;
        return p;
    };
    // layout (~48.9 MB, ws known >= 52.07 MB):
    // [dinv][off][csrp][H1 12.8M][xa2 25.6M][H2extra 6.4M][scr]
    // H2 = xa2 chunk-3 region + H2extra (contiguous). Chunks processed
    // DESCENDING so chunk 3's xa is consumed before agg2i writes H2.
    const size_t chunkHalf2 = (size_t)NN * 32;
    float*        dinv = (float*)       alloc((size_t)NN * 4);
    int*          off  = (int*)         alloc((size_t)(NN + 1) * 4);
    unsigned int* csrp = (unsigned int*)alloc((size_t)EE * 4);
    __half2*      H1   = (__half2*)     alloc((size_t)NN * 64 * 4);
    __half2*      xa2  = (__half2*)     alloc(chunkHalf2 * 4 * 4);
    __half2*      h2x  = (__half2*)     alloc(chunkHalf2 * 4);
    float*        scr  = (float*)       alloc((size_t)8 * GC * 4);
    (void)h2x;
    __half2* H2 = xa2 + 3 * chunkHalf2;
    float* pmaxT = scr;                   // [layer(3)][tc(2)][GC]
    float* psumT = scr + 6 * GC;          // [tc(2)][GC]

    // setup-only buffers aliased into H1 (dead before H1's first write)
    int* deg    = (int*)H1;
    int* cursor = ((int*)H1) + NN;
    int* bsum   = ((int*)H1) + 2 * NN;

    init_deg<<<NBLK, 256, 0, stream>>>(deg, cursor);
    count_deg<<<(EE + 255) / 256, 256, 0, stream>>>(dst, deg);
    compute_dinv<<<NBLK, 256, 0, stream>>>(deg, dinv);
    scan_blocks<<<NBLK, SCAN_B, 0, stream>>>(deg, off, bsum);
    scan_sums<<<1, SCAN_B, 0, stream>>>(bsum, off);
    scan_add<<<NBLK, SCAN_B, 0, stream>>>(off, bsum);
    fill_csr<<<(EE + 255) / 256, 256, 0, stream>>>(src, dst, off, cursor, dinv, csrp);
    scratch_init<<<(8 * GC + 255) / 256, 256, 0, stream>>>(scr, 8 * GC);

    agg_x_allT16<<<NN / 4, 256, 0, stream>>>(x, off, csrp, dinv, xa2);

    for (int c = 3; c >= 0; --c) {        // descending: frees chunk 3 first
        int t0 = 2 * c;
        const __half2* xc = xa2 + (size_t)c * chunkHalf2;
        l1mat2i<<<NN / 4, 256, 0, stream>>>(xc, W1, b1, W2, H1, pmaxT, psumT);
        agg2i<1><<<NN / 4, 256, 0, stream>>>(H1, off, csrp, dinv, b2, W3, H2,
                                             pmaxT + 2 * GC, psumT);
        agg2i<0><<<NN / 4, 256, 0, stream>>>(H2, off, csrp, dinv, b3, nullptr, nullptr,
                                             pmaxT + 4 * GC, psumT);
        fold2<<<(2 * GC + 255) / 256, 256, 0, stream>>>(pmaxT, psumT, out, t0);
    }
}

// Round 12
// 851.334 us; speedup vs baseline: 3.8300x; 1.0119x over previous
//
#include <hip/hip_runtime.h>
#include <hip/hip_fp16.h>
#include <math.h>

#define NN 50000
#define EE 800000
#define BB 250
#define TT 8
#define CIN 32
#define COUT 64
#define NPG 200          // nodes per graph (N/B)
#define SCAN_B 256
#define NBLK 196         // ceil(50000/256)
#define GC (BB * COUT)   // 16000 floats per pool slab

// pack/unpack CSR entry: low 16 = src node (NN<65536), high 16 = fp16 weight
__device__ __forceinline__ float unpack_w(unsigned int v) {
    union { unsigned short u; __half h; } cv;
    cv.u = (unsigned short)(v >> 16);
    return __half2float(cv.h);
}

// ---------------- setup kernels (graph structure, once per call) ----------------

__global__ void init_deg(int* deg, int* cursor) {
    int n = blockIdx.x * 256 + threadIdx.x;
    if (n < NN) { deg[n] = 1; cursor[n] = 0; }
}

__global__ void count_deg(const int* dst, int* deg) {
    int e = blockIdx.x * 256 + threadIdx.x;
    if (e < EE) atomicAdd(&deg[dst[e]], 1);
}

__global__ void compute_dinv(const int* deg, float* dinv) {
    int n = blockIdx.x * 256 + threadIdx.x;
    if (n < NN) dinv[n] = rsqrtf((float)deg[n]);
}

__global__ void scan_blocks(const int* deg, int* off, int* bsum) {
    __shared__ int sh[SCAN_B];
    int gid = blockIdx.x * SCAN_B + threadIdx.x;
    int v = (gid < NN) ? (deg[gid] - 1) : 0;
    sh[threadIdx.x] = v;
    __syncthreads();
    for (int s = 1; s < SCAN_B; s <<= 1) {
        int add = (threadIdx.x >= s) ? sh[threadIdx.x - s] : 0;
        __syncthreads();
        sh[threadIdx.x] += add;
        __syncthreads();
    }
    if (gid < NN) off[gid] = sh[threadIdx.x] - v;
    if (threadIdx.x == SCAN_B - 1) bsum[blockIdx.x] = sh[threadIdx.x];
}

__global__ void scan_sums(int* bsum, int* off) {
    __shared__ int sh[SCAN_B];
    int v = (threadIdx.x < NBLK) ? bsum[threadIdx.x] : 0;
    sh[threadIdx.x] = v;
    __syncthreads();
    for (int s = 1; s < SCAN_B; s <<= 1) {
        int add = (threadIdx.x >= s) ? sh[threadIdx.x - s] : 0;
        __syncthreads();
        sh[threadIdx.x] += add;
        __syncthreads();
    }
    if (threadIdx.x < NBLK) bsum[threadIdx.x] = sh[threadIdx.x] - v;
    if (threadIdx.x == 0) off[NN] = EE;
}

__global__ void scan_add(int* off, const int* bsum) {
    int gid = blockIdx.x * SCAN_B + threadIdx.x;
    if (gid < NN) off[gid] += bsum[blockIdx.x];
}

__global__ void fill_csr(const int* src, const int* dst, const int* off,
                         int* cursor, const float* dinv, unsigned int* csrp) {
    int e = blockIdx.x * 256 + threadIdx.x;
    if (e >= EE) return;
    int s = src[e], d = dst[e];
    int p = atomicAdd(&cursor[d], 1);
    union { __half h; unsigned short u; } cv;
    cv.h = __float2half(dinv[s] * dinv[d]);
    csrp[off[d] + p] = (unsigned int)s | ((unsigned int)cv.u << 16);
}

__global__ void scratch_init(float* scr, int ntot) {
    int i = blockIdx.x * 256 + threadIdx.x;
    if (i < ntot) scr[i] = 0.f;
}

// ---------------- compute kernels ----------------

// ONE pass over edges: xa2 chunk-interleaved fp16. Broadcast walk (16B/lane).
__global__ void agg_x_allT16(const float* __restrict__ x, const int* __restrict__ off,
                             const unsigned int* __restrict__ csrp,
                             const float* __restrict__ dinv, __half2* __restrict__ xa2) {
    int lane = threadIdx.x & 63;
    int w = threadIdx.x >> 6;
    int n = blockIdx.x * 4 + w;
    float dn = dinv[n];
    float sw = dn * dn;
    float4 v = ((const float4*)(x + (size_t)n * 256))[lane];
    float4 acc = make_float4(sw * v.x, sw * v.y, sw * v.z, sw * v.w);
    int e0 = off[n], e1 = off[n + 1];
    for (int base = e0; base < e1; base += 64) {
        int idx = base + lane;
        unsigned int cme = (idx < e1) ? csrp[idx] : 0u;
        int cnt = min(64, e1 - base);
        int k = 0;
        for (; k + 3 < cnt; k += 4) {
            unsigned int p0 = __shfl(cme, k, 64),     p1 = __shfl(cme, k + 1, 64);
            unsigned int p2 = __shfl(cme, k + 2, 64), p3 = __shfl(cme, k + 3, 64);
            float4 u0 = ((const float4*)(x + (size_t)(p0 & 0xffff) * 256))[lane];
            float4 u1 = ((const float4*)(x + (size_t)(p1 & 0xffff) * 256))[lane];
            float4 u2 = ((const float4*)(x + (size_t)(p2 & 0xffff) * 256))[lane];
            float4 u3 = ((const float4*)(x + (size_t)(p3 & 0xffff) * 256))[lane];
            float w0 = unpack_w(p0), w1 = unpack_w(p1);
            float w2 = unpack_w(p2), w3 = unpack_w(p3);
            acc.x = fmaf(w0, u0.x, acc.x); acc.y = fmaf(w0, u0.y, acc.y);
            acc.z = fmaf(w0, u0.z, acc.z); acc.w = fmaf(w0, u0.w, acc.w);
            acc.x = fmaf(w1, u1.x, acc.x); acc.y = fmaf(w1, u1.y, acc.y);
            acc.z = fmaf(w1, u1.z, acc.z); acc.w = fmaf(w1, u1.w, acc.w);
            acc.x = fmaf(w2, u2.x, acc.x); acc.y = fmaf(w2, u2.y, acc.y);
            acc.z = fmaf(w2, u2.z, acc.z); acc.w = fmaf(w2, u2.w, acc.w);
            acc.x = fmaf(w3, u3.x, acc.x); acc.y = fmaf(w3, u3.y, acc.y);
            acc.z = fmaf(w3, u3.z, acc.z); acc.w = fmaf(w3, u3.w, acc.w);
        }
        for (; k < cnt; ++k) {
            unsigned int p = __shfl(cme, k, 64);
            float wj = unpack_w(p);
            float4 u = ((const float4*)(x + (size_t)(p & 0xffff) * 256))[lane];
            acc.x = fmaf(wj, u.x, acc.x); acc.y = fmaf(wj, u.y, acc.y);
            acc.z = fmaf(wj, u.z, acc.z); acc.w = fmaf(wj, u.w, acc.w);
        }
    }
    // element flat idx f = 4*lane+k -> (c = f>>3, t = f&7)
    __shared__ float sh[4][TT][33];
    float av[4] = {acc.x, acc.y, acc.z, acc.w};
    #pragma unroll
    for (int k = 0; k < 4; ++k) {
        int f = 4 * lane + k;
        sh[w][f & 7][f >> 3] = av[k];
    }
    __syncthreads();
    // chunk-interleaved write: addr = (chunk*NN + n)*32 + tc*16 + pp
    for (int i = threadIdx.x; i < 512; i += 256) {
        int t = i >> 6;
        int r = i & 63;
        int nl = r >> 4;
        int pp = r & 15;
        xa2[((size_t)(t >> 1) * NN + blockIdx.x * 4 + nl) * 32 + (t & 1) * 16 + pp] =
            __floats2half2_rn(sh[nl][t][2 * pp], sh[nl][t][2 * pp + 1]);
    }
}

// h1 = relu(xa[chunk] W1 + b1), pool, H1[n][tc][pr] = h1 W2 (interleaved out)
__global__ void l1mat2i(const __half2* __restrict__ xa, const float* __restrict__ W1,
                        const float* __restrict__ b1, const float* __restrict__ W2,
                        __half2* __restrict__ H1,
                        float* __restrict__ pmax, float* __restrict__ psum) {
    __shared__ float W1s[CIN * COUT];      // 8 KB
    __shared__ __half2 W2s[COUT * 32];     // 8 KB
    __shared__ float Xs[4][2][CIN];
    __shared__ float tile[4][2][COUT];
    for (int i = threadIdx.x; i < CIN * COUT; i += 256) W1s[i] = W1[i];
    for (int i = threadIdx.x; i < COUT * 32; i += 256) {
        int k = i >> 5, pr = i & 31;
        W2s[i] = __floats2half2_rn(W2[k * COUT + 2 * pr], W2[k * COUT + 2 * pr + 1]);
    }
    if (threadIdx.x < 128) {
        int nl = threadIdx.x >> 5, idx = threadIdx.x & 31;
        int tc = idx >> 4, pp = idx & 15;
        float2 v = __half22float2(xa[((size_t)blockIdx.x * 4 + nl) * 32 + idx]);
        Xs[nl][tc][2 * pp] = v.x;
        Xs[nl][tc][2 * pp + 1] = v.y;
    }
    __syncthreads();
    int co = threadIdx.x & 63;
    int nl = threadIdx.x >> 6;
    float a0 = b1[co], a1 = b1[co];
    #pragma unroll
    for (int k = 0; k < CIN; ++k) {
        float wv = W1s[k * COUT + co];
        a0 = fmaf(Xs[nl][0][k], wv, a0);
        a1 = fmaf(Xs[nl][1][k], wv, a1);
    }
    tile[nl][0][co] = fmaxf(a0, 0.f);
    tile[nl][1][co] = fmaxf(a1, 0.f);
    __syncthreads();
    if (threadIdx.x < 128) {
        int c = threadIdx.x & 63, tc = threadIdx.x >> 6;
        float m = fmaxf(fmaxf(tile[0][tc][c], tile[1][tc][c]),
                        fmaxf(tile[2][tc][c], tile[3][tc][c]));
        float s = tile[0][tc][c] + tile[1][tc][c] + tile[2][tc][c] + tile[3][tc][c];
        int g = blockIdx.x / 50;
        atomicMax((int*)&pmax[tc * GC + g * COUT + c], __float_as_int(m));
        atomicAdd(&psum[tc * GC + g * COUT + c], s);
    }
    {   // W2 matmul: 256 thr = 8 rows (4 nodes x 2 tc) x 32 pairs
        int row = threadIdx.x >> 5;
        int pr = threadIdx.x & 31;
        int nl2 = row >> 1, tc2 = row & 1;
        float b0 = 0.f, bb1 = 0.f;
        #pragma unroll
        for (int k = 0; k < COUT; ++k) {
            float xv = tile[nl2][tc2][k];
            float2 wv = __half22float2(W2s[k * 32 + pr]);
            b0 = fmaf(xv, wv.x, b0);
            bb1 = fmaf(xv, wv.y, bb1);
        }
        H1[((size_t)blockIdx.x * 4 + nl2) * 64 + tc2 * 32 + pr] =
            __floats2half2_rn(b0, bb1);
    }
}

// Quad-edge 2-t aggregation: lane = (edge-in-quad sub, 16B-offset qoff).
// ONE global_load_dwordx4 per wave fetches FOUR edges' 256B rows (16B/lane).
// Tail edges masked with weight 0. shfl_xor(16,32) reduces edge groups.
template <int FUSE>
__global__ void agg2q(const __half2* __restrict__ Hin, const int* __restrict__ off,
                      const unsigned int* __restrict__ csrp,
                      const float* __restrict__ dinv, const float* __restrict__ b,
                      const float* __restrict__ W, __half2* __restrict__ Hout,
                      float* __restrict__ pmax, float* __restrict__ psum) {
    __shared__ __half2 Ws[FUSE ? COUT * 32 : 1];
    __shared__ float tile[4][2][COUT];
    if (FUSE)
        for (int i = threadIdx.x; i < COUT * 32; i += 256) {
            int k = i >> 5, pr = i & 31;
            Ws[i] = __floats2half2_rn(W[k * COUT + 2 * pr], W[k * COUT + 2 * pr + 1]);
        }
    int lane = threadIdx.x & 63;
    int sub = lane >> 4;       // which edge within quad
    int qoff = lane & 15;      // float4 slot within 256B row
    int w = threadIdx.x >> 6;
    int n = blockIdx.x * 4 + w;
    int e0 = off[n], e1 = off[n + 1];
    float a0 = 0.f, a1 = 0.f, a2 = 0.f, a3 = 0.f;
    float a4 = 0.f, a5 = 0.f, a6 = 0.f, a7 = 0.f;
    union F4H { float4 f; __half2 h[4]; };
    for (int base = e0; base < e1; base += 64) {
        int idx = base + lane;
        unsigned int cme = (idx < e1) ? csrp[idx] : 0u;   // 1 load / 64 edges
        int cnt = min(64, e1 - base);
        int rounds = (cnt + 3) >> 2;
        for (int r = 0; r < rounds; ++r) {
            int k = 4 * r + sub;
            unsigned int ce = __shfl(cme, k, 64);
            float wv = (k < cnt) ? unpack_w(ce) : 0.f;    // masked tail (ce=0 safe)
            F4H u;
            u.f = ((const float4*)(Hin + (size_t)(ce & 0xffff) * 64))[qoff];
            float2 f0 = __half22float2(u.h[0]);
            float2 f1 = __half22float2(u.h[1]);
            float2 f2 = __half22float2(u.h[2]);
            float2 f3 = __half22float2(u.h[3]);
            a0 = fmaf(wv, f0.x, a0); a1 = fmaf(wv, f0.y, a1);
            a2 = fmaf(wv, f1.x, a2); a3 = fmaf(wv, f1.y, a3);
            a4 = fmaf(wv, f2.x, a4); a5 = fmaf(wv, f2.y, a5);
            a6 = fmaf(wv, f3.x, a6); a7 = fmaf(wv, f3.y, a7);
        }
    }
    // reduce the 4 edge groups (lanes with same qoff)
    a0 += __shfl_xor(a0, 16, 64); a0 += __shfl_xor(a0, 32, 64);
    a1 += __shfl_xor(a1, 16, 64); a1 += __shfl_xor(a1, 32, 64);
    a2 += __shfl_xor(a2, 16, 64); a2 += __shfl_xor(a2, 32, 64);
    a3 += __shfl_xor(a3, 16, 64); a3 += __shfl_xor(a3, 32, 64);
    a4 += __shfl_xor(a4, 16, 64); a4 += __shfl_xor(a4, 32, 64);
    a5 += __shfl_xor(a5, 16, 64); a5 += __shfl_xor(a5, 32, 64);
    a6 += __shfl_xor(a6, 16, 64); a6 += __shfl_xor(a6, 32, 64);
    a7 += __shfl_xor(a7, 16, 64); a7 += __shfl_xor(a7, 32, 64);
    if (sub == 0) {
        // self-loop + bias + relu; lane qoff owns row half2 slots 4q..4q+3
        float dn = dinv[n];
        float sw = dn * dn;
        F4H su;
        su.f = ((const float4*)(Hin + (size_t)n * 64))[qoff];
        float acc[8] = {a0, a1, a2, a3, a4, a5, a6, a7};
        #pragma unroll
        for (int i = 0; i < 4; ++i) {
            int h = 4 * qoff + i;
            int tcc = h >> 5;
            int p = h & 31;
            float2 sv = __half22float2(su.h[i]);
            float ox = fmaxf(fmaf(sw, sv.x, acc[2 * i])     + b[2 * p],     0.f);
            float oy = fmaxf(fmaf(sw, sv.y, acc[2 * i + 1]) + b[2 * p + 1], 0.f);
            tile[w][tcc][2 * p] = ox;
            tile[w][tcc][2 * p + 1] = oy;
        }
    }
    __syncthreads();
    if (threadIdx.x < 128) {
        int c = threadIdx.x & 63, tcc = threadIdx.x >> 6;
        float m = fmaxf(fmaxf(tile[0][tcc][c], tile[1][tcc][c]),
                        fmaxf(tile[2][tcc][c], tile[3][tcc][c]));
        float s = tile[0][tcc][c] + tile[1][tcc][c] + tile[2][tcc][c] + tile[3][tcc][c];
        int g = blockIdx.x / 50;
        atomicMax((int*)&pmax[tcc * GC + g * COUT + c], __float_as_int(m));
        atomicAdd(&psum[tcc * GC + g * COUT + c], s);
    }
    if (FUSE) {
        int row = threadIdx.x >> 5;
        int pr = threadIdx.x & 31;
        int nl2 = row >> 1, tc2 = row & 1;
        float b0 = 0.f, bb1 = 0.f;
        #pragma unroll
        for (int k = 0; k < COUT; ++k) {
            float xv = tile[nl2][tc2][k];
            float2 wv = __half22float2(Ws[k * 32 + pr]);
            b0 = fmaf(xv, wv.x, b0);
            bb1 = fmaf(xv, wv.y, bb1);
        }
        Hout[((size_t)blockIdx.x * 4 + nl2) * 64 + tc2 * 32 + pr] =
            __floats2half2_rn(b0, bb1);
    }
}

// fold 2-t scratch -> out[:, :, t0..t0+1], reset
__global__ void fold2(float* __restrict__ pmaxT, float* __restrict__ psumT,
                      float* __restrict__ out, int t0) {
    int i = blockIdx.x * 256 + threadIdx.x;
    if (i >= 2 * GC) return;
    int tc = i / GC;
    int r = i - tc * GC;
    int g = r >> 6, c = r & 63;
    float m = pmaxT[tc * GC + r] + pmaxT[2 * GC + tc * GC + r] +
              pmaxT[4 * GC + tc * GC + r];
    float mean = psumT[i] * (1.0f / NPG);
    int t = t0 + tc;
    out[((size_t)g * 128 + c) * TT + t] = m;
    out[((size_t)g * 128 + 64 + c) * TT + t] = mean;
    pmaxT[tc * GC + r] = 0.f;
    pmaxT[2 * GC + tc * GC + r] = 0.f;
    pmaxT[4 * GC + tc * GC + r] = 0.f;
    psumT[i] = 0.f;
}

// ---------------- launch ----------------

extern "C" void kernel_launch(void* const* d_in, const int* in_sizes, int n_in,
                              void* d_out, int out_size, void* d_ws, size_t ws_size,
                              hipStream_t stream) {
    const float* x   = (const float*)d_in[0];
    const int*   ei  = (const int*)d_in[1];
    const int*   src = ei;
    const int*   dst = ei + EE;
    const float* W1  = (const float*)d_in[3];
    const float* b1  = (const float*)d_in[4];
    const float* W2  = (const float*)d_in[5];
    const float* b2  = (const float*)d_in[6];
    const float* W3  = (const float*)d_in[7];
    const float* b3  = (const float*)d_in[8];
    float* out = (float*)d_out;

    char* wsp = (char*)d_ws;
    auto alloc = [&](size_t bytes) {
        char* p = wsp;
        wsp += (bytes + 255) & ~(size_t)255;
        return p;
    };
    // layout (~48.9 MB, ws known >= 51.67 MB):
    // [dinv][off][csrp][H1 12.8M][xa2 25.6M][H2extra 6.4M][scr]
    // H2 = xa2 chunk-3 region + H2extra (contiguous). Chunks processed
    // DESCENDING so chunk 3's xa is consumed before agg2q writes H2.
    const size_t chunkHalf2 = (size_t)NN * 32;
    float*        dinv = (float*)       alloc((size_t)NN * 4);
    int*          off  = (int*)         alloc((size_t)(NN + 1) * 4);
    unsigned int* csrp = (unsigned int*)alloc((size_t)EE * 4);
    __half2*      H1   = (__half2*)     alloc((size_t)NN * 64 * 4);
    __half2*      xa2  = (__half2*)     alloc(chunkHalf2 * 4 * 4);
    __half2*      h2x  = (__half2*)     alloc(chunkHalf2 * 4);
    float*        scr  = (float*)       alloc((size_t)8 * GC * 4);
    (void)h2x;
    __half2* H2 = xa2 + 3 * chunkHalf2;
    float* pmaxT = scr;                   // [layer(3)][tc(2)][GC]
    float* psumT = scr + 6 * GC;          // [tc(2)][GC]

    // setup-only buffers aliased into H1 (dead before H1's first write)
    int* deg    = (int*)H1;
    int* cursor = ((int*)H1) + NN;
    int* bsum   = ((int*)H1) + 2 * NN;

    init_deg<<<NBLK, 256, 0, stream>>>(deg, cursor);
    count_deg<<<(EE + 255) / 256, 256, 0, stream>>>(dst, deg);
    compute_dinv<<<NBLK, 256, 0, stream>>>(deg, dinv);
    scan_blocks<<<NBLK, SCAN_B, 0, stream>>>(deg, off, bsum);
    scan_sums<<<1, SCAN_B, 0, stream>>>(bsum, off);
    scan_add<<<NBLK, SCAN_B, 0, stream>>>(off, bsum);
    fill_csr<<<(EE + 255) / 256, 256, 0, stream>>>(src, dst, off, cursor, dinv, csrp);
    scratch_init<<<(8 * GC + 255) / 256, 256, 0, stream>>>(scr, 8 * GC);

    agg_x_allT16<<<NN / 4, 256, 0, stream>>>(x, off, csrp, dinv, xa2);

    for (int c = 3; c >= 0; --c) {        // descending: frees chunk 3 first
        int t0 = 2 * c;
        const __half2* xc = xa2 + (size_t)c * chunkHalf2;
        l1mat2i<<<NN / 4, 256, 0, stream>>>(xc, W1, b1, W2, H1, pmaxT, psumT);
        agg2q<1><<<NN / 4, 256, 0, stream>>>(H1, off, csrp, dinv, b2, W3, H2,
                                             pmaxT + 2 * GC, psumT);
        agg2q<0><<<NN / 4, 256, 0, stream>>>(H2, off, csrp, dinv, b3, nullptr, nullptr,
                                             pmaxT + 4 * GC, psumT);
        fold2<<<(2 * GC + 255) / 256, 256, 0, stream>>>(pmaxT, psumT, out, t0);
    }
}